// Round 1
// baseline (223.537 us; speedup 1.0000x reference)
//
#include <hip/hip_runtime.h>
#include <math.h>

#define BB 64
#define NN 1024
#define F_IN 64
#define EE 128
#define TOPK 32
#define NEG_SLOPE 0.2f

// ---------------------------------------------------------------------------
// K1: per-node reciprocal norm + emb-side attention terms
//   rn[n]    = 1/||emb[n]||
//   u_src[n] = emb[n] . a_src[E:2E]
//   u_dst[n] = emb[n] . a_dst[E:2E]
// wave per node; grid 256 x 256
// ---------------------------------------------------------------------------
__global__ __launch_bounds__(256) void k1_node_pre(
    const float* __restrict__ emb, const float* __restrict__ a_src,
    const float* __restrict__ a_dst, float* __restrict__ rn,
    float* __restrict__ u_src, float* __restrict__ u_dst) {
  const int wid = threadIdx.x >> 6;
  const int lane = threadIdx.x & 63;
  const int n = blockIdx.x * 4 + wid;
  const float* er = emb + (size_t)n * EE;
  const float e0 = er[lane], e1 = er[lane + 64];
  float ss = e0 * e0 + e1 * e1;
  float us = e0 * a_src[EE + lane] + e1 * a_src[EE + lane + 64];
  float ud = e0 * a_dst[EE + lane] + e1 * a_dst[EE + lane + 64];
#pragma unroll
  for (int off = 32; off > 0; off >>= 1) {
    ss += __shfl_xor(ss, off);
    us += __shfl_xor(us, off);
    ud += __shfl_xor(ud, off);
  }
  if (lane == 0) {
    rn[n] = 1.0f / sqrtf(ss);
    u_src[n] = us;
    u_dst[n] = ud;
  }
}

// ---------------------------------------------------------------------------
// K2: top-32 by cosine similarity.
// Ranking key: dot(emb_i, emb_j) * rn[j]  (the rn[i] factor is a positive
// per-row constant -> does not change ordering).
// Block handles 4 rows i; compute sims into LDS; wave w selects row i0+w via
// 32 x (in-register argmax + 64-lane butterfly), keys packed u64.
// grid 256 x 256
// ---------------------------------------------------------------------------
__global__ __launch_bounds__(256) void k2_topk(const float* __restrict__ emb,
                                               const float* __restrict__ rn,
                                               int* __restrict__ idx_out) {
  __shared__ __align__(16) float embi[4][EE];   // 2 KB
  __shared__ __align__(16) float simlds[4][NN]; // 16 KB
  const int t = threadIdx.x;
  const int i0 = blockIdx.x * 4;

  for (int f = t; f < 4 * EE; f += 256) {
    const int ii = f >> 7, d = f & 127;
    embi[ii][d] = emb[(size_t)(i0 + ii) * EE + d];
  }
  __syncthreads();

  float acc[4][4];
#pragma unroll
  for (int ii = 0; ii < 4; ii++)
#pragma unroll
    for (int q = 0; q < 4; q++) acc[ii][q] = 0.f;

  for (int d = 0; d < EE; d += 4) {
    float4 ei[4];
#pragma unroll
    for (int ii = 0; ii < 4; ii++) ei[ii] = *(const float4*)&embi[ii][d];
#pragma unroll
    for (int q = 0; q < 4; q++) {
      const int j = q * 256 + t;
      const float4 ej = *(const float4*)&emb[(size_t)j * EE + d];
#pragma unroll
      for (int ii = 0; ii < 4; ii++) {
        acc[ii][q] += ej.x * ei[ii].x + ej.y * ei[ii].y + ej.z * ei[ii].z +
                      ej.w * ei[ii].w;
      }
    }
  }
#pragma unroll
  for (int q = 0; q < 4; q++) {
    const int j = q * 256 + t;
    const float r = rn[j];
#pragma unroll
    for (int ii = 0; ii < 4; ii++) simlds[ii][j] = acc[ii][q] * r;
  }
  __syncthreads();

  // selection: wave wid handles row i0+wid
  const int wid = t >> 6, lane = t & 63;
  unsigned long long keys[16];
#pragma unroll
  for (int q = 0; q < 16; q++) {
    const int j = q * 64 + lane; // lane-consecutive -> conflict-free LDS read
    const float v = simlds[wid][j];
    unsigned int u = __float_as_uint(v);
    u = (u & 0x80000000u) ? ~u : (u | 0x80000000u); // monotone float->uint
    keys[q] = ((unsigned long long)u << 32) | (unsigned int)j;
  }
  int* row_out = idx_out + (size_t)(i0 + wid) * TOPK;
  for (int s = 0; s < TOPK; s++) {
    unsigned long long m = keys[0];
#pragma unroll
    for (int q = 1; q < 16; q++) m = keys[q] > m ? keys[q] : m;
#pragma unroll
    for (int off = 32; off > 0; off >>= 1) {
      const unsigned long long o = __shfl_xor(m, off);
      m = o > m ? o : m;
    }
    const unsigned int j = (unsigned int)m;
    if (lane == 0) row_out[s] = (int)j;
    const int jq = (int)(j >> 6), jl = (int)(j & 63);
    if (jl == lane) {
#pragma unroll
      for (int q = 0; q < 16; q++)
        if (q == jq) keys[q] = 0ull;
    }
  }
}

// ---------------------------------------------------------------------------
// K3: h = x @ W_fe  (M=65536, K=64, N=128) + fused e_s/e_d row dots.
// Block: 256 threads, 64 rows. W in LDS (32 KB); x staged transposed
// (stride 68 -> 16B-aligned float4 reads, broadcast). Wave register-blocks
// 16 rows x 2 cols (cols 2*lane, 2*lane+1): 32 FMA per {1 b64 + 4 b128} LDS.
// grid 1024 x 256
// ---------------------------------------------------------------------------
__global__ __launch_bounds__(256) void k3_feat(
    const float* __restrict__ x, const float* __restrict__ W_fe,
    const float* __restrict__ a_src, const float* __restrict__ a_dst,
    const float* __restrict__ u_src, const float* __restrict__ u_dst,
    float* __restrict__ h, float* __restrict__ es, float* __restrict__ ed) {
  __shared__ __align__(16) float Wl[F_IN * EE]; // 32 KB
  __shared__ __align__(16) float xT[F_IN][68];  // 17.4 KB
  const int t = threadIdx.x;
  const int row0 = blockIdx.x * 64;

  for (int f4 = t; f4 < (F_IN * EE) / 4; f4 += 256)
    *(float4*)&Wl[f4 * 4] = *(const float4*)&W_fe[f4 * 4];
  for (int f4 = t; f4 < (64 * F_IN) / 4; f4 += 256) {
    const float4 v = *(const float4*)&x[(size_t)row0 * F_IN + (size_t)f4 * 4];
    const int r = f4 >> 4;
    const int k0 = (f4 & 15) * 4;
    xT[k0 + 0][r] = v.x;
    xT[k0 + 1][r] = v.y;
    xT[k0 + 2][r] = v.z;
    xT[k0 + 3][r] = v.w;
  }
  __syncthreads();

  const int wid = t >> 6, lane = t & 63;
  const int r0 = wid * 16;
  float acc0[16], acc1[16];
#pragma unroll
  for (int r = 0; r < 16; r++) {
    acc0[r] = 0.f;
    acc1[r] = 0.f;
  }
#pragma unroll 4
  for (int k = 0; k < F_IN; k++) {
    const float2 w2 = *(const float2*)&Wl[k * EE + 2 * lane];
    float xv[16];
    *(float4*)&xv[0] = *(const float4*)&xT[k][r0 + 0];
    *(float4*)&xv[4] = *(const float4*)&xT[k][r0 + 4];
    *(float4*)&xv[8] = *(const float4*)&xT[k][r0 + 8];
    *(float4*)&xv[12] = *(const float4*)&xT[k][r0 + 12];
#pragma unroll
    for (int r = 0; r < 16; r++) {
      acc0[r] += xv[r] * w2.x;
      acc1[r] += xv[r] * w2.y;
    }
  }
  const float2 as2 = *(const float2*)&a_src[2 * lane];
  const float2 ad2 = *(const float2*)&a_dst[2 * lane];
#pragma unroll
  for (int r = 0; r < 16; r++) {
    const int row = row0 + r0 + r;
    const float h0 = acc0[r], h1 = acc1[r];
    *(float2*)&h[(size_t)row * EE + 2 * lane] = make_float2(h0, h1);
    float ps = h0 * as2.x + h1 * as2.y;
    float pd = h0 * ad2.x + h1 * ad2.y;
#pragma unroll
    for (int off = 32; off > 0; off >>= 1) {
      ps += __shfl_xor(ps, off);
      pd += __shfl_xor(pd, off);
    }
    if (lane == 0) {
      const int n = row & (NN - 1);
      es[row] = ps + u_src[n];
      ed[row] = pd + u_dst[n];
    }
  }
}

// ---------------------------------------------------------------------------
// K4: per-(b,n) wave: gather e_d at idx, leaky-relu, softmax, weighted sum of
// 32 h-rows (float2/lane, coalesced), relu, dot lin_W, store scalar.
// b-major block order -> each XCD's L2 keeps h[b] (512 KB) hot.
// grid 16384 x 256
// ---------------------------------------------------------------------------
__global__ __launch_bounds__(256) void k4_attn(
    const float* __restrict__ h, const float* __restrict__ es,
    const float* __restrict__ ed, const int* __restrict__ idx,
    const float* __restrict__ lin_W, const float* __restrict__ lin_b,
    float* __restrict__ y) {
  __shared__ int jbuf[4][TOPK];
  __shared__ float pbuf[4][TOPK];
  const int t = threadIdx.x, wid = t >> 6, lane = t & 63;
  const int gw = blockIdx.x * 4 + wid; // = b*1024 + n  (b-major)
  const int b = gw >> 10, n = gw & 1023;

  const float esv = es[(size_t)b * NN + n];
  const float* edb = ed + (size_t)b * NN;
  float sv = -INFINITY;
  int j = 0;
  if (lane < TOPK) {
    j = idx[n * TOPK + lane];
    const float s = esv + edb[j];
    sv = s > 0.f ? s : NEG_SLOPE * s;
  }
  float m = sv;
#pragma unroll
  for (int off = 32; off > 0; off >>= 1) {
    const float o = __shfl_xor(m, off);
    m = o > m ? o : m;
  }
  const float p = (lane < TOPK) ? __expf(sv - m) : 0.f;
  float dsum = p;
#pragma unroll
  for (int off = 32; off > 0; off >>= 1) dsum += __shfl_xor(dsum, off);
  const float rd = 1.0f / dsum;
  if (lane < TOPK) {
    jbuf[wid][lane] = j;
    pbuf[wid][lane] = p * rd; // fold 1/sum into the weights
  }
  __syncthreads();

  float acc0 = 0.f, acc1 = 0.f;
  const float* hb = h + (size_t)b * NN * EE;
#pragma unroll 4
  for (int k = 0; k < TOPK; k++) {
    const int jk = jbuf[wid][k];     // wave-uniform broadcast
    const float ak = pbuf[wid][k];   // wave-uniform broadcast
    const float2 hv = *(const float2*)&hb[(size_t)jk * EE + 2 * lane];
    acc0 += ak * hv.x;
    acc1 += ak * hv.y;
  }
  acc0 = acc0 > 0.f ? acc0 : 0.f;
  acc1 = acc1 > 0.f ? acc1 : 0.f;
  const float2 lw = *(const float2*)&lin_W[2 * lane];
  float r = acc0 * lw.x + acc1 * lw.y;
#pragma unroll
  for (int off = 32; off > 0; off >>= 1) r += __shfl_xor(r, off);
  if (lane == 0) y[(size_t)b * NN + n] = r + lin_b[0];
}

// ---------------------------------------------------------------------------
extern "C" void kernel_launch(void* const* d_in, const int* in_sizes, int n_in,
                              void* d_out, int out_size, void* d_ws,
                              size_t ws_size, hipStream_t stream) {
  const float* x = (const float*)d_in[0];
  const float* emb = (const float*)d_in[1];
  const float* W_fe = (const float*)d_in[2];
  const float* a_src = (const float*)d_in[3];
  const float* a_dst = (const float*)d_in[4];
  const float* lin_W = (const float*)d_in[5];
  const float* lin_b = (const float*)d_in[6];
  float* y = (float*)d_out;

  char* ws = (char*)d_ws;
  float* rn = (float*)(ws + 0);
  float* u_src = (float*)(ws + 4096);
  float* u_dst = (float*)(ws + 8192);
  int* idx = (int*)(ws + 16384);                       // 128 KB
  float* es = (float*)(ws + 16384 + 131072);           // 256 KB
  float* ed = (float*)(ws + 16384 + 131072 + 262144);  // 256 KB
  float* h = (float*)(ws + 16384 + 131072 + 2 * 262144); // 32 MB

  k1_node_pre<<<NN / 4, 256, 0, stream>>>(emb, a_src, a_dst, rn, u_src, u_dst);
  k2_topk<<<NN / 4, 256, 0, stream>>>(emb, rn, idx);
  k3_feat<<<(BB * NN) / 64, 256, 0, stream>>>(x, W_fe, a_src, a_dst, u_src,
                                              u_dst, h, es, ed);
  k4_attn<<<(BB * NN) / 4, 256, 0, stream>>>(h, es, ed, idx, lin_W, lin_b, y);
}

// Round 2
// 206.393 us; speedup vs baseline: 1.0831x; 1.0831x over previous
//
#include <hip/hip_runtime.h>
#include <math.h>

#define BB 64
#define NN 1024
#define F_IN 64
#define EE 128
#define TOPK 32
#define NEG_SLOPE 0.2f

typedef unsigned int uint;

// pack float -> bf16 (round-to-nearest-even)
static __device__ __forceinline__ uint f2bf(float f) {
  const uint x = __float_as_uint(f);
  return (x + 0x7fffu + ((x >> 16) & 1u)) >> 16;
}

// ---------------------------------------------------------------------------
// K1: emb-side attention terms:
//   u_src[n] = emb[n] . a_src[E:2E],  u_dst[n] = emb[n] . a_dst[E:2E]
// ---------------------------------------------------------------------------
__global__ __launch_bounds__(256) void k1_node_pre(
    const float* __restrict__ emb, const float* __restrict__ a_src,
    const float* __restrict__ a_dst, float* __restrict__ u_src,
    float* __restrict__ u_dst) {
  const int wid = threadIdx.x >> 6;
  const int lane = threadIdx.x & 63;
  const int n = blockIdx.x * 4 + wid;
  const float* er = emb + (size_t)n * EE;
  const float e0 = er[lane], e1 = er[lane + 64];
  float us = e0 * a_src[EE + lane] + e1 * a_src[EE + lane + 64];
  float ud = e0 * a_dst[EE + lane] + e1 * a_dst[EE + lane + 64];
#pragma unroll
  for (int off = 32; off > 0; off >>= 1) {
    us += __shfl_xor(us, off);
    ud += __shfl_xor(ud, off);
  }
  if (lane == 0) {
    u_src[n] = us;
    u_dst[n] = ud;
  }
}

// ---------------------------------------------------------------------------
// K2: top-32 by cosine similarity. Rank key: dot(emb_i,emb_j)/||emb_j||
// (row factor 1/||emb_i|| is a positive constant -> order-invariant).
// ||emb_j|| accumulated inline (removes K1 dependency). d-loop unrolled x2
// for 8 outstanding gather loads.
// ---------------------------------------------------------------------------
__global__ __launch_bounds__(256) void k2_topk(const float* __restrict__ emb,
                                               int* __restrict__ idx_out) {
  __shared__ __align__(16) float embi[4][EE];   // 2 KB
  __shared__ __align__(16) float simlds[4][NN]; // 16 KB
  const int t = threadIdx.x;
  const int i0 = blockIdx.x * 4;

  for (int f = t; f < 4 * EE; f += 256) {
    const int ii = f >> 7, d = f & 127;
    embi[ii][d] = emb[(size_t)(i0 + ii) * EE + d];
  }
  __syncthreads();

  float acc[4][4];
  float sq[4];
#pragma unroll
  for (int q = 0; q < 4; q++) {
    sq[q] = 0.f;
#pragma unroll
    for (int ii = 0; ii < 4; ii++) acc[ii][q] = 0.f;
  }

#pragma unroll 2
  for (int d = 0; d < EE; d += 4) {
    float4 ei[4];
#pragma unroll
    for (int ii = 0; ii < 4; ii++) ei[ii] = *(const float4*)&embi[ii][d];
#pragma unroll
    for (int q = 0; q < 4; q++) {
      const int j = q * 256 + t;
      const float4 ej = *(const float4*)&emb[(size_t)j * EE + d];
      sq[q] += ej.x * ej.x + ej.y * ej.y + ej.z * ej.z + ej.w * ej.w;
#pragma unroll
      for (int ii = 0; ii < 4; ii++) {
        acc[ii][q] += ej.x * ei[ii].x + ej.y * ei[ii].y + ej.z * ei[ii].z +
                      ej.w * ei[ii].w;
      }
    }
  }
#pragma unroll
  for (int q = 0; q < 4; q++) {
    const int j = q * 256 + t;
    const float r = rsqrtf(sq[q]);
#pragma unroll
    for (int ii = 0; ii < 4; ii++) simlds[ii][j] = acc[ii][q] * r;
  }
  __syncthreads();

  // selection: wave wid selects top-32 for row i0+wid
  const int wid = t >> 6, lane = t & 63;
  unsigned long long keys[16];
#pragma unroll
  for (int q = 0; q < 16; q++) {
    const int j = q * 64 + lane;
    const float v = simlds[wid][j];
    uint u = __float_as_uint(v);
    u = (u & 0x80000000u) ? ~u : (u | 0x80000000u); // monotone float->uint
    keys[q] = ((unsigned long long)u << 32) | (uint)j;
  }
  int* row_out = idx_out + (size_t)(i0 + wid) * TOPK;
  for (int s = 0; s < TOPK; s++) {
    unsigned long long m = keys[0];
#pragma unroll
    for (int q = 1; q < 16; q++) m = keys[q] > m ? keys[q] : m;
#pragma unroll
    for (int off = 32; off > 0; off >>= 1) {
      const unsigned long long o = __shfl_xor(m, off);
      m = o > m ? o : m;
    }
    const uint j = (uint)m;
    if (lane == 0) row_out[s] = (int)j;
    const int jq = (int)(j >> 6), jl = (int)(j & 63);
    if (jl == lane) {
#pragma unroll
      for (int q = 0; q < 16; q++)
        if (q == jq) keys[q] = 0ull;
    }
  }
}

// ---------------------------------------------------------------------------
// K3: h = x @ W_fe  (65536 x 64 x 128) + fused e_s/e_d row dots.
// h stored as packed bf16 pairs (uint per col-pair) -> halves K4 gather bytes.
// e_s/e_d computed from fp32 accumulators (pre-quantization).
// ---------------------------------------------------------------------------
__global__ __launch_bounds__(256) void k3_feat(
    const float* __restrict__ x, const float* __restrict__ W_fe,
    const float* __restrict__ a_src, const float* __restrict__ a_dst,
    const float* __restrict__ u_src, const float* __restrict__ u_dst,
    uint* __restrict__ h2, float* __restrict__ es, float* __restrict__ ed) {
  __shared__ __align__(16) float Wl[F_IN * EE]; // 32 KB
  __shared__ __align__(16) float xT[F_IN][68];  // 17.4 KB
  const int t = threadIdx.x;
  const int row0 = blockIdx.x * 64;

  for (int f4 = t; f4 < (F_IN * EE) / 4; f4 += 256)
    *(float4*)&Wl[f4 * 4] = *(const float4*)&W_fe[f4 * 4];
  for (int f4 = t; f4 < (64 * F_IN) / 4; f4 += 256) {
    const float4 v = *(const float4*)&x[(size_t)row0 * F_IN + (size_t)f4 * 4];
    const int r = f4 >> 4;
    const int k0 = (f4 & 15) * 4;
    xT[k0 + 0][r] = v.x;
    xT[k0 + 1][r] = v.y;
    xT[k0 + 2][r] = v.z;
    xT[k0 + 3][r] = v.w;
  }
  __syncthreads();

  const int wid = t >> 6, lane = t & 63;
  const int r0 = wid * 16;
  float acc0[16], acc1[16];
#pragma unroll
  for (int r = 0; r < 16; r++) {
    acc0[r] = 0.f;
    acc1[r] = 0.f;
  }
#pragma unroll 4
  for (int k = 0; k < F_IN; k++) {
    const float2 w2 = *(const float2*)&Wl[k * EE + 2 * lane];
    float xv[16];
    *(float4*)&xv[0] = *(const float4*)&xT[k][r0 + 0];
    *(float4*)&xv[4] = *(const float4*)&xT[k][r0 + 4];
    *(float4*)&xv[8] = *(const float4*)&xT[k][r0 + 8];
    *(float4*)&xv[12] = *(const float4*)&xT[k][r0 + 12];
#pragma unroll
    for (int r = 0; r < 16; r++) {
      acc0[r] += xv[r] * w2.x;
      acc1[r] += xv[r] * w2.y;
    }
  }
  const float2 as2 = *(const float2*)&a_src[2 * lane];
  const float2 ad2 = *(const float2*)&a_dst[2 * lane];
#pragma unroll
  for (int r = 0; r < 16; r++) {
    const int row = row0 + r0 + r;
    const float h0 = acc0[r], h1 = acc1[r];
    h2[(size_t)row * 64 + lane] = f2bf(h0) | (f2bf(h1) << 16);
    float ps = h0 * as2.x + h1 * as2.y;
    float pd = h0 * ad2.x + h1 * ad2.y;
#pragma unroll
    for (int off = 32; off > 0; off >>= 1) {
      ps += __shfl_xor(ps, off);
      pd += __shfl_xor(pd, off);
    }
    if (lane == 0) {
      const int n = row & (NN - 1);
      es[row] = ps + u_src[n];
      ed[row] = pd + u_dst[n];
    }
  }
}

// ---------------------------------------------------------------------------
// K4: per-(b,n) wave attention. XCD-aware swizzle: blocks on XCD x (blk&7)
// handle only b in [8x, 8x+8) -> each XCD's 4 MB L2 holds its 8 h-slabs
// (8 x 256 KB bf16). Softmax via wave shuffles; all 32 gather loads issued
// up-front (deep MLP); no LDS, no __syncthreads.
// ---------------------------------------------------------------------------
__global__ __launch_bounds__(256) void k4_attn(
    const uint* __restrict__ h2, const float* __restrict__ es,
    const float* __restrict__ ed, const int* __restrict__ idx,
    const float* __restrict__ lin_W, const float* __restrict__ lin_b,
    float* __restrict__ y) {
  const int t = threadIdx.x, wid = t >> 6, lane = t & 63;
  const int blk = blockIdx.x;
  const int b = (blk & 7) * 8 + ((blk >> 3) >> 8);
  const int n = ((blk >> 3) & 255) * 4 + wid;

  const float esv = es[(size_t)b * NN + n];
  const float* edb = ed + (size_t)b * NN;
  float sv = -INFINITY;
  int j = 0;
  if (lane < TOPK) {
    j = idx[n * TOPK + lane];
    const float s = esv + edb[j];
    sv = s > 0.f ? s : NEG_SLOPE * s;
  }
  float m = sv;
#pragma unroll
  for (int off = 32; off > 0; off >>= 1) {
    const float o = __shfl_xor(m, off);
    m = o > m ? o : m;
  }
  const float p = (lane < TOPK) ? __expf(sv - m) : 0.f;
  float dsum = p;
#pragma unroll
  for (int off = 32; off > 0; off >>= 1) dsum += __shfl_xor(dsum, off);
  const float w = p * (1.0f / dsum); // fold 1/sum into the weights

  // gather: issue all 32 row loads before consuming any (32 outstanding)
  const uint* hb2 = h2 + (size_t)b * NN * 64;
  uint tmp[TOPK];
#pragma unroll
  for (int k = 0; k < TOPK; k++) {
    const int jk = __shfl(j, k); // wave-uniform broadcast (readlane)
    tmp[k] = hb2[(size_t)jk * 64 + lane];
  }
  float acc0 = 0.f, acc1 = 0.f;
#pragma unroll
  for (int k = 0; k < TOPK; k++) {
    const float ak = __shfl(w, k);
    const uint u = tmp[k];
    acc0 += ak * __uint_as_float(u << 16);          // col 2*lane
    acc1 += ak * __uint_as_float(u & 0xffff0000u);  // col 2*lane+1
  }
  acc0 = acc0 > 0.f ? acc0 : 0.f;
  acc1 = acc1 > 0.f ? acc1 : 0.f;
  const float2 lw = *(const float2*)&lin_W[2 * lane];
  float r = acc0 * lw.x + acc1 * lw.y;
#pragma unroll
  for (int off = 32; off > 0; off >>= 1) r += __shfl_xor(r, off);
  if (lane == 0) y[(size_t)b * NN + n] = r + lin_b[0];
}

// ---------------------------------------------------------------------------
extern "C" void kernel_launch(void* const* d_in, const int* in_sizes, int n_in,
                              void* d_out, int out_size, void* d_ws,
                              size_t ws_size, hipStream_t stream) {
  const float* x = (const float*)d_in[0];
  const float* emb = (const float*)d_in[1];
  const float* W_fe = (const float*)d_in[2];
  const float* a_src = (const float*)d_in[3];
  const float* a_dst = (const float*)d_in[4];
  const float* lin_W = (const float*)d_in[5];
  const float* lin_b = (const float*)d_in[6];
  float* y = (float*)d_out;

  char* ws = (char*)d_ws;
  float* u_src = (float*)(ws + 0);
  float* u_dst = (float*)(ws + 4096);
  int* idx = (int*)(ws + 16384);                        // 128 KB
  float* es = (float*)(ws + 16384 + 131072);            // 256 KB
  float* ed = (float*)(ws + 16384 + 131072 + 262144);   // 256 KB
  uint* h2 = (uint*)(ws + 16384 + 131072 + 2 * 262144); // 16 MB (bf16 pairs)

  k2_topk<<<NN / 4, 256, 0, stream>>>(emb, idx);
  k1_node_pre<<<NN / 4, 256, 0, stream>>>(emb, a_src, a_dst, u_src, u_dst);
  k3_feat<<<(BB * NN) / 64, 256, 0, stream>>>(x, W_fe, a_src, a_dst, u_src,
                                              u_dst, h2, es, ed);
  k4_attn<<<(BB * NN) / 4, 256, 0, stream>>>(h2, es, ed, idx, lin_W, lin_b, y);
}

// Round 3
// 188.043 us; speedup vs baseline: 1.1888x; 1.0976x over previous
//
#include <hip/hip_runtime.h>
#include <math.h>

#define BB 64
#define NN 1024
#define F_IN 64
#define EE 128
#define TOPK 32
#define NEG_SLOPE 0.2f

typedef unsigned int uint;

// pack float -> bf16 (round-to-nearest-even)
static __device__ __forceinline__ uint f2bf(float f) {
  const uint x = __float_as_uint(f);
  return (x + 0x7fffu + ((x >> 16) & 1u)) >> 16;
}
static __device__ __forceinline__ float bf_lo(uint u) {
  return __uint_as_float(u << 16);
}
static __device__ __forceinline__ float bf_hi(uint u) {
  return __uint_as_float(u & 0xffff0000u);
}

// ---------------------------------------------------------------------------
// K1: emb-side attention terms:
//   u_src[n] = emb[n] . a_src[E:2E],  u_dst[n] = emb[n] . a_dst[E:2E]
// ---------------------------------------------------------------------------
__global__ __launch_bounds__(256) void k1_node_pre(
    const float* __restrict__ emb, const float* __restrict__ a_src,
    const float* __restrict__ a_dst, float* __restrict__ u_src,
    float* __restrict__ u_dst) {
  const int wid = threadIdx.x >> 6;
  const int lane = threadIdx.x & 63;
  const int n = blockIdx.x * 4 + wid;
  const float* er = emb + (size_t)n * EE;
  const float e0 = er[lane], e1 = er[lane + 64];
  float us = e0 * a_src[EE + lane] + e1 * a_src[EE + lane + 64];
  float ud = e0 * a_dst[EE + lane] + e1 * a_dst[EE + lane + 64];
#pragma unroll
  for (int off = 32; off > 0; off >>= 1) {
    us += __shfl_xor(us, off);
    ud += __shfl_xor(ud, off);
  }
  if (lane == 0) {
    u_src[n] = us;
    u_dst[n] = ud;
  }
}

// ---------------------------------------------------------------------------
// K2: top-32 by cosine similarity. Rank key: dot(emb_i,emb_j)/||emb_j||
// (row factor 1/||emb_i|| is a positive constant -> order-invariant).
// fp32 throughout: top-k SET membership must match the fp32 reference.
// ---------------------------------------------------------------------------
__global__ __launch_bounds__(256) void k2_topk(const float* __restrict__ emb,
                                               int* __restrict__ idx_out) {
  __shared__ __align__(16) float embi[4][EE];   // 2 KB
  __shared__ __align__(16) float simlds[4][NN]; // 16 KB
  const int t = threadIdx.x;
  const int i0 = blockIdx.x * 4;

  for (int f = t; f < 4 * EE; f += 256) {
    const int ii = f >> 7, d = f & 127;
    embi[ii][d] = emb[(size_t)(i0 + ii) * EE + d];
  }
  __syncthreads();

  float acc[4][4];
  float sq[4];
#pragma unroll
  for (int q = 0; q < 4; q++) {
    sq[q] = 0.f;
#pragma unroll
    for (int ii = 0; ii < 4; ii++) acc[ii][q] = 0.f;
  }

#pragma unroll 2
  for (int d = 0; d < EE; d += 4) {
    float4 ei[4];
#pragma unroll
    for (int ii = 0; ii < 4; ii++) ei[ii] = *(const float4*)&embi[ii][d];
#pragma unroll
    for (int q = 0; q < 4; q++) {
      const int j = q * 256 + t;
      const float4 ej = *(const float4*)&emb[(size_t)j * EE + d];
      sq[q] += ej.x * ej.x + ej.y * ej.y + ej.z * ej.z + ej.w * ej.w;
#pragma unroll
      for (int ii = 0; ii < 4; ii++) {
        acc[ii][q] += ej.x * ei[ii].x + ej.y * ei[ii].y + ej.z * ei[ii].z +
                      ej.w * ei[ii].w;
      }
    }
  }
#pragma unroll
  for (int q = 0; q < 4; q++) {
    const int j = q * 256 + t;
    const float r = rsqrtf(sq[q]);
#pragma unroll
    for (int ii = 0; ii < 4; ii++) simlds[ii][j] = acc[ii][q] * r;
  }
  __syncthreads();

  // selection: wave wid selects top-32 for row i0+wid
  const int wid = t >> 6, lane = t & 63;
  unsigned long long keys[16];
#pragma unroll
  for (int q = 0; q < 16; q++) {
    const int j = q * 64 + lane;
    const float v = simlds[wid][j];
    uint u = __float_as_uint(v);
    u = (u & 0x80000000u) ? ~u : (u | 0x80000000u); // monotone float->uint
    keys[q] = ((unsigned long long)u << 32) | (uint)j;
  }
  int* row_out = idx_out + (size_t)(i0 + wid) * TOPK;
  for (int s = 0; s < TOPK; s++) {
    unsigned long long m = keys[0];
#pragma unroll
    for (int q = 1; q < 16; q++) m = keys[q] > m ? keys[q] : m;
#pragma unroll
    for (int off = 32; off > 0; off >>= 1) {
      const unsigned long long o = __shfl_xor(m, off);
      m = o > m ? o : m;
    }
    const uint j = (uint)m;
    if (lane == 0) row_out[s] = (int)j;
    const int jq = (int)(j >> 6), jl = (int)(j & 63);
    if (jl == lane) {
#pragma unroll
      for (int q = 0; q < 16; q++)
        if (q == jq) keys[q] = 0ull;
    }
  }
}

// ---------------------------------------------------------------------------
// K3: h = x @ W_fe  (65536 x 64 x 128) + fused e_s/e_d row dots.
// h stored as packed bf16 pairs (uint per col-pair) -> halves K4 gather bytes.
// e_s/e_d computed from fp32 accumulators (pre-quantization).
// ---------------------------------------------------------------------------
__global__ __launch_bounds__(256) void k3_feat(
    const float* __restrict__ x, const float* __restrict__ W_fe,
    const float* __restrict__ a_src, const float* __restrict__ a_dst,
    const float* __restrict__ u_src, const float* __restrict__ u_dst,
    uint* __restrict__ h2, float* __restrict__ es, float* __restrict__ ed) {
  __shared__ __align__(16) float Wl[F_IN * EE]; // 32 KB
  __shared__ __align__(16) float xT[F_IN][68];  // 17.4 KB
  const int t = threadIdx.x;
  const int row0 = blockIdx.x * 64;

  for (int f4 = t; f4 < (F_IN * EE) / 4; f4 += 256)
    *(float4*)&Wl[f4 * 4] = *(const float4*)&W_fe[f4 * 4];
  for (int f4 = t; f4 < (64 * F_IN) / 4; f4 += 256) {
    const float4 v = *(const float4*)&x[(size_t)row0 * F_IN + (size_t)f4 * 4];
    const int r = f4 >> 4;
    const int k0 = (f4 & 15) * 4;
    xT[k0 + 0][r] = v.x;
    xT[k0 + 1][r] = v.y;
    xT[k0 + 2][r] = v.z;
    xT[k0 + 3][r] = v.w;
  }
  __syncthreads();

  const int wid = t >> 6, lane = t & 63;
  const int r0 = wid * 16;
  float acc0[16], acc1[16];
#pragma unroll
  for (int r = 0; r < 16; r++) {
    acc0[r] = 0.f;
    acc1[r] = 0.f;
  }
#pragma unroll 4
  for (int k = 0; k < F_IN; k++) {
    const float2 w2 = *(const float2*)&Wl[k * EE + 2 * lane];
    float xv[16];
    *(float4*)&xv[0] = *(const float4*)&xT[k][r0 + 0];
    *(float4*)&xv[4] = *(const float4*)&xT[k][r0 + 4];
    *(float4*)&xv[8] = *(const float4*)&xT[k][r0 + 8];
    *(float4*)&xv[12] = *(const float4*)&xT[k][r0 + 12];
#pragma unroll
    for (int r = 0; r < 16; r++) {
      acc0[r] += xv[r] * w2.x;
      acc1[r] += xv[r] * w2.y;
    }
  }
  const float2 as2 = *(const float2*)&a_src[2 * lane];
  const float2 ad2 = *(const float2*)&a_dst[2 * lane];
#pragma unroll
  for (int r = 0; r < 16; r++) {
    const int row = row0 + r0 + r;
    const float h0 = acc0[r], h1 = acc1[r];
    h2[(size_t)row * 64 + lane] = f2bf(h0) | (f2bf(h1) << 16);
    float ps = h0 * as2.x + h1 * as2.y;
    float pd = h0 * ad2.x + h1 * ad2.y;
#pragma unroll
    for (int off = 32; off > 0; off >>= 1) {
      ps += __shfl_xor(ps, off);
      pd += __shfl_xor(pd, off);
    }
    if (lane == 0) {
      const int n = row & (NN - 1);
      es[row] = ps + u_src[n];
      ed[row] = pd + u_dst[n];
    }
  }
}

// ---------------------------------------------------------------------------
// K4: per-(b,n) wave attention. XCD swizzle keeps 8 b-slabs (2 MB bf16)
// per XCD-L2. Gather restructured: lane l reads uint4 (8 bf16 cols) of row
// j[4k + (l>>4)] -> 4 rows per load instruction, 8 loads/wave total, all
// hoistable into flight (32 payload VGPRs). Cross-sub-group reduction via
// shfl_xor(16/32); relu -> lin_W dot -> shfl_xor(1,2,4,8).
// ---------------------------------------------------------------------------
__global__ __launch_bounds__(256) void k4_attn(
    const uint* __restrict__ h2, const float* __restrict__ es,
    const float* __restrict__ ed, const int* __restrict__ idx,
    const float* __restrict__ lin_W, const float* __restrict__ lin_b,
    float* __restrict__ y) {
  const int t = threadIdx.x, wid = t >> 6, lane = t & 63;
  const int blk = blockIdx.x;
  const int b = (blk & 7) * 8 + ((blk >> 3) >> 8);
  const int n = ((blk >> 3) & 255) * 4 + wid;

  const float esv = es[(size_t)b * NN + n];
  const float* edb = ed + (size_t)b * NN;
  float sv = -INFINITY;
  int j = 0;
  if (lane < TOPK) {
    j = idx[n * TOPK + lane];
    const float s = esv + edb[j];
    sv = s > 0.f ? s : NEG_SLOPE * s;
  }
  float m = sv;
#pragma unroll
  for (int off = 32; off > 0; off >>= 1) {
    const float o = __shfl_xor(m, off);
    m = o > m ? o : m;
  }
  const float p = (lane < TOPK) ? __expf(sv - m) : 0.f;
  float dsum = p;
#pragma unroll
  for (int off = 32; off > 0; off >>= 1) dsum += __shfl_xor(dsum, off);
  const float w = p * (1.0f / dsum); // fold 1/sum into the weights

  // gather: lane l covers cols c16*8..c16*8+7 of row j[4k+sub]
  const int sub = lane >> 4;  // 0..3
  const int c16 = lane & 15;  // 0..15
  const uint* hb2 = h2 + (size_t)b * NN * 64;

  uint4 tv[8];
  float wr[8];
#pragma unroll
  for (int k = 0; k < 8; k++) {
    const int r = 4 * k + sub;
    const int jk = __shfl(j, r); // per-lane index -> ds_bpermute
    wr[k] = __shfl(w, r);
    tv[k] = *(const uint4*)&hb2[(size_t)jk * 64 + c16 * 4];
  }
  float acc[8];
#pragma unroll
  for (int i = 0; i < 8; i++) acc[i] = 0.f;
#pragma unroll
  for (int k = 0; k < 8; k++) {
    const float ak = wr[k];
    const uint4 u = tv[k];
    acc[0] += ak * bf_lo(u.x);
    acc[1] += ak * bf_hi(u.x);
    acc[2] += ak * bf_lo(u.y);
    acc[3] += ak * bf_hi(u.y);
    acc[4] += ak * bf_lo(u.z);
    acc[5] += ak * bf_hi(u.z);
    acc[6] += ak * bf_lo(u.w);
    acc[7] += ak * bf_hi(u.w);
  }
  // sum the 4 sub-groups (rows 4k+0..3), then relu
#pragma unroll
  for (int i = 0; i < 8; i++) {
    acc[i] += __shfl_xor(acc[i], 16);
    acc[i] += __shfl_xor(acc[i], 32);
    acc[i] = acc[i] > 0.f ? acc[i] : 0.f;
  }
  const float4 lw0 = *(const float4*)&lin_W[c16 * 8];
  const float4 lw1 = *(const float4*)&lin_W[c16 * 8 + 4];
  float r = acc[0] * lw0.x + acc[1] * lw0.y + acc[2] * lw0.z +
            acc[3] * lw0.w + acc[4] * lw1.x + acc[5] * lw1.y +
            acc[6] * lw1.z + acc[7] * lw1.w;
#pragma unroll
  for (int off = 8; off > 0; off >>= 1) r += __shfl_xor(r, off);
  if (lane == 0) y[(size_t)b * NN + n] = r + lin_b[0];
}

// ---------------------------------------------------------------------------
extern "C" void kernel_launch(void* const* d_in, const int* in_sizes, int n_in,
                              void* d_out, int out_size, void* d_ws,
                              size_t ws_size, hipStream_t stream) {
  const float* x = (const float*)d_in[0];
  const float* emb = (const float*)d_in[1];
  const float* W_fe = (const float*)d_in[2];
  const float* a_src = (const float*)d_in[3];
  const float* a_dst = (const float*)d_in[4];
  const float* lin_W = (const float*)d_in[5];
  const float* lin_b = (const float*)d_in[6];
  float* y = (float*)d_out;

  char* ws = (char*)d_ws;
  float* u_src = (float*)(ws + 0);
  float* u_dst = (float*)(ws + 4096);
  int* idx = (int*)(ws + 16384);                        // 128 KB
  float* es = (float*)(ws + 16384 + 131072);            // 256 KB
  float* ed = (float*)(ws + 16384 + 131072 + 262144);   // 256 KB
  uint* h2 = (uint*)(ws + 16384 + 131072 + 2 * 262144); // 16 MB (bf16 pairs)

  k2_topk<<<NN / 4, 256, 0, stream>>>(emb, idx);
  k1_node_pre<<<NN / 4, 256, 0, stream>>>(emb, a_src, a_dst, u_src, u_dst);
  k3_feat<<<(BB * NN) / 64, 256, 0, stream>>>(x, W_fe, a_src, a_dst, u_src,
                                              u_dst, h2, es, ed);
  k4_attn<<<(BB * NN) / 4, 256, 0, stream>>>(h2, es, ed, idx, lin_W, lin_b, y);
}

// Round 4
// 185.294 us; speedup vs baseline: 1.2064x; 1.0148x over previous
//
#include <hip/hip_runtime.h>
#include <math.h>

#define BB 64
#define NN 1024
#define F_IN 64
#define EE 128
#define TOPK 32
#define NEG_SLOPE 0.2f

typedef unsigned int uint;
typedef unsigned long long ull;

// pack float -> bf16 (round-to-nearest-even)
static __device__ __forceinline__ uint f2bf(float f) {
  const uint x = __float_as_uint(f);
  return (x + 0x7fffu + ((x >> 16) & 1u)) >> 16;
}
static __device__ __forceinline__ float bf_lo(uint u) {
  return __uint_as_float(u << 16);
}
static __device__ __forceinline__ float bf_hi(uint u) {
  return __uint_as_float(u & 0xffff0000u);
}
static __device__ __forceinline__ uint fmono(float f) {
  uint u = __float_as_uint(f);
  return (u & 0x80000000u) ? ~u : (u | 0x80000000u);
}
static __device__ __forceinline__ ull umax64(ull a, ull b) {
  return a > b ? a : b;
}
static __device__ __forceinline__ ull umin64(ull a, ull b) {
  return a < b ? a : b;
}

// ---------------------------------------------------------------------------
// K1: emb-side attention terms:
//   u_src[n] = emb[n] . a_src[E:2E],  u_dst[n] = emb[n] . a_dst[E:2E]
// ---------------------------------------------------------------------------
__global__ __launch_bounds__(256) void k1_node_pre(
    const float* __restrict__ emb, const float* __restrict__ a_src,
    const float* __restrict__ a_dst, float* __restrict__ u_src,
    float* __restrict__ u_dst) {
  const int wid = threadIdx.x >> 6;
  const int lane = threadIdx.x & 63;
  const int n = blockIdx.x * 4 + wid;
  const float* er = emb + (size_t)n * EE;
  const float e0 = er[lane], e1 = er[lane + 64];
  float us = e0 * a_src[EE + lane] + e1 * a_src[EE + lane + 64];
  float ud = e0 * a_dst[EE + lane] + e1 * a_dst[EE + lane + 64];
#pragma unroll
  for (int off = 32; off > 0; off >>= 1) {
    us += __shfl_xor(us, off);
    ud += __shfl_xor(ud, off);
  }
  if (lane == 0) {
    u_src[n] = us;
    u_dst[n] = ud;
  }
}

// ---------------------------------------------------------------------------
// K2a: similarity keys. key[i][j] = monotone_u32(dot(emb_i,emb_j)/||emb_j||)
// (row factor 1/||emb_i|| is positive -> rank-invariant). 4 rows/block for
// ej reuse; d-loop unrolled x4 for 16 outstanding loads.
// ---------------------------------------------------------------------------
__global__ __launch_bounds__(256) void k2a_sim(const float* __restrict__ emb,
                                               uint* __restrict__ keys) {
  __shared__ __align__(16) float embi[4][EE]; // 2 KB
  const int t = threadIdx.x;
  const int i0 = blockIdx.x * 4;

  for (int f = t; f < 4 * EE; f += 256) {
    const int ii = f >> 7, d = f & 127;
    embi[ii][d] = emb[(size_t)(i0 + ii) * EE + d];
  }
  __syncthreads();

  float acc[4][4];
  float sq[4];
#pragma unroll
  for (int q = 0; q < 4; q++) {
    sq[q] = 0.f;
#pragma unroll
    for (int ii = 0; ii < 4; ii++) acc[ii][q] = 0.f;
  }

#pragma unroll 4
  for (int d = 0; d < EE; d += 4) {
    float4 ei[4];
#pragma unroll
    for (int ii = 0; ii < 4; ii++) ei[ii] = *(const float4*)&embi[ii][d];
#pragma unroll
    for (int q = 0; q < 4; q++) {
      const int j = q * 256 + t;
      const float4 ej = *(const float4*)&emb[(size_t)j * EE + d];
      sq[q] += ej.x * ej.x + ej.y * ej.y + ej.z * ej.z + ej.w * ej.w;
#pragma unroll
      for (int ii = 0; ii < 4; ii++) {
        acc[ii][q] += ej.x * ei[ii].x + ej.y * ei[ii].y + ej.z * ei[ii].z +
                      ej.w * ei[ii].w;
      }
    }
  }
#pragma unroll
  for (int q = 0; q < 4; q++) {
    const int j = q * 256 + t;
    const float r = rsqrtf(sq[q]);
#pragma unroll
    for (int ii = 0; ii < 4; ii++)
      keys[(size_t)(i0 + ii) * NN + j] = fmono(acc[ii][q] * r);
  }
}

// ---------------------------------------------------------------------------
// K2b: top-32 selection, one row per block (1024 blocks -> 4 blocks/CU,
// 16 waves/CU). Each wave: 256 candidates (4/lane, sorted desc in regs),
// 32 x {butterfly-max of heads (u64), winner pops} -> local top-32 to LDS.
// Wave 0 then bitonic-sorts the 128 candidates (2/lane, 28 CE steps) and
// emits positions 0..31. u64 = (key32<<32)|j is unique -> no tie ambiguity.
// ---------------------------------------------------------------------------
__global__ __launch_bounds__(256) void k2b_sel(const uint* __restrict__ keys,
                                               int* __restrict__ idx_out) {
  __shared__ ull cand[128]; // 1 KB
  const int t = threadIdx.x, wid = t >> 6, lane = t & 63;
  const int row = blockIdx.x;

  const int jb = wid * 256 + lane * 4;
  const uint4 kv = *(const uint4*)&keys[(size_t)row * NN + jb];
  ull L0 = ((ull)kv.x << 32) | (uint)(jb + 0);
  ull L1 = ((ull)kv.y << 32) | (uint)(jb + 1);
  ull L2 = ((ull)kv.z << 32) | (uint)(jb + 2);
  ull L3 = ((ull)kv.w << 32) | (uint)(jb + 3);
  // sort 4 descending (L0 >= L1 >= L2 >= L3)
  {
    ull a, b;
    a = umax64(L0, L1); b = umin64(L0, L1); L0 = a; L1 = b;
    a = umax64(L2, L3); b = umin64(L2, L3); L2 = a; L3 = b;
    a = umax64(L0, L2); b = umin64(L0, L2); L0 = a; L2 = b;
    a = umax64(L1, L3); b = umin64(L1, L3); L1 = a; L3 = b;
    a = umax64(L1, L2); b = umin64(L1, L2); L1 = a; L2 = b;
  }
  for (int s = 0; s < TOPK; s++) {
    ull m = L0;
#pragma unroll
    for (int off = 32; off > 0; off >>= 1) {
      const ull o = __shfl_xor(m, off);
      m = o > m ? o : m;
    }
    if (lane == 0) cand[wid * TOPK + s] = m;
    const bool w = (L0 == m); // exactly one lane (u64 unique)
    L0 = w ? L1 : L0;
    L1 = w ? L2 : L1;
    L2 = w ? L3 : L2;
    L3 = w ? 0ull : L3;
  }
  __syncthreads();

  if (wid == 0) {
    ull k0 = cand[2 * lane];     // element m = 2*lane
    ull k1 = cand[2 * lane + 1]; // element m = 2*lane + 1
    // bitonic sort 128 descending
#pragma unroll
    for (int k = 2; k <= 128; k <<= 1) {
#pragma unroll
      for (int d = k >> 1; d > 0; d >>= 1) {
        if (d >= 2) {
          const int pl = d >> 1; // partner lane distance
          const ull o0 = __shfl_xor(k0, pl);
          const ull o1 = __shfl_xor(k1, pl);
          const bool keepmax =
              ((lane & (k >> 1)) == 0) == ((lane & pl) == 0);
          k0 = keepmax ? umax64(k0, o0) : umin64(k0, o0);
          k1 = keepmax ? umax64(k1, o1) : umin64(k1, o1);
        } else {
          const bool keepmax0 = ((lane & (k >> 1)) == 0);
          const ull hi = umax64(k0, k1), lo = umin64(k0, k1);
          k0 = keepmax0 ? hi : lo;
          k1 = keepmax0 ? lo : hi;
        }
      }
    }
    if (lane < 16) {
      int* ro = idx_out + (size_t)row * TOPK;
      ro[2 * lane] = (int)(k0 & 1023u);
      ro[2 * lane + 1] = (int)(k1 & 1023u);
    }
  }
}

// ---------------------------------------------------------------------------
// K3: h = x @ W_fe  (65536 x 64 x 128) + fused e_s/e_d row dots.
// h stored as packed bf16 pairs (uint per col-pair) -> halves K4 gather bytes.
// ---------------------------------------------------------------------------
__global__ __launch_bounds__(256) void k3_feat(
    const float* __restrict__ x, const float* __restrict__ W_fe,
    const float* __restrict__ a_src, const float* __restrict__ a_dst,
    const float* __restrict__ u_src, const float* __restrict__ u_dst,
    uint* __restrict__ h2, float* __restrict__ es, float* __restrict__ ed) {
  __shared__ __align__(16) float Wl[F_IN * EE]; // 32 KB
  __shared__ __align__(16) float xT[F_IN][68];  // 17.4 KB
  const int t = threadIdx.x;
  const int row0 = blockIdx.x * 64;

  for (int f4 = t; f4 < (F_IN * EE) / 4; f4 += 256)
    *(float4*)&Wl[f4 * 4] = *(const float4*)&W_fe[f4 * 4];
  for (int f4 = t; f4 < (64 * F_IN) / 4; f4 += 256) {
    const float4 v = *(const float4*)&x[(size_t)row0 * F_IN + (size_t)f4 * 4];
    const int r = f4 >> 4;
    const int k0 = (f4 & 15) * 4;
    xT[k0 + 0][r] = v.x;
    xT[k0 + 1][r] = v.y;
    xT[k0 + 2][r] = v.z;
    xT[k0 + 3][r] = v.w;
  }
  __syncthreads();

  const int wid = t >> 6, lane = t & 63;
  const int r0 = wid * 16;
  float acc0[16], acc1[16];
#pragma unroll
  for (int r = 0; r < 16; r++) {
    acc0[r] = 0.f;
    acc1[r] = 0.f;
  }
#pragma unroll 4
  for (int k = 0; k < F_IN; k++) {
    const float2 w2 = *(const float2*)&Wl[k * EE + 2 * lane];
    float xv[16];
    *(float4*)&xv[0] = *(const float4*)&xT[k][r0 + 0];
    *(float4*)&xv[4] = *(const float4*)&xT[k][r0 + 4];
    *(float4*)&xv[8] = *(const float4*)&xT[k][r0 + 8];
    *(float4*)&xv[12] = *(const float4*)&xT[k][r0 + 12];
#pragma unroll
    for (int r = 0; r < 16; r++) {
      acc0[r] += xv[r] * w2.x;
      acc1[r] += xv[r] * w2.y;
    }
  }
  const float2 as2 = *(const float2*)&a_src[2 * lane];
  const float2 ad2 = *(const float2*)&a_dst[2 * lane];
#pragma unroll
  for (int r = 0; r < 16; r++) {
    const int row = row0 + r0 + r;
    const float h0 = acc0[r], h1 = acc1[r];
    h2[(size_t)row * 64 + lane] = f2bf(h0) | (f2bf(h1) << 16);
    float ps = h0 * as2.x + h1 * as2.y;
    float pd = h0 * ad2.x + h1 * ad2.y;
#pragma unroll
    for (int off = 32; off > 0; off >>= 1) {
      ps += __shfl_xor(ps, off);
      pd += __shfl_xor(pd, off);
    }
    if (lane == 0) {
      const int n = row & (NN - 1);
      es[row] = ps + u_src[n];
      ed[row] = pd + u_dst[n];
    }
  }
}

// ---------------------------------------------------------------------------
// K4: per-(b,n) wave attention. XCD swizzle keeps 8 b-slabs (2 MB bf16)
// per XCD-L2. Lane l reads uint4 (8 bf16 cols) of row j[4k+(l>>4)]:
// 8 loads/wave, all in flight. shfl_xor(16/32) cross-sub reduce.
// ---------------------------------------------------------------------------
__global__ __launch_bounds__(256) void k4_attn(
    const uint* __restrict__ h2, const float* __restrict__ es,
    const float* __restrict__ ed, const int* __restrict__ idx,
    const float* __restrict__ lin_W, const float* __restrict__ lin_b,
    float* __restrict__ y) {
  const int t = threadIdx.x, wid = t >> 6, lane = t & 63;
  const int blk = blockIdx.x;
  const int b = (blk & 7) * 8 + ((blk >> 3) >> 8);
  const int n = ((blk >> 3) & 255) * 4 + wid;

  const float esv = es[(size_t)b * NN + n];
  const float* edb = ed + (size_t)b * NN;
  float sv = -INFINITY;
  int j = 0;
  if (lane < TOPK) {
    j = idx[n * TOPK + lane];
    const float s = esv + edb[j];
    sv = s > 0.f ? s : NEG_SLOPE * s;
  }
  float m = sv;
#pragma unroll
  for (int off = 32; off > 0; off >>= 1) {
    const float o = __shfl_xor(m, off);
    m = o > m ? o : m;
  }
  const float p = (lane < TOPK) ? __expf(sv - m) : 0.f;
  float dsum = p;
#pragma unroll
  for (int off = 32; off > 0; off >>= 1) dsum += __shfl_xor(dsum, off);
  const float w = p * (1.0f / dsum); // fold 1/sum into the weights

  // gather: lane l covers cols c16*8..c16*8+7 of row j[4k+sub]
  const int sub = lane >> 4;  // 0..3
  const int c16 = lane & 15;  // 0..15
  const uint* hb2 = h2 + (size_t)b * NN * 64;

  uint4 tv[8];
  float wr[8];
#pragma unroll
  for (int k = 0; k < 8; k++) {
    const int r = 4 * k + sub;
    const int jk = __shfl(j, r);
    wr[k] = __shfl(w, r);
    tv[k] = *(const uint4*)&hb2[(size_t)jk * 64 + c16 * 4];
  }
  float acc[8];
#pragma unroll
  for (int i = 0; i < 8; i++) acc[i] = 0.f;
#pragma unroll
  for (int k = 0; k < 8; k++) {
    const float ak = wr[k];
    const uint4 u = tv[k];
    acc[0] += ak * bf_lo(u.x);
    acc[1] += ak * bf_hi(u.x);
    acc[2] += ak * bf_lo(u.y);
    acc[3] += ak * bf_hi(u.y);
    acc[4] += ak * bf_lo(u.z);
    acc[5] += ak * bf_hi(u.z);
    acc[6] += ak * bf_lo(u.w);
    acc[7] += ak * bf_hi(u.w);
  }
#pragma unroll
  for (int i = 0; i < 8; i++) {
    acc[i] += __shfl_xor(acc[i], 16);
    acc[i] += __shfl_xor(acc[i], 32);
    acc[i] = acc[i] > 0.f ? acc[i] : 0.f;
  }
  const float4 lw0 = *(const float4*)&lin_W[c16 * 8];
  const float4 lw1 = *(const float4*)&lin_W[c16 * 8 + 4];
  float r = acc[0] * lw0.x + acc[1] * lw0.y + acc[2] * lw0.z +
            acc[3] * lw0.w + acc[4] * lw1.x + acc[5] * lw1.y +
            acc[6] * lw1.z + acc[7] * lw1.w;
#pragma unroll
  for (int off = 8; off > 0; off >>= 1) r += __shfl_xor(r, off);
  if (lane == 0) y[(size_t)b * NN + n] = r + lin_b[0];
}

// ---------------------------------------------------------------------------
extern "C" void kernel_launch(void* const* d_in, const int* in_sizes, int n_in,
                              void* d_out, int out_size, void* d_ws,
                              size_t ws_size, hipStream_t stream) {
  const float* x = (const float*)d_in[0];
  const float* emb = (const float*)d_in[1];
  const float* W_fe = (const float*)d_in[2];
  const float* a_src = (const float*)d_in[3];
  const float* a_dst = (const float*)d_in[4];
  const float* lin_W = (const float*)d_in[5];
  const float* lin_b = (const float*)d_in[6];
  float* y = (float*)d_out;

  char* ws = (char*)d_ws;
  float* u_src = (float*)(ws + 0);
  float* u_dst = (float*)(ws + 4096);
  int* idx = (int*)(ws + 16384);                        // 128 KB
  float* es = (float*)(ws + 16384 + 131072);            // 256 KB
  float* ed = (float*)(ws + 16384 + 131072 + 262144);   // 256 KB
  uint* h2 = (uint*)(ws + 16384 + 131072 + 2 * 262144); // 16 MB (bf16 pairs)
  uint* keys = (uint*)(ws + 16384 + 131072 + 2 * 262144 + 16777216); // 4 MB

  k2a_sim<<<NN / 4, 256, 0, stream>>>(emb, keys);
  k2b_sel<<<NN, 256, 0, stream>>>(keys, idx);
  k1_node_pre<<<NN / 4, 256, 0, stream>>>(emb, a_src, a_dst, u_src, u_dst);
  k3_feat<<<(BB * NN) / 64, 256, 0, stream>>>(x, W_fe, a_src, a_dst, u_src,
                                              u_dst, h2, es, ed);
  k4_attn<<<(BB * NN) / 4, 256, 0, stream>>>(h2, es, ed, idx, lin_W, lin_b, y);
}

// Round 5
// 181.315 us; speedup vs baseline: 1.2329x; 1.0219x over previous
//
#include <hip/hip_runtime.h>
#include <math.h>

#define BB 64
#define NN 1024
#define F_IN 64
#define EE 128
#define TOPK 32
#define NEG_SLOPE 0.2f

typedef unsigned int uint;
typedef unsigned long long ull;

// pack float -> bf16 (round-to-nearest-even)
static __device__ __forceinline__ uint f2bf(float f) {
  const uint x = __float_as_uint(f);
  return (x + 0x7fffu + ((x >> 16) & 1u)) >> 16;
}
static __device__ __forceinline__ float bf_lo(uint u) {
  return __uint_as_float(u << 16);
}
static __device__ __forceinline__ float bf_hi(uint u) {
  return __uint_as_float(u & 0xffff0000u);
}
static __device__ __forceinline__ uint fmono(float f) {
  uint u = __float_as_uint(f);
  return (u & 0x80000000u) ? ~u : (u | 0x80000000u);
}
static __device__ __forceinline__ ull umax64(ull a, ull b) {
  return a > b ? a : b;
}
static __device__ __forceinline__ ull umin64(ull a, ull b) {
  return a < b ? a : b;
}

// ---------------------------------------------------------------------------
// K1: per-node rn = 1/||emb||  +  u_src/u_dst = emb . a_*[E:2E]
// ---------------------------------------------------------------------------
__global__ __launch_bounds__(256) void k1_node_pre(
    const float* __restrict__ emb, const float* __restrict__ a_src,
    const float* __restrict__ a_dst, float* __restrict__ rn,
    float* __restrict__ u_src, float* __restrict__ u_dst) {
  const int wid = threadIdx.x >> 6;
  const int lane = threadIdx.x & 63;
  const int n = blockIdx.x * 4 + wid;
  const float* er = emb + (size_t)n * EE;
  const float e0 = er[lane], e1 = er[lane + 64];
  float ss = e0 * e0 + e1 * e1;
  float us = e0 * a_src[EE + lane] + e1 * a_src[EE + lane + 64];
  float ud = e0 * a_dst[EE + lane] + e1 * a_dst[EE + lane + 64];
#pragma unroll
  for (int off = 32; off > 0; off >>= 1) {
    ss += __shfl_xor(ss, off);
    us += __shfl_xor(us, off);
    ud += __shfl_xor(ud, off);
  }
  if (lane == 0) {
    rn[n] = 1.0f / sqrtf(ss);
    u_src[n] = us;
    u_dst[n] = ud;
  }
}

// ---------------------------------------------------------------------------
// K2a v2: sim keys via LDS-staged tiles (kills the divergent column gather).
// Block = 8 i-rows x 256 j-cols (grid 512 = 2 blocks/CU). j processed in 4
// chunks of 64: stage ej chunk coalesced (float4 rows -> stride-130 LDS),
// lane = j reads its row as b64 (4-way conflict = 1.58x, free-ish), ei rows
// read broadcast. key = fmono(dot * rn[j]) (row factor rank-invariant).
// ---------------------------------------------------------------------------
__global__ __launch_bounds__(256) void k2a_sim(const float* __restrict__ emb,
                                               const float* __restrict__ rn,
                                               uint* __restrict__ keys) {
  __shared__ float ei[8][130];  // 4.2 KB
  __shared__ float ej[64][130]; // 33.3 KB
  const int t = threadIdx.x, wid = t >> 6, lane = t & 63;
  const int i0 = (blockIdx.x >> 2) * 8;
  const int jbase = (blockIdx.x & 3) * 256;

  { // stage ei: 8 rows x 128 = 256 float4, one per thread (coalesced)
    const int r = t >> 5, c4 = t & 31;
    const float4 v = *(const float4*)&emb[(size_t)(i0 + r) * EE + c4 * 4];
    *(float2*)&ei[r][c4 * 4] = make_float2(v.x, v.y);
    *(float2*)&ei[r][c4 * 4 + 2] = make_float2(v.z, v.w);
  }

  const int ia = i0 + wid * 2; // this wave's two i-rows: ia, ia+1

  for (int ch = 0; ch < 4; ++ch) {
    const int j0 = jbase + ch * 64;
    // stage ej chunk: 64 rows x 128 = 2048 float4, 8 per thread (coalesced)
#pragma unroll
    for (int p = 0; p < 8; ++p) {
      const int g = p * 256 + t;
      const int r = g >> 5, c4 = g & 31;
      const float4 v = *(const float4*)&emb[(size_t)(j0 + r) * EE + c4 * 4];
      *(float2*)&ej[r][c4 * 4] = make_float2(v.x, v.y);
      *(float2*)&ej[r][c4 * 4 + 2] = make_float2(v.z, v.w);
    }
    __syncthreads(); // staging done (covers ei on ch==0)

    float a0 = 0.f, a1 = 0.f;
#pragma unroll 8
    for (int d2 = 0; d2 < 64; ++d2) {
      const float2 e = *(const float2*)&ej[lane][2 * d2];
      const float2 wa = *(const float2*)&ei[wid * 2][2 * d2];     // broadcast
      const float2 wb = *(const float2*)&ei[wid * 2 + 1][2 * d2]; // broadcast
      a0 += e.x * wa.x + e.y * wa.y;
      a1 += e.x * wb.x + e.y * wb.y;
    }
    const int jg = j0 + lane;
    const float rj = rn[jg];
    keys[(size_t)ia * NN + jg] = fmono(a0 * rj);
    keys[(size_t)(ia + 1) * NN + jg] = fmono(a1 * rj);
    __syncthreads(); // compute done before ej overwrite
  }
}

// ---------------------------------------------------------------------------
// K2b: top-32 selection, one row per block (1024 blocks). Each wave:
// 256 candidates (4/lane, reg-sorted), 32 x butterfly-argmax pop -> LDS.
// Wave 0 bitonic-sorts the 128 survivors, emits top-32.
// ---------------------------------------------------------------------------
__global__ __launch_bounds__(256) void k2b_sel(const uint* __restrict__ keys,
                                               int* __restrict__ idx_out) {
  __shared__ ull cand[128]; // 1 KB
  const int t = threadIdx.x, wid = t >> 6, lane = t & 63;
  const int row = blockIdx.x;

  const int jb = wid * 256 + lane * 4;
  const uint4 kv = *(const uint4*)&keys[(size_t)row * NN + jb];
  ull L0 = ((ull)kv.x << 32) | (uint)(jb + 0);
  ull L1 = ((ull)kv.y << 32) | (uint)(jb + 1);
  ull L2 = ((ull)kv.z << 32) | (uint)(jb + 2);
  ull L3 = ((ull)kv.w << 32) | (uint)(jb + 3);
  {
    ull a, b;
    a = umax64(L0, L1); b = umin64(L0, L1); L0 = a; L1 = b;
    a = umax64(L2, L3); b = umin64(L2, L3); L2 = a; L3 = b;
    a = umax64(L0, L2); b = umin64(L0, L2); L0 = a; L2 = b;
    a = umax64(L1, L3); b = umin64(L1, L3); L1 = a; L3 = b;
    a = umax64(L1, L2); b = umin64(L1, L2); L1 = a; L2 = b;
  }
  for (int s = 0; s < TOPK; s++) {
    ull m = L0;
#pragma unroll
    for (int off = 32; off > 0; off >>= 1) {
      const ull o = __shfl_xor(m, off);
      m = o > m ? o : m;
    }
    if (lane == 0) cand[wid * TOPK + s] = m;
    const bool w = (L0 == m);
    L0 = w ? L1 : L0;
    L1 = w ? L2 : L1;
    L2 = w ? L3 : L2;
    L3 = w ? 0ull : L3;
  }
  __syncthreads();

  if (wid == 0) {
    ull k0 = cand[2 * lane];
    ull k1 = cand[2 * lane + 1];
#pragma unroll
    for (int k = 2; k <= 128; k <<= 1) {
#pragma unroll
      for (int d = k >> 1; d > 0; d >>= 1) {
        if (d >= 2) {
          const int pl = d >> 1;
          const ull o0 = __shfl_xor(k0, pl);
          const ull o1 = __shfl_xor(k1, pl);
          const bool keepmax =
              ((lane & (k >> 1)) == 0) == ((lane & pl) == 0);
          k0 = keepmax ? umax64(k0, o0) : umin64(k0, o0);
          k1 = keepmax ? umax64(k1, o1) : umin64(k1, o1);
        } else {
          const bool keepmax0 = ((lane & (k >> 1)) == 0);
          const ull hi = umax64(k0, k1), lo = umin64(k0, k1);
          k0 = keepmax0 ? hi : lo;
          k1 = keepmax0 ? lo : hi;
        }
      }
    }
    if (lane < 16) {
      int* ro = idx_out + (size_t)row * TOPK;
      ro[2 * lane] = (int)(k0 & 1023u);
      ro[2 * lane + 1] = (int)(k1 & 1023u);
    }
  }
}

// ---------------------------------------------------------------------------
// K3: h = x @ W_fe (unchanged this round — diagnostic: its true duration
// will surface in next round's top-5).
// ---------------------------------------------------------------------------
__global__ __launch_bounds__(256) void k3_feat(
    const float* __restrict__ x, const float* __restrict__ W_fe,
    const float* __restrict__ a_src, const float* __restrict__ a_dst,
    const float* __restrict__ u_src, const float* __restrict__ u_dst,
    uint* __restrict__ h2, float* __restrict__ es, float* __restrict__ ed) {
  __shared__ __align__(16) float Wl[F_IN * EE]; // 32 KB
  __shared__ __align__(16) float xT[F_IN][68];  // 17.4 KB
  const int t = threadIdx.x;
  const int row0 = blockIdx.x * 64;

  for (int f4 = t; f4 < (F_IN * EE) / 4; f4 += 256)
    *(float4*)&Wl[f4 * 4] = *(const float4*)&W_fe[f4 * 4];
  for (int f4 = t; f4 < (64 * F_IN) / 4; f4 += 256) {
    const float4 v = *(const float4*)&x[(size_t)row0 * F_IN + (size_t)f4 * 4];
    const int r = f4 >> 4;
    const int k0 = (f4 & 15) * 4;
    xT[k0 + 0][r] = v.x;
    xT[k0 + 1][r] = v.y;
    xT[k0 + 2][r] = v.z;
    xT[k0 + 3][r] = v.w;
  }
  __syncthreads();

  const int wid = t >> 6, lane = t & 63;
  const int r0 = wid * 16;
  float acc0[16], acc1[16];
#pragma unroll
  for (int r = 0; r < 16; r++) {
    acc0[r] = 0.f;
    acc1[r] = 0.f;
  }
#pragma unroll 4
  for (int k = 0; k < F_IN; k++) {
    const float2 w2 = *(const float2*)&Wl[k * EE + 2 * lane];
    float xv[16];
    *(float4*)&xv[0] = *(const float4*)&xT[k][r0 + 0];
    *(float4*)&xv[4] = *(const float4*)&xT[k][r0 + 4];
    *(float4*)&xv[8] = *(const float4*)&xT[k][r0 + 8];
    *(float4*)&xv[12] = *(const float4*)&xT[k][r0 + 12];
#pragma unroll
    for (int r = 0; r < 16; r++) {
      acc0[r] += xv[r] * w2.x;
      acc1[r] += xv[r] * w2.y;
    }
  }
  const float2 as2 = *(const float2*)&a_src[2 * lane];
  const float2 ad2 = *(const float2*)&a_dst[2 * lane];
#pragma unroll
  for (int r = 0; r < 16; r++) {
    const int row = row0 + r0 + r;
    const float h0 = acc0[r], h1 = acc1[r];
    h2[(size_t)row * 64 + lane] = f2bf(h0) | (f2bf(h1) << 16);
    float ps = h0 * as2.x + h1 * as2.y;
    float pd = h0 * ad2.x + h1 * ad2.y;
#pragma unroll
    for (int off = 32; off > 0; off >>= 1) {
      ps += __shfl_xor(ps, off);
      pd += __shfl_xor(pd, off);
    }
    if (lane == 0) {
      const int n = row & (NN - 1);
      es[row] = ps + u_src[n];
      ed[row] = pd + u_dst[n];
    }
  }
}

// ---------------------------------------------------------------------------
// K4 v3: grid 4096, each wave processes 4 n's (hoisted lin_W/ed/h bases).
// Softmax without max-subtraction (scores bounded |s| <~ 6 -> exp safe,
// matches ref to fp32 rounding), 5-step 32-lane sum reduce. Gather: lane l
// reads uint4 (8 bf16 cols) of row j[4k+(l>>4)], 8 loads in flight.
// ---------------------------------------------------------------------------
__global__ __launch_bounds__(256) void k4_attn(
    const uint* __restrict__ h2, const float* __restrict__ es,
    const float* __restrict__ ed, const int* __restrict__ idx,
    const float* __restrict__ lin_W, const float* __restrict__ lin_b,
    float* __restrict__ y) {
  const int t = threadIdx.x, wid = t >> 6, lane = t & 63;
  const int blk = blockIdx.x;
  const int x = blk >> 3, xcd = blk & 7;
  const int b = xcd * 8 + (x >> 6);        // 8 b's per XCD -> L2-resident h
  const int nb = (x & 63) * 16 + wid * 4;  // 4 n's per wave

  const float* edb = ed + (size_t)b * NN;
  const float* esb = es + (size_t)b * NN;
  const uint* hb2 = h2 + (size_t)b * NN * 64;
  const int sub = lane >> 4;  // 0..3
  const int c16 = lane & 15;  // 0..15
  const float4 lw0 = *(const float4*)&lin_W[c16 * 8];
  const float4 lw1 = *(const float4*)&lin_W[c16 * 8 + 4];
  const float bias = lin_b[0];

#pragma unroll 1
  for (int q = 0; q < 4; ++q) {
    const int n = nb + q;
    const float esv = esb[n];
    float sv = 0.f;
    int j = 0;
    if (lane < TOPK) {
      j = idx[n * TOPK + lane];
      const float s = esv + edb[j];
      sv = s > 0.f ? s : NEG_SLOPE * s;
    }
    float p = (lane < TOPK) ? __expf(sv) : 0.f;
    float dsum = p;
#pragma unroll
    for (int off = 1; off <= 16; off <<= 1) dsum += __shfl_xor(dsum, off);
    const float w = p * (1.0f / dsum); // valid in lanes 0..31 (all we read)

    uint4 tv[8];
    float wr[8];
#pragma unroll
    for (int k = 0; k < 8; k++) {
      const int r = 4 * k + sub;
      const int jk = __shfl(j, r);
      wr[k] = __shfl(w, r);
      tv[k] = *(const uint4*)&hb2[(size_t)jk * 64 + c16 * 4];
    }
    float acc[8];
#pragma unroll
    for (int i = 0; i < 8; i++) acc[i] = 0.f;
#pragma unroll
    for (int k = 0; k < 8; k++) {
      const float ak = wr[k];
      const uint4 u = tv[k];
      acc[0] += ak * bf_lo(u.x);
      acc[1] += ak * bf_hi(u.x);
      acc[2] += ak * bf_lo(u.y);
      acc[3] += ak * bf_hi(u.y);
      acc[4] += ak * bf_lo(u.z);
      acc[5] += ak * bf_hi(u.z);
      acc[6] += ak * bf_lo(u.w);
      acc[7] += ak * bf_hi(u.w);
    }
#pragma unroll
    for (int i = 0; i < 8; i++) {
      acc[i] += __shfl_xor(acc[i], 16);
      acc[i] += __shfl_xor(acc[i], 32);
      acc[i] = acc[i] > 0.f ? acc[i] : 0.f;
    }
    float r = acc[0] * lw0.x + acc[1] * lw0.y + acc[2] * lw0.z +
              acc[3] * lw0.w + acc[4] * lw1.x + acc[5] * lw1.y +
              acc[6] * lw1.z + acc[7] * lw1.w;
#pragma unroll
    for (int off = 8; off > 0; off >>= 1) r += __shfl_xor(r, off);
    if (lane == 0) y[(size_t)b * NN + n] = r + bias;
  }
}

// ---------------------------------------------------------------------------
extern "C" void kernel_launch(void* const* d_in, const int* in_sizes, int n_in,
                              void* d_out, int out_size, void* d_ws,
                              size_t ws_size, hipStream_t stream) {
  const float* x = (const float*)d_in[0];
  const float* emb = (const float*)d_in[1];
  const float* W_fe = (const float*)d_in[2];
  const float* a_src = (const float*)d_in[3];
  const float* a_dst = (const float*)d_in[4];
  const float* lin_W = (const float*)d_in[5];
  const float* lin_b = (const float*)d_in[6];
  float* y = (float*)d_out;

  char* ws = (char*)d_ws;
  float* rn = (float*)(ws + 0);
  float* u_src = (float*)(ws + 4096);
  float* u_dst = (float*)(ws + 8192);
  int* idx = (int*)(ws + 16384);                        // 128 KB
  float* es = (float*)(ws + 16384 + 131072);            // 256 KB
  float* ed = (float*)(ws + 16384 + 131072 + 262144);   // 256 KB
  uint* h2 = (uint*)(ws + 16384 + 131072 + 2 * 262144); // 16 MB (bf16 pairs)
  uint* keys = (uint*)(ws + 16384 + 131072 + 2 * 262144 + 16777216); // 4 MB

  k1_node_pre<<<NN / 4, 256, 0, stream>>>(emb, a_src, a_dst, rn, u_src, u_dst);
  k2a_sim<<<512, 256, 0, stream>>>(emb, rn, keys);
  k2b_sel<<<NN, 256, 0, stream>>>(keys, idx);
  k3_feat<<<(BB * NN) / 64, 256, 0, stream>>>(x, W_fe, a_src, a_dst, u_src,
                                              u_dst, h2, es, ed);
  k4_attn<<<4096, 256, 0, stream>>>(h2, es, ed, idx, lin_W, lin_b, y);
}

// Round 6
// 180.330 us; speedup vs baseline: 1.2396x; 1.0055x over previous
//
#include <hip/hip_runtime.h>
#include <math.h>

#define BB 64
#define NN 1024
#define F_IN 64
#define EE 128
#define TOPK 32
#define NEG_SLOPE 0.2f

typedef unsigned int uint;
typedef unsigned long long ull;

// pack float -> bf16 (round-to-nearest-even)
static __device__ __forceinline__ uint f2bf(float f) {
  const uint x = __float_as_uint(f);
  return (x + 0x7fffu + ((x >> 16) & 1u)) >> 16;
}
static __device__ __forceinline__ float bf_lo(uint u) {
  return __uint_as_float(u << 16);
}
static __device__ __forceinline__ float bf_hi(uint u) {
  return __uint_as_float(u & 0xffff0000u);
}
static __device__ __forceinline__ uint fmono(float f) {
  uint u = __float_as_uint(f);
  return (u & 0x80000000u) ? ~u : (u | 0x80000000u);
}
static __device__ __forceinline__ ull umax64(ull a, ull b) {
  return a > b ? a : b;
}
static __device__ __forceinline__ ull umin64(ull a, ull b) {
  return a < b ? a : b;
}

// ---------------------------------------------------------------------------
// K2a v3: sim keys via LDS-staged tiles. rn folded inline (sq accumulated
// alongside the dots; rsqrtf). Block = 8 i-rows x 256 j-cols, grid 512.
// ---------------------------------------------------------------------------
__global__ __launch_bounds__(256) void k2a_sim(const float* __restrict__ emb,
                                               uint* __restrict__ keys) {
  __shared__ float ei[8][130];  // 4.2 KB
  __shared__ float ej[64][130]; // 33.3 KB
  const int t = threadIdx.x, wid = t >> 6, lane = t & 63;
  const int i0 = (blockIdx.x >> 2) * 8;
  const int jbase = (blockIdx.x & 3) * 256;

  { // stage ei: 8 rows x 128 = 256 float4, one per thread (coalesced)
    const int r = t >> 5, c4 = t & 31;
    const float4 v = *(const float4*)&emb[(size_t)(i0 + r) * EE + c4 * 4];
    *(float2*)&ei[r][c4 * 4] = make_float2(v.x, v.y);
    *(float2*)&ei[r][c4 * 4 + 2] = make_float2(v.z, v.w);
  }

  const int ia = i0 + wid * 2; // this wave's two i-rows: ia, ia+1

  for (int ch = 0; ch < 4; ++ch) {
    const int j0 = jbase + ch * 64;
#pragma unroll
    for (int p = 0; p < 8; ++p) {
      const int g = p * 256 + t;
      const int r = g >> 5, c4 = g & 31;
      const float4 v = *(const float4*)&emb[(size_t)(j0 + r) * EE + c4 * 4];
      *(float2*)&ej[r][c4 * 4] = make_float2(v.x, v.y);
      *(float2*)&ej[r][c4 * 4 + 2] = make_float2(v.z, v.w);
    }
    __syncthreads(); // staging done (covers ei on ch==0)

    float a0 = 0.f, a1 = 0.f, sq = 0.f;
#pragma unroll 8
    for (int d2 = 0; d2 < 64; ++d2) {
      const float2 e = *(const float2*)&ej[lane][2 * d2];
      const float2 wa = *(const float2*)&ei[wid * 2][2 * d2];     // broadcast
      const float2 wb = *(const float2*)&ei[wid * 2 + 1][2 * d2]; // broadcast
      a0 += e.x * wa.x + e.y * wa.y;
      a1 += e.x * wb.x + e.y * wb.y;
      sq += e.x * e.x + e.y * e.y;
    }
    const int jg = j0 + lane;
    const float rj = rsqrtf(sq);
    keys[(size_t)ia * NN + jg] = fmono(a0 * rj);
    keys[(size_t)(ia + 1) * NN + jg] = fmono(a1 * rj);
    __syncthreads(); // compute done before ej overwrite
  }
}

// ---------------------------------------------------------------------------
// K2b v2: top-32 selection, one row per block. Waves 0-3: 256 candidates
// each (4/lane reg-sorted, 32 x butterfly-argmax pop -> LDS). After the
// barrier: wave 0 bitonic-merges 128 survivors; wave 3 concurrently computes
// k1's u_src/u_dst for node `row` (fuses the old k1 kernel away).
// ---------------------------------------------------------------------------
__global__ __launch_bounds__(256) void k2b_sel(
    const uint* __restrict__ keys, const float* __restrict__ emb,
    const float* __restrict__ a_src, const float* __restrict__ a_dst,
    int* __restrict__ idx_out, float* __restrict__ u_src,
    float* __restrict__ u_dst) {
  __shared__ ull cand[128]; // 1 KB
  const int t = threadIdx.x, wid = t >> 6, lane = t & 63;
  const int row = blockIdx.x;

  const int jb = wid * 256 + lane * 4;
  const uint4 kv = *(const uint4*)&keys[(size_t)row * NN + jb];
  ull L0 = ((ull)kv.x << 32) | (uint)(jb + 0);
  ull L1 = ((ull)kv.y << 32) | (uint)(jb + 1);
  ull L2 = ((ull)kv.z << 32) | (uint)(jb + 2);
  ull L3 = ((ull)kv.w << 32) | (uint)(jb + 3);
  {
    ull a, b;
    a = umax64(L0, L1); b = umin64(L0, L1); L0 = a; L1 = b;
    a = umax64(L2, L3); b = umin64(L2, L3); L2 = a; L3 = b;
    a = umax64(L0, L2); b = umin64(L0, L2); L0 = a; L2 = b;
    a = umax64(L1, L3); b = umin64(L1, L3); L1 = a; L3 = b;
    a = umax64(L1, L2); b = umin64(L1, L2); L1 = a; L2 = b;
  }
  for (int s = 0; s < TOPK; s++) {
    ull m = L0;
#pragma unroll
    for (int off = 32; off > 0; off >>= 1) {
      const ull o = __shfl_xor(m, off);
      m = o > m ? o : m;
    }
    if (lane == 0) cand[wid * TOPK + s] = m;
    const bool w = (L0 == m);
    L0 = w ? L1 : L0;
    L1 = w ? L2 : L1;
    L2 = w ? L3 : L2;
    L3 = w ? 0ull : L3;
  }
  __syncthreads();

  if (wid == 0) {
    ull k0 = cand[2 * lane];
    ull k1 = cand[2 * lane + 1];
#pragma unroll
    for (int k = 2; k <= 128; k <<= 1) {
#pragma unroll
      for (int d = k >> 1; d > 0; d >>= 1) {
        if (d >= 2) {
          const int pl = d >> 1;
          const ull o0 = __shfl_xor(k0, pl);
          const ull o1 = __shfl_xor(k1, pl);
          const bool keepmax =
              ((lane & (k >> 1)) == 0) == ((lane & pl) == 0);
          k0 = keepmax ? umax64(k0, o0) : umin64(k0, o0);
          k1 = keepmax ? umax64(k1, o1) : umin64(k1, o1);
        } else {
          const bool keepmax0 = ((lane & (k >> 1)) == 0);
          const ull hi = umax64(k0, k1), lo = umin64(k0, k1);
          k0 = keepmax0 ? hi : lo;
          k1 = keepmax0 ? lo : hi;
        }
      }
    }
    if (lane < 16) {
      int* ro = idx_out + (size_t)row * TOPK;
      ro[2 * lane] = (int)(k0 & 1023u);
      ro[2 * lane + 1] = (int)(k1 & 1023u);
    }
  } else if (wid == 3) {
    // fused k1: u_src[row], u_dst[row]
    const float* er = emb + (size_t)row * EE;
    const float e0 = er[lane], e1 = er[lane + 64];
    float us = e0 * a_src[EE + lane] + e1 * a_src[EE + lane + 64];
    float ud = e0 * a_dst[EE + lane] + e1 * a_dst[EE + lane + 64];
#pragma unroll
    for (int off = 32; off > 0; off >>= 1) {
      us += __shfl_xor(us, off);
      ud += __shfl_xor(ud, off);
    }
    if (lane == 0) {
      u_src[row] = us;
      u_dst[row] = ud;
    }
  }
}

// ---------------------------------------------------------------------------
// K3: h = x @ W_fe (65536 x 64 x 128) + fused e_s/e_d row dots.
// h stored as packed bf16 pairs.
// ---------------------------------------------------------------------------
__global__ __launch_bounds__(256) void k3_feat(
    const float* __restrict__ x, const float* __restrict__ W_fe,
    const float* __restrict__ a_src, const float* __restrict__ a_dst,
    const float* __restrict__ u_src, const float* __restrict__ u_dst,
    uint* __restrict__ h2, float* __restrict__ es, float* __restrict__ ed) {
  __shared__ __align__(16) float Wl[F_IN * EE]; // 32 KB
  __shared__ __align__(16) float xT[F_IN][68];  // 17.4 KB
  const int t = threadIdx.x;
  const int row0 = blockIdx.x * 64;

  for (int f4 = t; f4 < (F_IN * EE) / 4; f4 += 256)
    *(float4*)&Wl[f4 * 4] = *(const float4*)&W_fe[f4 * 4];
  for (int f4 = t; f4 < (64 * F_IN) / 4; f4 += 256) {
    const float4 v = *(const float4*)&x[(size_t)row0 * F_IN + (size_t)f4 * 4];
    const int r = f4 >> 4;
    const int k0 = (f4 & 15) * 4;
    xT[k0 + 0][r] = v.x;
    xT[k0 + 1][r] = v.y;
    xT[k0 + 2][r] = v.z;
    xT[k0 + 3][r] = v.w;
  }
  __syncthreads();

  const int wid = t >> 6, lane = t & 63;
  const int r0 = wid * 16;
  float acc0[16], acc1[16];
#pragma unroll
  for (int r = 0; r < 16; r++) {
    acc0[r] = 0.f;
    acc1[r] = 0.f;
  }
#pragma unroll 4
  for (int k = 0; k < F_IN; k++) {
    const float2 w2 = *(const float2*)&Wl[k * EE + 2 * lane];
    float xv[16];
    *(float4*)&xv[0] = *(const float4*)&xT[k][r0 + 0];
    *(float4*)&xv[4] = *(const float4*)&xT[k][r0 + 4];
    *(float4*)&xv[8] = *(const float4*)&xT[k][r0 + 8];
    *(float4*)&xv[12] = *(const float4*)&xT[k][r0 + 12];
#pragma unroll
    for (int r = 0; r < 16; r++) {
      acc0[r] += xv[r] * w2.x;
      acc1[r] += xv[r] * w2.y;
    }
  }
  const float2 as2 = *(const float2*)&a_src[2 * lane];
  const float2 ad2 = *(const float2*)&a_dst[2 * lane];
#pragma unroll
  for (int r = 0; r < 16; r++) {
    const int row = row0 + r0 + r;
    const float h0 = acc0[r], h1 = acc1[r];
    h2[(size_t)row * 64 + lane] = f2bf(h0) | (f2bf(h1) << 16);
    float ps = h0 * as2.x + h1 * as2.y;
    float pd = h0 * ad2.x + h1 * ad2.y;
#pragma unroll
    for (int off = 32; off > 0; off >>= 1) {
      ps += __shfl_xor(ps, off);
      pd += __shfl_xor(pd, off);
    }
    if (lane == 0) {
      const int n = row & (NN - 1);
      es[row] = ps + u_src[n];
      ed[row] = pd + u_dst[n];
    }
  }
}

// ---------------------------------------------------------------------------
// K4 v4: zero dynamic shuffles. Per n: lanes 0..31 compute softmax weights
// and write (w_bits, byte_off) uint2 into a per-wave LDS buffer; all lanes
// then ds_read_b64 their (w, off) per k-group (4 distinct addrs -> broadcast,
// conflict-free). Gather: lane l reads uint4 (8 bf16 cols) of row j[4k+sub],
// 8 loads in flight. Static shfl_xor reduces only.
// ---------------------------------------------------------------------------
__global__ __launch_bounds__(256) void k4_attn(
    const uint* __restrict__ h2, const float* __restrict__ es,
    const float* __restrict__ ed, const int* __restrict__ idx,
    const float* __restrict__ lin_W, const float* __restrict__ lin_b,
    float* __restrict__ y) {
  __shared__ uint2 meta[4][TOPK]; // 1 KB
  const int t = threadIdx.x, wid = t >> 6, lane = t & 63;
  const int blk = blockIdx.x;
  const int x = blk >> 3, xcd = blk & 7;
  const int b = xcd * 8 + (x >> 6);        // 8 b's per XCD -> L2-resident h
  const int nb = (x & 63) * 16 + wid * 4;  // 4 n's per wave

  const float* edb = ed + (size_t)b * NN;
  const float* esb = es + (size_t)b * NN;
  const char* hb2 = (const char*)(h2 + (size_t)b * NN * 64);
  const int sub = lane >> 4;  // 0..3
  const int c16 = lane & 15;  // 0..15
  const float4 lw0 = *(const float4*)&lin_W[c16 * 8];
  const float4 lw1 = *(const float4*)&lin_W[c16 * 8 + 4];
  const float bias = lin_b[0];

#pragma unroll 2
  for (int q = 0; q < 4; ++q) {
    const int n = nb + q;
    const float esv = esb[n];
    float sv = 0.f;
    int j = 0;
    if (lane < TOPK) {
      j = idx[n * TOPK + lane];
      const float s = esv + edb[j];
      sv = s > 0.f ? s : NEG_SLOPE * s;
    }
    float p = (lane < TOPK) ? __expf(sv) : 0.f;
    float dsum = p;
#pragma unroll
    for (int off = 1; off <= 16; off <<= 1) dsum += __shfl_xor(dsum, off);
    if (lane < TOPK) {
      const float w = p * (1.0f / dsum);
      meta[wid][lane] = make_uint2(__float_as_uint(w), (uint)(j << 8));
    }
    // wave-private LDS RAW: compiler inserts lgkmcnt wait; no barrier needed
    uint4 tv[8];
    float wr[8];
#pragma unroll
    for (int k = 0; k < 8; k++) {
      const uint2 mw = meta[wid][4 * k + sub]; // 4 distinct addrs: broadcast
      wr[k] = __uint_as_float(mw.x);
      tv[k] = *(const uint4*)(hb2 + mw.y + c16 * 16);
    }
    float acc[8];
#pragma unroll
    for (int i = 0; i < 8; i++) acc[i] = 0.f;
#pragma unroll
    for (int k = 0; k < 8; k++) {
      const float ak = wr[k];
      const uint4 u = tv[k];
      acc[0] += ak * bf_lo(u.x);
      acc[1] += ak * bf_hi(u.x);
      acc[2] += ak * bf_lo(u.y);
      acc[3] += ak * bf_hi(u.y);
      acc[4] += ak * bf_lo(u.z);
      acc[5] += ak * bf_hi(u.z);
      acc[6] += ak * bf_lo(u.w);
      acc[7] += ak * bf_hi(u.w);
    }
#pragma unroll
    for (int i = 0; i < 8; i++) {
      acc[i] += __shfl_xor(acc[i], 16);
      acc[i] += __shfl_xor(acc[i], 32);
      acc[i] = acc[i] > 0.f ? acc[i] : 0.f;
    }
    float r = acc[0] * lw0.x + acc[1] * lw0.y + acc[2] * lw0.z +
              acc[3] * lw0.w + acc[4] * lw1.x + acc[5] * lw1.y +
              acc[6] * lw1.z + acc[7] * lw1.w;
#pragma unroll
    for (int off = 8; off > 0; off >>= 1) r += __shfl_xor(r, off);
    if (lane == 0) y[(size_t)b * NN + n] = r + bias;
  }
}

// ---------------------------------------------------------------------------
extern "C" void kernel_launch(void* const* d_in, const int* in_sizes, int n_in,
                              void* d_out, int out_size, void* d_ws,
                              size_t ws_size, hipStream_t stream) {
  const float* x = (const float*)d_in[0];
  const float* emb = (const float*)d_in[1];
  const float* W_fe = (const float*)d_in[2];
  const float* a_src = (const float*)d_in[3];
  const float* a_dst = (const float*)d_in[4];
  const float* lin_W = (const float*)d_in[5];
  const float* lin_b = (const float*)d_in[6];
  float* y = (float*)d_out;

  char* ws = (char*)d_ws;
  float* u_src = (float*)(ws + 4096);
  float* u_dst = (float*)(ws + 8192);
  int* idx = (int*)(ws + 16384);                        // 128 KB
  float* es = (float*)(ws + 16384 + 131072);            // 256 KB
  float* ed = (float*)(ws + 16384 + 131072 + 262144);   // 256 KB
  uint* h2 = (uint*)(ws + 16384 + 131072 + 2 * 262144); // 16 MB (bf16 pairs)
  uint* keys = (uint*)(ws + 16384 + 131072 + 2 * 262144 + 16777216); // 4 MB

  k2a_sim<<<512, 256, 0, stream>>>(emb, keys);
  k2b_sel<<<NN, 256, 0, stream>>>(keys, emb, a_src, a_dst, idx, u_src, u_dst);
  k3_feat<<<(BB * NN) / 64, 256, 0, stream>>>(x, W_fe, a_src, a_dst, u_src,
                                              u_dst, h2, es, ed);
  k4_attn<<<4096, 256, 0, stream>>>(h2, es, ed, idx, lin_W, lin_b, y);
}

// Round 7
// 174.644 us; speedup vs baseline: 1.2800x; 1.0326x over previous
//
#include <hip/hip_runtime.h>
#include <math.h>

#define BB 64
#define NN 1024
#define F_IN 64
#define EE 128
#define TOPK 32
#define NEG_SLOPE 0.2f

typedef unsigned int uint;
typedef unsigned long long ull;

// pack float -> bf16 (round-to-nearest-even)
static __device__ __forceinline__ uint f2bf(float f) {
  const uint x = __float_as_uint(f);
  return (x + 0x7fffu + ((x >> 16) & 1u)) >> 16;
}
static __device__ __forceinline__ float bf_lo(uint u) {
  return __uint_as_float(u << 16);
}
static __device__ __forceinline__ float bf_hi(uint u) {
  return __uint_as_float(u & 0xffff0000u);
}
static __device__ __forceinline__ uint fmono(float f) {
  uint u = __float_as_uint(f);
  return (u & 0x80000000u) ? ~u : (u | 0x80000000u);
}
static __device__ __forceinline__ ull umax64(ull a, ull b) {
  return a > b ? a : b;
}
static __device__ __forceinline__ ull umin64(ull a, ull b) {
  return a < b ? a : b;
}

// ---------------------------------------------------------------------------
// K2a v3: sim keys via LDS-staged tiles. rn folded inline (sq accumulated
// alongside the dots; rsqrtf). Block = 8 i-rows x 256 j-cols, grid 512.
// ---------------------------------------------------------------------------
__global__ __launch_bounds__(256) void k2a_sim(const float* __restrict__ emb,
                                               uint* __restrict__ keys) {
  __shared__ float ei[8][130];  // 4.2 KB
  __shared__ float ej[64][130]; // 33.3 KB
  const int t = threadIdx.x, wid = t >> 6, lane = t & 63;
  const int i0 = (blockIdx.x >> 2) * 8;
  const int jbase = (blockIdx.x & 3) * 256;

  { // stage ei: 8 rows x 128 = 256 float4, one per thread (coalesced)
    const int r = t >> 5, c4 = t & 31;
    const float4 v = *(const float4*)&emb[(size_t)(i0 + r) * EE + c4 * 4];
    *(float2*)&ei[r][c4 * 4] = make_float2(v.x, v.y);
    *(float2*)&ei[r][c4 * 4 + 2] = make_float2(v.z, v.w);
  }

  const int ia = i0 + wid * 2; // this wave's two i-rows: ia, ia+1

  for (int ch = 0; ch < 4; ++ch) {
    const int j0 = jbase + ch * 64;
#pragma unroll
    for (int p = 0; p < 8; ++p) {
      const int g = p * 256 + t;
      const int r = g >> 5, c4 = g & 31;
      const float4 v = *(const float4*)&emb[(size_t)(j0 + r) * EE + c4 * 4];
      *(float2*)&ej[r][c4 * 4] = make_float2(v.x, v.y);
      *(float2*)&ej[r][c4 * 4 + 2] = make_float2(v.z, v.w);
    }
    __syncthreads(); // staging done (covers ei on ch==0)

    float a0 = 0.f, a1 = 0.f, sq = 0.f;
#pragma unroll 8
    for (int d2 = 0; d2 < 64; ++d2) {
      const float2 e = *(const float2*)&ej[lane][2 * d2];
      const float2 wa = *(const float2*)&ei[wid * 2][2 * d2];     // broadcast
      const float2 wb = *(const float2*)&ei[wid * 2 + 1][2 * d2]; // broadcast
      a0 += e.x * wa.x + e.y * wa.y;
      a1 += e.x * wb.x + e.y * wb.y;
      sq += e.x * e.x + e.y * e.y;
    }
    const int jg = j0 + lane;
    const float rj = rsqrtf(sq);
    keys[(size_t)ia * NN + jg] = fmono(a0 * rj);
    keys[(size_t)(ia + 1) * NN + jg] = fmono(a1 * rj);
    __syncthreads(); // compute done before ej overwrite
  }
}

// ---------------------------------------------------------------------------
// K2b v2: top-32 selection, one row per block. Waves 0-3: 256 candidates
// each (4/lane reg-sorted, 32 x butterfly-argmax pop -> LDS). After the
// barrier: wave 0 bitonic-merges 128 survivors; wave 3 concurrently computes
// u_src/u_dst for node `row` (fused k1).
// ---------------------------------------------------------------------------
__global__ __launch_bounds__(256) void k2b_sel(
    const uint* __restrict__ keys, const float* __restrict__ emb,
    const float* __restrict__ a_src, const float* __restrict__ a_dst,
    int* __restrict__ idx_out, float* __restrict__ u_src,
    float* __restrict__ u_dst) {
  __shared__ ull cand[128]; // 1 KB
  const int t = threadIdx.x, wid = t >> 6, lane = t & 63;
  const int row = blockIdx.x;

  const int jb = wid * 256 + lane * 4;
  const uint4 kv = *(const uint4*)&keys[(size_t)row * NN + jb];
  ull L0 = ((ull)kv.x << 32) | (uint)(jb + 0);
  ull L1 = ((ull)kv.y << 32) | (uint)(jb + 1);
  ull L2 = ((ull)kv.z << 32) | (uint)(jb + 2);
  ull L3 = ((ull)kv.w << 32) | (uint)(jb + 3);
  {
    ull a, b;
    a = umax64(L0, L1); b = umin64(L0, L1); L0 = a; L1 = b;
    a = umax64(L2, L3); b = umin64(L2, L3); L2 = a; L3 = b;
    a = umax64(L0, L2); b = umin64(L0, L2); L0 = a; L2 = b;
    a = umax64(L1, L3); b = umin64(L1, L3); L1 = a; L3 = b;
    a = umax64(L1, L2); b = umin64(L1, L2); L1 = a; L2 = b;
  }
  for (int s = 0; s < TOPK; s++) {
    ull m = L0;
#pragma unroll
    for (int off = 32; off > 0; off >>= 1) {
      const ull o = __shfl_xor(m, off);
      m = o > m ? o : m;
    }
    if (lane == 0) cand[wid * TOPK + s] = m;
    const bool w = (L0 == m);
    L0 = w ? L1 : L0;
    L1 = w ? L2 : L1;
    L2 = w ? L3 : L2;
    L3 = w ? 0ull : L3;
  }
  __syncthreads();

  if (wid == 0) {
    ull k0 = cand[2 * lane];
    ull k1 = cand[2 * lane + 1];
#pragma unroll
    for (int k = 2; k <= 128; k <<= 1) {
#pragma unroll
      for (int d = k >> 1; d > 0; d >>= 1) {
        if (d >= 2) {
          const int pl = d >> 1;
          const ull o0 = __shfl_xor(k0, pl);
          const ull o1 = __shfl_xor(k1, pl);
          const bool keepmax =
              ((lane & (k >> 1)) == 0) == ((lane & pl) == 0);
          k0 = keepmax ? umax64(k0, o0) : umin64(k0, o0);
          k1 = keepmax ? umax64(k1, o1) : umin64(k1, o1);
        } else {
          const bool keepmax0 = ((lane & (k >> 1)) == 0);
          const ull hi = umax64(k0, k1), lo = umin64(k0, k1);
          k0 = keepmax0 ? hi : lo;
          k1 = keepmax0 ? lo : hi;
        }
      }
    }
    if (lane < 16) {
      int* ro = idx_out + (size_t)row * TOPK;
      ro[2 * lane] = (int)(k0 & 1023u);
      ro[2 * lane + 1] = (int)(k1 & 1023u);
    }
  } else if (wid == 3) {
    const float* er = emb + (size_t)row * EE;
    const float e0 = er[lane], e1 = er[lane + 64];
    float us = e0 * a_src[EE + lane] + e1 * a_src[EE + lane + 64];
    float ud = e0 * a_dst[EE + lane] + e1 * a_dst[EE + lane + 64];
#pragma unroll
    for (int off = 32; off > 0; off >>= 1) {
      us += __shfl_xor(us, off);
      ud += __shfl_xor(ud, off);
    }
    if (lane == 0) {
      u_src[row] = us;
      u_dst[row] = ud;
    }
  }
}

// ---------------------------------------------------------------------------
// K3: h = x @ W_fe (65536 x 64 x 128) + fused e_s/e_d row dots.
// h stored as packed bf16 pairs.
// ---------------------------------------------------------------------------
__global__ __launch_bounds__(256) void k3_feat(
    const float* __restrict__ x, const float* __restrict__ W_fe,
    const float* __restrict__ a_src, const float* __restrict__ a_dst,
    const float* __restrict__ u_src, const float* __restrict__ u_dst,
    uint* __restrict__ h2, float* __restrict__ es, float* __restrict__ ed) {
  __shared__ __align__(16) float Wl[F_IN * EE]; // 32 KB
  __shared__ __align__(16) float xT[F_IN][68];  // 17.4 KB
  const int t = threadIdx.x;
  const int row0 = blockIdx.x * 64;

  for (int f4 = t; f4 < (F_IN * EE) / 4; f4 += 256)
    *(float4*)&Wl[f4 * 4] = *(const float4*)&W_fe[f4 * 4];
  for (int f4 = t; f4 < (64 * F_IN) / 4; f4 += 256) {
    const float4 v = *(const float4*)&x[(size_t)row0 * F_IN + (size_t)f4 * 4];
    const int r = f4 >> 4;
    const int k0 = (f4 & 15) * 4;
    xT[k0 + 0][r] = v.x;
    xT[k0 + 1][r] = v.y;
    xT[k0 + 2][r] = v.z;
    xT[k0 + 3][r] = v.w;
  }
  __syncthreads();

  const int wid = t >> 6, lane = t & 63;
  const int r0 = wid * 16;
  float acc0[16], acc1[16];
#pragma unroll
  for (int r = 0; r < 16; r++) {
    acc0[r] = 0.f;
    acc1[r] = 0.f;
  }
#pragma unroll 4
  for (int k = 0; k < F_IN; k++) {
    const float2 w2 = *(const float2*)&Wl[k * EE + 2 * lane];
    float xv[16];
    *(float4*)&xv[0] = *(const float4*)&xT[k][r0 + 0];
    *(float4*)&xv[4] = *(const float4*)&xT[k][r0 + 4];
    *(float4*)&xv[8] = *(const float4*)&xT[k][r0 + 8];
    *(float4*)&xv[12] = *(const float4*)&xT[k][r0 + 12];
#pragma unroll
    for (int r = 0; r < 16; r++) {
      acc0[r] += xv[r] * w2.x;
      acc1[r] += xv[r] * w2.y;
    }
  }
  const float2 as2 = *(const float2*)&a_src[2 * lane];
  const float2 ad2 = *(const float2*)&a_dst[2 * lane];
#pragma unroll
  for (int r = 0; r < 16; r++) {
    const int row = row0 + r0 + r;
    const float h0 = acc0[r], h1 = acc1[r];
    h2[(size_t)row * 64 + lane] = f2bf(h0) | (f2bf(h1) << 16);
    float ps = h0 * as2.x + h1 * as2.y;
    float pd = h0 * ad2.x + h1 * ad2.y;
#pragma unroll
    for (int off = 32; off > 0; off >>= 1) {
      ps += __shfl_xor(ps, off);
      pd += __shfl_xor(pd, off);
    }
    if (lane == 0) {
      const int n = row & (NN - 1);
      es[row] = ps + u_src[n];
      ed[row] = pd + u_dst[n];
    }
  }
}

// ---------------------------------------------------------------------------
// K4 v5: half-wave per n (lanes 0-31 -> n, 32-63 -> n+1): softmax does 2 n's
// per instruction, no idle lanes. Gather offsets broadcast via ds_bpermute
// IMMEDIATELY after the idx load -> all 16 uint4 loads issue before the
// ed-gather/softmax chain runs (overlap); weights follow by a second
// bpermute. No LDS, no false deps; 4 independent iterations of 2 n's.
// Grid 2048: XCD swizzle keeps 8 b-slabs (2 MB bf16) per XCD-L2.
// ---------------------------------------------------------------------------
__global__ __launch_bounds__(256) void k4_attn(
    const uint* __restrict__ h2, const float* __restrict__ es,
    const float* __restrict__ ed, const int* __restrict__ idx,
    const float* __restrict__ lin_W, const float* __restrict__ lin_b,
    float* __restrict__ y) {
  const int t = threadIdx.x, wid = t >> 6, lane = t & 63;
  const int blk = blockIdx.x;
  const int xcd = blk & 7, x = blk >> 3;   // x: 0..255
  const int b = xcd * 8 + (x >> 5);        // 8 b's per XCD -> L2-resident h
  const int nb0 = (x & 31) * 32 + wid * 8; // 8 n's per wave

  const int half = lane >> 5, ll = lane & 31;
  const int sub2 = ll >> 4, c16 = ll & 15;
  const float* edb = ed + (size_t)b * NN;
  const float* esb = es + (size_t)b * NN;
  const char* hb = (const char*)(h2 + (size_t)b * NN * 64);
  const float4 lw0 = *(const float4*)&lin_W[c16 * 8];
  const float4 lw1 = *(const float4*)&lin_W[c16 * 8 + 4];
  const float bias = lin_b[0];
  const int pbase = half * 128 + sub2 * 4; // bpermute byte base

#pragma unroll 1
  for (int it = 0; it < 4; ++it) {
    const int nh = nb0 + it * 2 + half;
    const int j = idx[nh * TOPK + ll]; // one coalesced 64-lane load (2 rows)
    const int off = j << 8;            // byte offset of h-row (256 B)
    // broadcast row offsets to gather lanes (source lane: half*32+2k+sub2)
    int offk[16];
#pragma unroll
    for (int k = 0; k < 16; ++k)
      offk[k] = __builtin_amdgcn_ds_bpermute(pbase + k * 8, off);
    // issue all 16 row loads (1 KB each) before the softmax chain
    uint4 tv[16];
#pragma unroll
    for (int k = 0; k < 16; ++k)
      tv[k] = *(const uint4*)(hb + ((uint)offk[k] + c16 * 16));
    // softmax for this half's n (all 32 lanes active; overlaps gathers)
    const float esv = esb[nh];
    float s = esv + edb[j];
    s = s > 0.f ? s : NEG_SLOPE * s;
    const float p = __expf(s); // |s| <~ 6: safe without max-subtraction
    float dsum = p;
#pragma unroll
    for (int o = 1; o <= 16; o <<= 1) dsum += __shfl_xor(dsum, o);
    const float w = p * (1.0f / dsum);
    float wk[16];
#pragma unroll
    for (int k = 0; k < 16; ++k)
      wk[k] = __uint_as_float(
          __builtin_amdgcn_ds_bpermute(pbase + k * 8, __float_as_uint(w)));
    float acc[8];
#pragma unroll
    for (int i = 0; i < 8; i++) acc[i] = 0.f;
#pragma unroll
    for (int k = 0; k < 16; ++k) {
      const float ak = wk[k];
      const uint4 u = tv[k];
      acc[0] += ak * bf_lo(u.x);
      acc[1] += ak * bf_hi(u.x);
      acc[2] += ak * bf_lo(u.y);
      acc[3] += ak * bf_hi(u.y);
      acc[4] += ak * bf_lo(u.z);
      acc[5] += ak * bf_hi(u.z);
      acc[6] += ak * bf_lo(u.w);
      acc[7] += ak * bf_hi(u.w);
    }
    // sum the two sub-groups (within this half), relu
#pragma unroll
    for (int i = 0; i < 8; i++) {
      acc[i] += __shfl_xor(acc[i], 16);
      acc[i] = acc[i] > 0.f ? acc[i] : 0.f;
    }
    float r = acc[0] * lw0.x + acc[1] * lw0.y + acc[2] * lw0.z +
              acc[3] * lw0.w + acc[4] * lw1.x + acc[5] * lw1.y +
              acc[6] * lw1.z + acc[7] * lw1.w;
#pragma unroll
    for (int o = 8; o > 0; o >>= 1) r += __shfl_xor(r, o);
    if (ll == 0) y[(size_t)b * NN + nh] = r + bias; // lanes 0 and 32 store
  }
}

// ---------------------------------------------------------------------------
extern "C" void kernel_launch(void* const* d_in, const int* in_sizes, int n_in,
                              void* d_out, int out_size, void* d_ws,
                              size_t ws_size, hipStream_t stream) {
  const float* x = (const float*)d_in[0];
  const float* emb = (const float*)d_in[1];
  const float* W_fe = (const float*)d_in[2];
  const float* a_src = (const float*)d_in[3];
  const float* a_dst = (const float*)d_in[4];
  const float* lin_W = (const float*)d_in[5];
  const float* lin_b = (const float*)d_in[6];
  float* y = (float*)d_out;

  char* ws = (char*)d_ws;
  float* u_src = (float*)(ws + 4096);
  float* u_dst = (float*)(ws + 8192);
  int* idx = (int*)(ws + 16384);                        // 128 KB
  float* es = (float*)(ws + 16384 + 131072);            // 256 KB
  float* ed = (float*)(ws + 16384 + 131072 + 262144);   // 256 KB
  uint* h2 = (uint*)(ws + 16384 + 131072 + 2 * 262144); // 16 MB (bf16 pairs)
  uint* keys = (uint*)(ws + 16384 + 131072 + 2 * 262144 + 16777216); // 4 MB

  k2a_sim<<<512, 256, 0, stream>>>(emb, keys);
  k2b_sel<<<NN, 256, 0, stream>>>(keys, emb, a_src, a_dst, idx, u_src, u_dst);
  k3_feat<<<(BB * NN) / 64, 256, 0, stream>>>(x, W_fe, a_src, a_dst, u_src,
                                              u_dst, h2, es, ed);
  k4_attn<<<2048, 256, 0, stream>>>(h2, es, ed, idx, lin_W, lin_b, y);
}

// Round 8
// 169.263 us; speedup vs baseline: 1.3207x; 1.0318x over previous
//
#include <hip/hip_runtime.h>
#include <math.h>

#define BB 64
#define NN 1024
#define F_IN 64
#define EE 128
#define TOPK 32
#define NEG_SLOPE 0.2f

typedef unsigned int uint;
typedef unsigned long long ull;

// pack float -> bf16 (round-to-nearest-even)
static __device__ __forceinline__ uint f2bf(float f) {
  const uint x = __float_as_uint(f);
  return (x + 0x7fffu + ((x >> 16) & 1u)) >> 16;
}
static __device__ __forceinline__ float bf_lo(uint u) {
  return __uint_as_float(u << 16);
}
// hi bf16 WITHOUT masking: low 16 bits (the other column's bf16) act as
// extra mantissa garbage, rel err < 2^-7 -- inside the error budget.
static __device__ __forceinline__ float bf_hi_raw(uint u) {
  return __uint_as_float(u);
}
static __device__ __forceinline__ uint fmono(float f) {
  uint u = __float_as_uint(f);
  return (u & 0x80000000u) ? ~u : (u | 0x80000000u);
}
static __device__ __forceinline__ ull umax64(ull a, ull b) {
  return a > b ? a : b;
}
static __device__ __forceinline__ ull umin64(ull a, ull b) {
  return a < b ? a : b;
}

// ---------------------------------------------------------------------------
// K2a v3: sim keys via LDS-staged tiles. rn folded inline (sq accumulated
// alongside the dots; rsqrtf). Block = 8 i-rows x 256 j-cols, grid 512.
// ---------------------------------------------------------------------------
__global__ __launch_bounds__(256) void k2a_sim(const float* __restrict__ emb,
                                               uint* __restrict__ keys) {
  __shared__ float ei[8][130];  // 4.2 KB
  __shared__ float ej[64][130]; // 33.3 KB
  const int t = threadIdx.x, wid = t >> 6, lane = t & 63;
  const int i0 = (blockIdx.x >> 2) * 8;
  const int jbase = (blockIdx.x & 3) * 256;

  { // stage ei: 8 rows x 128 = 256 float4, one per thread (coalesced)
    const int r = t >> 5, c4 = t & 31;
    const float4 v = *(const float4*)&emb[(size_t)(i0 + r) * EE + c4 * 4];
    *(float2*)&ei[r][c4 * 4] = make_float2(v.x, v.y);
    *(float2*)&ei[r][c4 * 4 + 2] = make_float2(v.z, v.w);
  }

  const int ia = i0 + wid * 2; // this wave's two i-rows: ia, ia+1

  for (int ch = 0; ch < 4; ++ch) {
    const int j0 = jbase + ch * 64;
#pragma unroll
    for (int p = 0; p < 8; ++p) {
      const int g = p * 256 + t;
      const int r = g >> 5, c4 = g & 31;
      const float4 v = *(const float4*)&emb[(size_t)(j0 + r) * EE + c4 * 4];
      *(float2*)&ej[r][c4 * 4] = make_float2(v.x, v.y);
      *(float2*)&ej[r][c4 * 4 + 2] = make_float2(v.z, v.w);
    }
    __syncthreads(); // staging done (covers ei on ch==0)

    float a0 = 0.f, a1 = 0.f, sq = 0.f;
#pragma unroll 8
    for (int d2 = 0; d2 < 64; ++d2) {
      const float2 e = *(const float2*)&ej[lane][2 * d2];
      const float2 wa = *(const float2*)&ei[wid * 2][2 * d2];     // broadcast
      const float2 wb = *(const float2*)&ei[wid * 2 + 1][2 * d2]; // broadcast
      a0 += e.x * wa.x + e.y * wa.y;
      a1 += e.x * wb.x + e.y * wb.y;
      sq += e.x * e.x + e.y * e.y;
    }
    const int jg = j0 + lane;
    const float rj = rsqrtf(sq);
    keys[(size_t)ia * NN + jg] = fmono(a0 * rj);
    keys[(size_t)(ia + 1) * NN + jg] = fmono(a1 * rj);
    __syncthreads(); // compute done before ej overwrite
  }
}

// ---------------------------------------------------------------------------
// K2b v2: top-32 selection, one row per block. Waves 0-3: 256 candidates
// each (4/lane reg-sorted, 32 x butterfly-argmax pop -> LDS). After the
// barrier: wave 0 bitonic-merges 128 survivors; wave 3 concurrently computes
// u_src/u_dst for node `row` (fused k1).
// ---------------------------------------------------------------------------
__global__ __launch_bounds__(256) void k2b_sel(
    const uint* __restrict__ keys, const float* __restrict__ emb,
    const float* __restrict__ a_src, const float* __restrict__ a_dst,
    int* __restrict__ idx_out, float* __restrict__ u_src,
    float* __restrict__ u_dst) {
  __shared__ ull cand[128]; // 1 KB
  const int t = threadIdx.x, wid = t >> 6, lane = t & 63;
  const int row = blockIdx.x;

  const int jb = wid * 256 + lane * 4;
  const uint4 kv = *(const uint4*)&keys[(size_t)row * NN + jb];
  ull L0 = ((ull)kv.x << 32) | (uint)(jb + 0);
  ull L1 = ((ull)kv.y << 32) | (uint)(jb + 1);
  ull L2 = ((ull)kv.z << 32) | (uint)(jb + 2);
  ull L3 = ((ull)kv.w << 32) | (uint)(jb + 3);
  {
    ull a, b;
    a = umax64(L0, L1); b = umin64(L0, L1); L0 = a; L1 = b;
    a = umax64(L2, L3); b = umin64(L2, L3); L2 = a; L3 = b;
    a = umax64(L0, L2); b = umin64(L0, L2); L0 = a; L2 = b;
    a = umax64(L1, L3); b = umin64(L1, L3); L1 = a; L3 = b;
    a = umax64(L1, L2); b = umin64(L1, L2); L1 = a; L2 = b;
  }
  for (int s = 0; s < TOPK; s++) {
    ull m = L0;
#pragma unroll
    for (int off = 32; off > 0; off >>= 1) {
      const ull o = __shfl_xor(m, off);
      m = o > m ? o : m;
    }
    if (lane == 0) cand[wid * TOPK + s] = m;
    const bool w = (L0 == m);
    L0 = w ? L1 : L0;
    L1 = w ? L2 : L1;
    L2 = w ? L3 : L2;
    L3 = w ? 0ull : L3;
  }
  __syncthreads();

  if (wid == 0) {
    ull k0 = cand[2 * lane];
    ull k1 = cand[2 * lane + 1];
#pragma unroll
    for (int k = 2; k <= 128; k <<= 1) {
#pragma unroll
      for (int d = k >> 1; d > 0; d >>= 1) {
        if (d >= 2) {
          const int pl = d >> 1;
          const ull o0 = __shfl_xor(k0, pl);
          const ull o1 = __shfl_xor(k1, pl);
          const bool keepmax =
              ((lane & (k >> 1)) == 0) == ((lane & pl) == 0);
          k0 = keepmax ? umax64(k0, o0) : umin64(k0, o0);
          k1 = keepmax ? umax64(k1, o1) : umin64(k1, o1);
        } else {
          const bool keepmax0 = ((lane & (k >> 1)) == 0);
          const ull hi = umax64(k0, k1), lo = umin64(k0, k1);
          k0 = keepmax0 ? hi : lo;
          k1 = keepmax0 ? lo : hi;
        }
      }
    }
    if (lane < 16) {
      int* ro = idx_out + (size_t)row * TOPK;
      ro[2 * lane] = (int)(k0 & 1023u);
      ro[2 * lane + 1] = (int)(k1 & 1023u);
    }
  } else if (wid == 3) {
    const float* er = emb + (size_t)row * EE;
    const float e0 = er[lane], e1 = er[lane + 64];
    float us = e0 * a_src[EE + lane] + e1 * a_src[EE + lane + 64];
    float ud = e0 * a_dst[EE + lane] + e1 * a_dst[EE + lane + 64];
#pragma unroll
    for (int off = 32; off > 0; off >>= 1) {
      us += __shfl_xor(us, off);
      ud += __shfl_xor(ud, off);
    }
    if (lane == 0) {
      u_src[row] = us;
      u_dst[row] = ud;
    }
  }
}

// ---------------------------------------------------------------------------
// K3: h = x @ W_fe (65536 x 64 x 128) + fused e_s/e_d row dots.
// h stored as packed bf16 pairs.
// ---------------------------------------------------------------------------
__global__ __launch_bounds__(256) void k3_feat(
    const float* __restrict__ x, const float* __restrict__ W_fe,
    const float* __restrict__ a_src, const float* __restrict__ a_dst,
    const float* __restrict__ u_src, const float* __restrict__ u_dst,
    uint* __restrict__ h2, float* __restrict__ es, float* __restrict__ ed) {
  __shared__ __align__(16) float Wl[F_IN * EE]; // 32 KB
  __shared__ __align__(16) float xT[F_IN][68];  // 17.4 KB
  const int t = threadIdx.x;
  const int row0 = blockIdx.x * 64;

  for (int f4 = t; f4 < (F_IN * EE) / 4; f4 += 256)
    *(float4*)&Wl[f4 * 4] = *(const float4*)&W_fe[f4 * 4];
  for (int f4 = t; f4 < (64 * F_IN) / 4; f4 += 256) {
    const float4 v = *(const float4*)&x[(size_t)row0 * F_IN + (size_t)f4 * 4];
    const int r = f4 >> 4;
    const int k0 = (f4 & 15) * 4;
    xT[k0 + 0][r] = v.x;
    xT[k0 + 1][r] = v.y;
    xT[k0 + 2][r] = v.z;
    xT[k0 + 3][r] = v.w;
  }
  __syncthreads();

  const int wid = t >> 6, lane = t & 63;
  const int r0 = wid * 16;
  float acc0[16], acc1[16];
#pragma unroll
  for (int r = 0; r < 16; r++) {
    acc0[r] = 0.f;
    acc1[r] = 0.f;
  }
#pragma unroll 4
  for (int k = 0; k < F_IN; k++) {
    const float2 w2 = *(const float2*)&Wl[k * EE + 2 * lane];
    float xv[16];
    *(float4*)&xv[0] = *(const float4*)&xT[k][r0 + 0];
    *(float4*)&xv[4] = *(const float4*)&xT[k][r0 + 4];
    *(float4*)&xv[8] = *(const float4*)&xT[k][r0 + 8];
    *(float4*)&xv[12] = *(const float4*)&xT[k][r0 + 12];
#pragma unroll
    for (int r = 0; r < 16; r++) {
      acc0[r] += xv[r] * w2.x;
      acc1[r] += xv[r] * w2.y;
    }
  }
  const float2 as2 = *(const float2*)&a_src[2 * lane];
  const float2 ad2 = *(const float2*)&a_dst[2 * lane];
#pragma unroll
  for (int r = 0; r < 16; r++) {
    const int row = row0 + r0 + r;
    const float h0 = acc0[r], h1 = acc1[r];
    h2[(size_t)row * 64 + lane] = f2bf(h0) | (f2bf(h1) << 16);
    float ps = h0 * as2.x + h1 * as2.y;
    float pd = h0 * ad2.x + h1 * ad2.y;
#pragma unroll
    for (int off = 32; off > 0; off >>= 1) {
      ps += __shfl_xor(ps, off);
      pd += __shfl_xor(pd, off);
    }
    if (lane == 0) {
      const int n = row & (NN - 1);
      es[row] = ps + u_src[n];
      ed[row] = pd + u_dst[n];
    }
  }
}

// ---------------------------------------------------------------------------
// K4 v6: single-shot waves — 2 n's per wave (half-wave each), ONE iteration,
// grid 8192 -> 32k waves of pure TLP (no cross-iteration register
// serialization). Offsets broadcast via ds_bpermute right after the idx
// load; all 16 uint4 gathers issue before the softmax chain. hi-column
// accumulate uses the raw uint (garbage low mantissa, rel err < 2^-7):
// accumulate block is 192 instr/n instead of 256.
// ---------------------------------------------------------------------------
__global__ __launch_bounds__(256) void k4_attn(
    const uint* __restrict__ h2, const float* __restrict__ es,
    const float* __restrict__ ed, const int* __restrict__ idx,
    const float* __restrict__ lin_W, const float* __restrict__ lin_b,
    float* __restrict__ y) {
  const int t = threadIdx.x, wid = t >> 6, lane = t & 63;
  const int blk = blockIdx.x;
  const int xcd = blk & 7, x = blk >> 3;   // x: 0..1023
  const int b = xcd * 8 + (x >> 7);        // 8 b's per XCD -> L2-resident h
  const int half = lane >> 5, ll = lane & 31;
  const int nh = (x & 127) * 8 + wid * 2 + half; // this half-wave's n
  const int sub2 = ll >> 4, c16 = ll & 15;
  const int pbase = half * 128 + sub2 * 4; // bpermute byte base

  const float* edb = ed + (size_t)b * NN;
  const float* esb = es + (size_t)b * NN;
  const char* hb = (const char*)(h2 + (size_t)b * NN * 64);

  // idx load + offset broadcast + issue all 16 gathers (before softmax)
  const int j = idx[nh * TOPK + ll];
  const int off = j << 8; // byte offset of h-row (256 B)
  int offk[16];
#pragma unroll
  for (int k = 0; k < 16; ++k)
    offk[k] = __builtin_amdgcn_ds_bpermute(pbase + k * 8, off);
  uint4 tv[16];
#pragma unroll
  for (int k = 0; k < 16; ++k)
    tv[k] = *(const uint4*)(hb + ((uint)offk[k] + c16 * 16));

  // softmax for this half's n (runs while gathers are in flight)
  const float esv = esb[nh];
  float s = esv + edb[j];
  s = s > 0.f ? s : NEG_SLOPE * s;
  const float p = __expf(s); // |s| <~ 6: safe without max-subtraction
  float dsum = p;
#pragma unroll
  for (int o = 1; o <= 16; o <<= 1) dsum += __shfl_xor(dsum, o);
  const float w = p * (1.0f / dsum);
  float wk[16];
#pragma unroll
  for (int k = 0; k < 16; ++k)
    wk[k] = __uint_as_float(
        __builtin_amdgcn_ds_bpermute(pbase + k * 8, __float_as_uint(w)));

  const float4 lw0 = *(const float4*)&lin_W[c16 * 8];
  const float4 lw1 = *(const float4*)&lin_W[c16 * 8 + 4];
  const float bias = lin_b[0];

  float acc[8];
#pragma unroll
  for (int i = 0; i < 8; i++) acc[i] = 0.f;
#pragma unroll
  for (int k = 0; k < 16; ++k) {
    const float ak = wk[k];
    const uint4 u = tv[k];
    acc[0] += ak * bf_lo(u.x);
    acc[1] += ak * bf_hi_raw(u.x);
    acc[2] += ak * bf_lo(u.y);
    acc[3] += ak * bf_hi_raw(u.y);
    acc[4] += ak * bf_lo(u.z);
    acc[5] += ak * bf_hi_raw(u.z);
    acc[6] += ak * bf_lo(u.w);
    acc[7] += ak * bf_hi_raw(u.w);
  }
  // sum the two sub-groups (within this half), relu
#pragma unroll
  for (int i = 0; i < 8; i++) {
    acc[i] += __shfl_xor(acc[i], 16);
    acc[i] = acc[i] > 0.f ? acc[i] : 0.f;
  }
  float r = acc[0] * lw0.x + acc[1] * lw0.y + acc[2] * lw0.z + acc[3] * lw0.w +
            acc[4] * lw1.x + acc[5] * lw1.y + acc[6] * lw1.z + acc[7] * lw1.w;
#pragma unroll
  for (int o = 8; o > 0; o >>= 1) r += __shfl_xor(r, o);
  if (ll == 0) y[(size_t)b * NN + nh] = r + bias; // lanes 0 and 32 store
}

// ---------------------------------------------------------------------------
extern "C" void kernel_launch(void* const* d_in, const int* in_sizes, int n_in,
                              void* d_out, int out_size, void* d_ws,
                              size_t ws_size, hipStream_t stream) {
  const float* x = (const float*)d_in[0];
  const float* emb = (const float*)d_in[1];
  const float* W_fe = (const float*)d_in[2];
  const float* a_src = (const float*)d_in[3];
  const float* a_dst = (const float*)d_in[4];
  const float* lin_W = (const float*)d_in[5];
  const float* lin_b = (const float*)d_in[6];
  float* y = (float*)d_out;

  char* ws = (char*)d_ws;
  float* u_src = (float*)(ws + 4096);
  float* u_dst = (float*)(ws + 8192);
  int* idx = (int*)(ws + 16384);                        // 128 KB
  float* es = (float*)(ws + 16384 + 131072);            // 256 KB
  float* ed = (float*)(ws + 16384 + 131072 + 262144);   // 256 KB
  uint* h2 = (uint*)(ws + 16384 + 131072 + 2 * 262144); // 16 MB (bf16 pairs)
  uint* keys = (uint*)(ws + 16384 + 131072 + 2 * 262144 + 16777216); // 4 MB

  k2a_sim<<<512, 256, 0, stream>>>(emb, keys);
  k2b_sel<<<NN, 256, 0, stream>>>(keys, emb, a_src, a_dst, idx, u_src, u_dst);
  k3_feat<<<(BB * NN) / 64, 256, 0, stream>>>(x, W_fe, a_src, a_dst, u_src,
                                              u_dst, h2, es, ed);
  k4_attn<<<8192, 256, 0, stream>>>(h2, es, ed, idx, lin_W, lin_b, y);
}

// Round 9
// 160.523 us; speedup vs baseline: 1.3926x; 1.0544x over previous
//
#include <hip/hip_runtime.h>
#include <math.h>

#define BB 64
#define NN 1024
#define F_IN 64
#define EE 128
#define TOPK 32
#define NEG_SLOPE 0.2f

typedef unsigned int uint;
typedef unsigned long long ull;

// pack float -> bf16 (round-to-nearest-even)
static __device__ __forceinline__ uint f2bf(float f) {
  const uint x = __float_as_uint(f);
  return (x + 0x7fffu + ((x >> 16) & 1u)) >> 16;
}
static __device__ __forceinline__ float bf_lo(uint u) {
  return __uint_as_float(u << 16);
}
// hi bf16 WITHOUT masking: low 16 bits act as mantissa garbage, rel err <2^-7
static __device__ __forceinline__ float bf_hi_raw(uint u) {
  return __uint_as_float(u);
}
static __device__ __forceinline__ uint fmono(float f) {
  uint u = __float_as_uint(f);
  return (u & 0x80000000u) ? ~u : (u | 0x80000000u);
}
static __device__ __forceinline__ ull umax64(ull a, ull b) {
  return a > b ? a : b;
}
static __device__ __forceinline__ ull umin64(ull a, ull b) {
  return a < b ? a : b;
}

// ---------------------------------------------------------------------------
// K2a v4: sim keys via LDS-staged tiles + fused u_src/u_dst (one quarter of
// the blocks computes them from L2-hot emb rows, removing the k2b->k3 dep).
// Block = 8 i-rows x 256 j-cols, grid 512.
// ---------------------------------------------------------------------------
__global__ __launch_bounds__(256) void k2a_sim(
    const float* __restrict__ emb, const float* __restrict__ a_src,
    const float* __restrict__ a_dst, uint* __restrict__ keys,
    float* __restrict__ u_src, float* __restrict__ u_dst) {
  __shared__ float ei[8][130];  // 4.2 KB
  __shared__ float ej[64][130]; // 33.3 KB
  const int t = threadIdx.x, wid = t >> 6, lane = t & 63;
  const int i0 = (blockIdx.x >> 2) * 8;
  const int jbase = (blockIdx.x & 3) * 256;

  // fused k1: blocks with (blk&3)==0 compute u_src/u_dst for their 8 rows
  if ((blockIdx.x & 3) == 0) {
    const int row = i0 + 2 * wid + (lane >> 5); // half-wave per row
    const int ll = lane & 31;
    const float* er = emb + (size_t)row * EE;
    float us = 0.f, ud = 0.f;
#pragma unroll
    for (int c0 = 0; c0 < EE; c0 += 32) {
      const int c = c0 + ll;
      const float e = er[c];
      us += e * a_src[EE + c];
      ud += e * a_dst[EE + c];
    }
#pragma unroll
    for (int o = 1; o <= 16; o <<= 1) {
      us += __shfl_xor(us, o);
      ud += __shfl_xor(ud, o);
    }
    if (ll == 0) {
      u_src[row] = us;
      u_dst[row] = ud;
    }
  }

  { // stage ei: 8 rows x 128 = 256 float4, one per thread (coalesced)
    const int r = t >> 5, c4 = t & 31;
    const float4 v = *(const float4*)&emb[(size_t)(i0 + r) * EE + c4 * 4];
    *(float2*)&ei[r][c4 * 4] = make_float2(v.x, v.y);
    *(float2*)&ei[r][c4 * 4 + 2] = make_float2(v.z, v.w);
  }

  const int ia = i0 + wid * 2; // this wave's two i-rows: ia, ia+1

  for (int ch = 0; ch < 4; ++ch) {
    const int j0 = jbase + ch * 64;
#pragma unroll
    for (int p = 0; p < 8; ++p) {
      const int g = p * 256 + t;
      const int r = g >> 5, c4 = g & 31;
      const float4 v = *(const float4*)&emb[(size_t)(j0 + r) * EE + c4 * 4];
      *(float2*)&ej[r][c4 * 4] = make_float2(v.x, v.y);
      *(float2*)&ej[r][c4 * 4 + 2] = make_float2(v.z, v.w);
    }
    __syncthreads(); // staging done (covers ei on ch==0)

    float a0 = 0.f, a1 = 0.f, sq = 0.f;
#pragma unroll 8
    for (int d2 = 0; d2 < 64; ++d2) {
      const float2 e = *(const float2*)&ej[lane][2 * d2];
      const float2 wa = *(const float2*)&ei[wid * 2][2 * d2];     // broadcast
      const float2 wb = *(const float2*)&ei[wid * 2 + 1][2 * d2]; // broadcast
      a0 += e.x * wa.x + e.y * wa.y;
      a1 += e.x * wb.x + e.y * wb.y;
      sq += e.x * e.x + e.y * e.y;
    }
    const int jg = j0 + lane;
    const float rj = rsqrtf(sq);
    keys[(size_t)ia * NN + jg] = fmono(a0 * rj);
    keys[(size_t)(ia + 1) * NN + jg] = fmono(a1 * rj);
    __syncthreads(); // compute done before ej overwrite
  }
}

// ---------------------------------------------------------------------------
// K23: fused k2b (top-32 selection) + k3 (feature GEMM). Blocks [0,1024):
// selection for row=blk (shfl/latency-bound, low VALU). Blocks [1024,2048):
// h = x @ W_fe for 64 rows (VALU-bound). Complementary pipes co-schedule;
// one launch instead of two. LDS = union of both roles (49.4 KB).
// ---------------------------------------------------------------------------
__global__ __launch_bounds__(256) void k23(
    const uint* __restrict__ keys, int* __restrict__ idx_out,
    const float* __restrict__ x, const float* __restrict__ W_fe,
    const float* __restrict__ a_src, const float* __restrict__ a_dst,
    const float* __restrict__ u_src, const float* __restrict__ u_dst,
    uint* __restrict__ h2, float* __restrict__ es, float* __restrict__ ed) {
  __shared__ __align__(16) float smem[F_IN * EE + F_IN * 68]; // 49.4 KB
  const int t = threadIdx.x, wid = t >> 6, lane = t & 63;

  if (blockIdx.x < NN) {
    // ---------------- k2b role: top-32 for row = blockIdx.x ---------------
    ull* cand = (ull*)smem; // 1 KB
    const int row = blockIdx.x;

    const int jb = wid * 256 + lane * 4;
    const uint4 kv = *(const uint4*)&keys[(size_t)row * NN + jb];
    ull L0 = ((ull)kv.x << 32) | (uint)(jb + 0);
    ull L1 = ((ull)kv.y << 32) | (uint)(jb + 1);
    ull L2 = ((ull)kv.z << 32) | (uint)(jb + 2);
    ull L3 = ((ull)kv.w << 32) | (uint)(jb + 3);
    {
      ull a, b;
      a = umax64(L0, L1); b = umin64(L0, L1); L0 = a; L1 = b;
      a = umax64(L2, L3); b = umin64(L2, L3); L2 = a; L3 = b;
      a = umax64(L0, L2); b = umin64(L0, L2); L0 = a; L2 = b;
      a = umax64(L1, L3); b = umin64(L1, L3); L1 = a; L3 = b;
      a = umax64(L1, L2); b = umin64(L1, L2); L1 = a; L2 = b;
    }
    for (int s = 0; s < TOPK; s++) {
      ull m = L0;
#pragma unroll
      for (int off = 32; off > 0; off >>= 1) {
        const ull o = __shfl_xor(m, off);
        m = o > m ? o : m;
      }
      if (lane == 0) cand[wid * TOPK + s] = m;
      const bool w = (L0 == m);
      L0 = w ? L1 : L0;
      L1 = w ? L2 : L1;
      L2 = w ? L3 : L2;
      L3 = w ? 0ull : L3;
    }
    __syncthreads();

    if (wid == 0) {
      ull k0 = cand[2 * lane];
      ull k1 = cand[2 * lane + 1];
#pragma unroll
      for (int k = 2; k <= 128; k <<= 1) {
#pragma unroll
        for (int d = k >> 1; d > 0; d >>= 1) {
          if (d >= 2) {
            const int pl = d >> 1;
            const ull o0 = __shfl_xor(k0, pl);
            const ull o1 = __shfl_xor(k1, pl);
            const bool keepmax =
                ((lane & (k >> 1)) == 0) == ((lane & pl) == 0);
            k0 = keepmax ? umax64(k0, o0) : umin64(k0, o0);
            k1 = keepmax ? umax64(k1, o1) : umin64(k1, o1);
          } else {
            const bool keepmax0 = ((lane & (k >> 1)) == 0);
            const ull hi = umax64(k0, k1), lo = umin64(k0, k1);
            k0 = keepmax0 ? hi : lo;
            k1 = keepmax0 ? lo : hi;
          }
        }
      }
      if (lane < 16) {
        int* ro = idx_out + (size_t)row * TOPK;
        ro[2 * lane] = (int)(k0 & 1023u);
        ro[2 * lane + 1] = (int)(k1 & 1023u);
      }
    }
  } else {
    // ---------------- k3 role: h = x @ W_fe for 64 rows -------------------
    float* Wl = smem;                              // 32 KB
    float(*xT)[68] = (float(*)[68])(smem + F_IN * EE); // 17.4 KB
    const int row0 = (blockIdx.x - NN) * 64;

    for (int f4 = t; f4 < (F_IN * EE) / 4; f4 += 256)
      *(float4*)&Wl[f4 * 4] = *(const float4*)&W_fe[f4 * 4];
    for (int f4 = t; f4 < (64 * F_IN) / 4; f4 += 256) {
      const float4 v = *(const float4*)&x[(size_t)row0 * F_IN + (size_t)f4 * 4];
      const int r = f4 >> 4;
      const int k0 = (f4 & 15) * 4;
      xT[k0 + 0][r] = v.x;
      xT[k0 + 1][r] = v.y;
      xT[k0 + 2][r] = v.z;
      xT[k0 + 3][r] = v.w;
    }
    __syncthreads();

    const int r0 = wid * 16;
    float acc0[16], acc1[16];
#pragma unroll
    for (int r = 0; r < 16; r++) {
      acc0[r] = 0.f;
      acc1[r] = 0.f;
    }
#pragma unroll 4
    for (int k = 0; k < F_IN; k++) {
      const float2 w2 = *(const float2*)&Wl[k * EE + 2 * lane];
      float xv[16];
      *(float4*)&xv[0] = *(const float4*)&xT[k][r0 + 0];
      *(float4*)&xv[4] = *(const float4*)&xT[k][r0 + 4];
      *(float4*)&xv[8] = *(const float4*)&xT[k][r0 + 8];
      *(float4*)&xv[12] = *(const float4*)&xT[k][r0 + 12];
#pragma unroll
      for (int r = 0; r < 16; r++) {
        acc0[r] += xv[r] * w2.x;
        acc1[r] += xv[r] * w2.y;
      }
    }
    const float2 as2 = *(const float2*)&a_src[2 * lane];
    const float2 ad2 = *(const float2*)&a_dst[2 * lane];
#pragma unroll
    for (int r = 0; r < 16; r++) {
      const int row = row0 + r0 + r;
      const float h0 = acc0[r], h1 = acc1[r];
      h2[(size_t)row * 64 + lane] = f2bf(h0) | (f2bf(h1) << 16);
      float ps = h0 * as2.x + h1 * as2.y;
      float pd = h0 * ad2.x + h1 * ad2.y;
#pragma unroll
      for (int off = 32; off > 0; off >>= 1) {
        ps += __shfl_xor(ps, off);
        pd += __shfl_xor(pd, off);
      }
      if (lane == 0) {
        const int n = row & (NN - 1);
        es[row] = ps + u_src[n];
        ed[row] = pd + u_dst[n];
      }
    }
  }
}

// ---------------------------------------------------------------------------
// K4 v6: single-shot waves — 2 n's per wave (half-wave each), ONE iteration,
// grid 8192 -> 32k waves of pure TLP. Offsets broadcast via ds_bpermute right
// after the idx load; all 16 uint4 gathers issue before the softmax chain.
// hi-column accumulate uses the raw uint (rel err < 2^-7).
// ---------------------------------------------------------------------------
__global__ __launch_bounds__(256) void k4_attn(
    const uint* __restrict__ h2, const float* __restrict__ es,
    const float* __restrict__ ed, const int* __restrict__ idx,
    const float* __restrict__ lin_W, const float* __restrict__ lin_b,
    float* __restrict__ y) {
  const int t = threadIdx.x, wid = t >> 6, lane = t & 63;
  const int blk = blockIdx.x;
  const int xcd = blk & 7, x = blk >> 3;   // x: 0..1023
  const int b = xcd * 8 + (x >> 7);        // 8 b's per XCD -> L2-resident h
  const int half = lane >> 5, ll = lane & 31;
  const int nh = (x & 127) * 8 + wid * 2 + half; // this half-wave's n
  const int sub2 = ll >> 4, c16 = ll & 15;
  const int pbase = half * 128 + sub2 * 4; // bpermute byte base

  const float* edb = ed + (size_t)b * NN;
  const float* esb = es + (size_t)b * NN;
  const char* hb = (const char*)(h2 + (size_t)b * NN * 64);

  // idx load + offset broadcast + issue all 16 gathers (before softmax)
  const int j = idx[nh * TOPK + ll];
  const int off = j << 8; // byte offset of h-row (256 B)
  int offk[16];
#pragma unroll
  for (int k = 0; k < 16; ++k)
    offk[k] = __builtin_amdgcn_ds_bpermute(pbase + k * 8, off);
  uint4 tv[16];
#pragma unroll
  for (int k = 0; k < 16; ++k)
    tv[k] = *(const uint4*)(hb + ((uint)offk[k] + c16 * 16));

  // softmax for this half's n (runs while gathers are in flight)
  const float esv = esb[nh];
  float s = esv + edb[j];
  s = s > 0.f ? s : NEG_SLOPE * s;
  const float p = __expf(s); // |s| <~ 6: safe without max-subtraction
  float dsum = p;
#pragma unroll
  for (int o = 1; o <= 16; o <<= 1) dsum += __shfl_xor(dsum, o);
  const float w = p * (1.0f / dsum);
  float wk[16];
#pragma unroll
  for (int k = 0; k < 16; ++k)
    wk[k] = __uint_as_float(
        __builtin_amdgcn_ds_bpermute(pbase + k * 8, __float_as_uint(w)));

  const float4 lw0 = *(const float4*)&lin_W[c16 * 8];
  const float4 lw1 = *(const float4*)&lin_W[c16 * 8 + 4];
  const float bias = lin_b[0];

  float acc[8];
#pragma unroll
  for (int i = 0; i < 8; i++) acc[i] = 0.f;
#pragma unroll
  for (int k = 0; k < 16; ++k) {
    const float ak = wk[k];
    const uint4 u = tv[k];
    acc[0] += ak * bf_lo(u.x);
    acc[1] += ak * bf_hi_raw(u.x);
    acc[2] += ak * bf_lo(u.y);
    acc[3] += ak * bf_hi_raw(u.y);
    acc[4] += ak * bf_lo(u.z);
    acc[5] += ak * bf_hi_raw(u.z);
    acc[6] += ak * bf_lo(u.w);
    acc[7] += ak * bf_hi_raw(u.w);
  }
  // sum the two sub-groups (within this half), relu
#pragma unroll
  for (int i = 0; i < 8; i++) {
    acc[i] += __shfl_xor(acc[i], 16);
    acc[i] = acc[i] > 0.f ? acc[i] : 0.f;
  }
  float r = acc[0] * lw0.x + acc[1] * lw0.y + acc[2] * lw0.z + acc[3] * lw0.w +
            acc[4] * lw1.x + acc[5] * lw1.y + acc[6] * lw1.z + acc[7] * lw1.w;
#pragma unroll
  for (int o = 8; o > 0; o >>= 1) r += __shfl_xor(r, o);
  if (ll == 0) y[(size_t)b * NN + nh] = r + bias; // lanes 0 and 32 store
}

// ---------------------------------------------------------------------------
extern "C" void kernel_launch(void* const* d_in, const int* in_sizes, int n_in,
                              void* d_out, int out_size, void* d_ws,
                              size_t ws_size, hipStream_t stream) {
  const float* x = (const float*)d_in[0];
  const float* emb = (const float*)d_in[1];
  const float* W_fe = (const float*)d_in[2];
  const float* a_src = (const float*)d_in[3];
  const float* a_dst = (const float*)d_in[4];
  const float* lin_W = (const float*)d_in[5];
  const float* lin_b = (const float*)d_in[6];
  float* y = (float*)d_out;

  char* ws = (char*)d_ws;
  float* u_src = (float*)(ws + 4096);
  float* u_dst = (float*)(ws + 8192);
  int* idx = (int*)(ws + 16384);                        // 128 KB
  float* es = (float*)(ws + 16384 + 131072);            // 256 KB
  float* ed = (float*)(ws + 16384 + 131072 + 262144);   // 256 KB
  uint* h2 = (uint*)(ws + 16384 + 131072 + 2 * 262144); // 16 MB (bf16 pairs)
  uint* keys = (uint*)(ws + 16384 + 131072 + 2 * 262144 + 16777216); // 4 MB

  k2a_sim<<<512, 256, 0, stream>>>(emb, a_src, a_dst, keys, u_src, u_dst);
  k23<<<2048, 256, 0, stream>>>(keys, idx, x, W_fe, a_src, a_dst, u_src,
                                u_dst, h2, es, ed);
  k4_attn<<<8192, 256, 0, stream>>>(h2, es, ed, idx, lin_W, lin_b, y);
}

// Round 10
// 146.273 us; speedup vs baseline: 1.5282x; 1.0974x over previous
//
#include <hip/hip_runtime.h>
#include <math.h>

#define BB 64
#define NN 1024
#define F_IN 64
#define EE 128
#define TOPK 32
#define NEG_SLOPE 0.2f

typedef unsigned int uint;
typedef unsigned short ushort;
typedef unsigned long long ull;
typedef __attribute__((ext_vector_type(8))) short short8; // bf16x8 MFMA frag
typedef __attribute__((ext_vector_type(4))) float f32x4;  // MFMA acc

// pack float -> bf16 (round-to-nearest-even)
static __device__ __forceinline__ uint f2bf(float f) {
  const uint x = __float_as_uint(f);
  return (x + 0x7fffu + ((x >> 16) & 1u)) >> 16;
}
static __device__ __forceinline__ float bf_lo(uint u) {
  return __uint_as_float(u << 16);
}
// hi bf16 WITHOUT masking: low 16 bits act as mantissa garbage, rel err <2^-7
static __device__ __forceinline__ float bf_hi_raw(uint u) {
  return __uint_as_float(u);
}
static __device__ __forceinline__ uint fmono(float f) {
  uint u = __float_as_uint(f);
  return (u & 0x80000000u) ? ~u : (u | 0x80000000u);
}
static __device__ __forceinline__ ull umax64(ull a, ull b) {
  return a > b ? a : b;
}
static __device__ __forceinline__ ull umin64(ull a, ull b) {
  return a < b ? a : b;
}

// ---------------------------------------------------------------------------
// K2a v4: sim keys via LDS-staged tiles + fused u_src/u_dst. fp32 throughout
// (top-k SET membership must match the fp32 reference ranking).
// ---------------------------------------------------------------------------
__global__ __launch_bounds__(256) void k2a_sim(
    const float* __restrict__ emb, const float* __restrict__ a_src,
    const float* __restrict__ a_dst, uint* __restrict__ keys,
    float* __restrict__ u_src, float* __restrict__ u_dst) {
  __shared__ float ei[8][130];  // 4.2 KB
  __shared__ float ej[64][130]; // 33.3 KB
  const int t = threadIdx.x, wid = t >> 6, lane = t & 63;
  const int i0 = (blockIdx.x >> 2) * 8;
  const int jbase = (blockIdx.x & 3) * 256;

  // fused k1: blocks with (blk&3)==0 compute u_src/u_dst for their 8 rows
  if ((blockIdx.x & 3) == 0) {
    const int row = i0 + 2 * wid + (lane >> 5); // half-wave per row
    const int ll = lane & 31;
    const float* er = emb + (size_t)row * EE;
    float us = 0.f, ud = 0.f;
#pragma unroll
    for (int c0 = 0; c0 < EE; c0 += 32) {
      const int c = c0 + ll;
      const float e = er[c];
      us += e * a_src[EE + c];
      ud += e * a_dst[EE + c];
    }
#pragma unroll
    for (int o = 1; o <= 16; o <<= 1) {
      us += __shfl_xor(us, o);
      ud += __shfl_xor(ud, o);
    }
    if (ll == 0) {
      u_src[row] = us;
      u_dst[row] = ud;
    }
  }

  { // stage ei: 8 rows x 128 = 256 float4, one per thread (coalesced)
    const int r = t >> 5, c4 = t & 31;
    const float4 v = *(const float4*)&emb[(size_t)(i0 + r) * EE + c4 * 4];
    *(float2*)&ei[r][c4 * 4] = make_float2(v.x, v.y);
    *(float2*)&ei[r][c4 * 4 + 2] = make_float2(v.z, v.w);
  }

  const int ia = i0 + wid * 2; // this wave's two i-rows: ia, ia+1

  for (int ch = 0; ch < 4; ++ch) {
    const int j0 = jbase + ch * 64;
#pragma unroll
    for (int p = 0; p < 8; ++p) {
      const int g = p * 256 + t;
      const int r = g >> 5, c4 = g & 31;
      const float4 v = *(const float4*)&emb[(size_t)(j0 + r) * EE + c4 * 4];
      *(float2*)&ej[r][c4 * 4] = make_float2(v.x, v.y);
      *(float2*)&ej[r][c4 * 4 + 2] = make_float2(v.z, v.w);
    }
    __syncthreads(); // staging done (covers ei on ch==0)

    float a0 = 0.f, a1 = 0.f, sq = 0.f;
#pragma unroll 8
    for (int d2 = 0; d2 < 64; ++d2) {
      const float2 e = *(const float2*)&ej[lane][2 * d2];
      const float2 wa = *(const float2*)&ei[wid * 2][2 * d2];     // broadcast
      const float2 wb = *(const float2*)&ei[wid * 2 + 1][2 * d2]; // broadcast
      a0 += e.x * wa.x + e.y * wa.y;
      a1 += e.x * wb.x + e.y * wb.y;
      sq += e.x * e.x + e.y * e.y;
    }
    const int jg = j0 + lane;
    const float rj = rsqrtf(sq);
    keys[(size_t)ia * NN + jg] = fmono(a0 * rj);
    keys[(size_t)(ia + 1) * NN + jg] = fmono(a1 * rj);
    __syncthreads(); // compute done before ej overwrite
  }
}

// ---------------------------------------------------------------------------
// K23 v2: fused k2b (top-32 selection) + k3 (MFMA feature GEMM).
// Blocks [0,1024): selection for row=blk. Blocks [1024,2048): h = x @ W_fe
// for 64 rows via mfma_f32_16x16x32_bf16 — wave computes 16 rows x 128 cols
// = 16 MFMAs (vs ~4500 VALU FMA before). LDS now only Wt (18.4 KB, bf16,
// transposed) -> ~8 blocks/CU. A-frags read direct from global x.
// h2 column pairs pack TILE PAIRS (uint c=t4*16+n holds cols 32t4+n /
// 32t4+16+n) — a fixed permutation k4 compensates in its lin_W indexing.
// ---------------------------------------------------------------------------
__global__ __launch_bounds__(256) void k23(
    const uint* __restrict__ keys, int* __restrict__ idx_out,
    const float* __restrict__ x, const float* __restrict__ W_fe,
    const float* __restrict__ a_src, const float* __restrict__ a_dst,
    const float* __restrict__ u_src, const float* __restrict__ u_dst,
    uint* __restrict__ h2, float* __restrict__ es, float* __restrict__ ed) {
  __shared__ __align__(16) ushort smem_w[EE * 72]; // 18.4 KB (union w/ cand)
  const int t = threadIdx.x, wid = t >> 6, lane = t & 63;

  if (blockIdx.x < NN) {
    // ---------------- k2b role: top-32 for row = blockIdx.x ---------------
    ull* cand = (ull*)smem_w; // 1 KB
    const int row = blockIdx.x;

    const int jb = wid * 256 + lane * 4;
    const uint4 kv = *(const uint4*)&keys[(size_t)row * NN + jb];
    ull L0 = ((ull)kv.x << 32) | (uint)(jb + 0);
    ull L1 = ((ull)kv.y << 32) | (uint)(jb + 1);
    ull L2 = ((ull)kv.z << 32) | (uint)(jb + 2);
    ull L3 = ((ull)kv.w << 32) | (uint)(jb + 3);
    {
      ull a, b;
      a = umax64(L0, L1); b = umin64(L0, L1); L0 = a; L1 = b;
      a = umax64(L2, L3); b = umin64(L2, L3); L2 = a; L3 = b;
      a = umax64(L0, L2); b = umin64(L0, L2); L0 = a; L2 = b;
      a = umax64(L1, L3); b = umin64(L1, L3); L1 = a; L3 = b;
      a = umax64(L1, L2); b = umin64(L1, L2); L1 = a; L2 = b;
    }
    for (int s = 0; s < TOPK; s++) {
      ull m = L0;
#pragma unroll
      for (int off = 32; off > 0; off >>= 1) {
        const ull o = __shfl_xor(m, off);
        m = o > m ? o : m;
      }
      if (lane == 0) cand[wid * TOPK + s] = m;
      const bool w = (L0 == m);
      L0 = w ? L1 : L0;
      L1 = w ? L2 : L1;
      L2 = w ? L3 : L2;
      L3 = w ? 0ull : L3;
    }
    __syncthreads();

    if (wid == 0) {
      ull k0 = cand[2 * lane];
      ull k1 = cand[2 * lane + 1];
#pragma unroll
      for (int k = 2; k <= 128; k <<= 1) {
#pragma unroll
        for (int d = k >> 1; d > 0; d >>= 1) {
          if (d >= 2) {
            const int pl = d >> 1;
            const ull o0 = __shfl_xor(k0, pl);
            const ull o1 = __shfl_xor(k1, pl);
            const bool keepmax =
                ((lane & (k >> 1)) == 0) == ((lane & pl) == 0);
            k0 = keepmax ? umax64(k0, o0) : umin64(k0, o0);
            k1 = keepmax ? umax64(k1, o1) : umin64(k1, o1);
          } else {
            const bool keepmax0 = ((lane & (k >> 1)) == 0);
            const ull hi = umax64(k0, k1), lo = umin64(k0, k1);
            k0 = keepmax0 ? hi : lo;
            k1 = keepmax0 ? lo : hi;
          }
        }
      }
      if (lane < 16) {
        int* ro = idx_out + (size_t)row * TOPK;
        ro[2 * lane] = (int)(k0 & 1023u);
        ro[2 * lane + 1] = (int)(k1 & 1023u);
      }
    }
  } else {
    // ---------------- k3 role: MFMA GEMM, 64 rows -------------------------
    const int row0 = (blockIdx.x - NN) * 64;

    // stage Wt bf16 transposed: Wt[n][k], row stride 72 bf16 (144 B, 16B ok)
#pragma unroll
    for (int p = 0; p < 8; ++p) {
      const int idx4 = p * 256 + t; // 0..2047 float4s of W_fe
      const int k = idx4 >> 5;
      const int n4 = (idx4 & 31) * 4;
      const float4 v = *(const float4*)&W_fe[k * EE + n4];
      smem_w[(n4 + 0) * 72 + k] = (ushort)f2bf(v.x);
      smem_w[(n4 + 1) * 72 + k] = (ushort)f2bf(v.y);
      smem_w[(n4 + 2) * 72 + k] = (ushort)f2bf(v.z);
      smem_w[(n4 + 3) * 72 + k] = (ushort)f2bf(v.w);
    }
    __syncthreads();

    const int nn = lane & 15, quad = lane >> 4;
    const int row0w = row0 + wid * 16;

    // A-frags direct from global x: A[m=nn][k = s*32 + quad*8 + j]
    short8 af[2];
#pragma unroll
    for (int s = 0; s < 2; ++s) {
      const float* xr = x + (size_t)(row0w + nn) * F_IN + s * 32 + quad * 8;
      const float4 v0 = *(const float4*)&xr[0];
      const float4 v1 = *(const float4*)&xr[4];
      af[s][0] = (short)f2bf(v0.x);
      af[s][1] = (short)f2bf(v0.y);
      af[s][2] = (short)f2bf(v0.z);
      af[s][3] = (short)f2bf(v0.w);
      af[s][4] = (short)f2bf(v1.x);
      af[s][5] = (short)f2bf(v1.y);
      af[s][6] = (short)f2bf(v1.z);
      af[s][7] = (short)f2bf(v1.w);
    }

    f32x4 acc[8];
#pragma unroll
    for (int T = 0; T < 8; ++T) acc[T] = (f32x4){0.f, 0.f, 0.f, 0.f};

#pragma unroll
    for (int T = 0; T < 8; ++T) {
#pragma unroll
      for (int s = 0; s < 2; ++s) {
        // B-frag: B[k = s*32+quad*8+j][n = T*16+nn] from Wt[n][k]
        const short8 bf =
            *(const short8*)&smem_w[(T * 16 + nn) * 72 + s * 32 + quad * 8];
        acc[T] =
            __builtin_amdgcn_mfma_f32_16x16x32_bf16(af[s], bf, acc[T], 0, 0, 0);
      }
    }

    // epilogue: h2 packed (tile-pair permuted cols) + es/ed row dots
    const int growbase = row0w + quad * 4;
#pragma unroll
    for (int reg = 0; reg < 4; ++reg) {
      uint* hr = h2 + (size_t)(growbase + reg) * 64 + nn;
#pragma unroll
      for (int T4 = 0; T4 < 4; ++T4) {
        hr[T4 * 16] =
            f2bf(acc[2 * T4][reg]) | (f2bf(acc[2 * T4 + 1][reg]) << 16);
      }
    }
    float ae[8], de[8];
#pragma unroll
    for (int T = 0; T < 8; ++T) {
      ae[T] = a_src[T * 16 + nn];
      de[T] = a_dst[T * 16 + nn];
    }
#pragma unroll
    for (int reg = 0; reg < 4; ++reg) {
      float ps = 0.f, pd = 0.f;
#pragma unroll
      for (int T = 0; T < 8; ++T) {
        ps += acc[T][reg] * ae[T];
        pd += acc[T][reg] * de[T];
      }
#pragma unroll
      for (int o = 1; o <= 8; o <<= 1) {
        ps += __shfl_xor(ps, o);
        pd += __shfl_xor(pd, o);
      }
      if (nn == 0) {
        const int grow = growbase + reg;
        const int node = grow & (NN - 1);
        es[grow] = ps + u_src[node];
        ed[grow] = pd + u_dst[node];
      }
    }
  }
}

// ---------------------------------------------------------------------------
// K4 v7: as v6 (single-shot waves, bpermute broadcast, 16 gathers in flight)
// but lin_W loads follow h2's tile-pair column permutation:
// uint index c = t4*16+n holds cols (32*t4+n, 32*t4+16+n).
// ---------------------------------------------------------------------------
__global__ __launch_bounds__(256) void k4_attn(
    const uint* __restrict__ h2, const float* __restrict__ es,
    const float* __restrict__ ed, const int* __restrict__ idx,
    const float* __restrict__ lin_W, const float* __restrict__ lin_b,
    float* __restrict__ y) {
  const int t = threadIdx.x, wid = t >> 6, lane = t & 63;
  const int blk = blockIdx.x;
  const int xcd = blk & 7, x = blk >> 3;   // x: 0..1023
  const int b = xcd * 8 + (x >> 7);        // 8 b's per XCD -> L2-resident h
  const int half = lane >> 5, ll = lane & 31;
  const int nh = (x & 127) * 8 + wid * 2 + half; // this half-wave's n
  const int sub2 = ll >> 4, c16 = ll & 15;
  const int pbase = half * 128 + sub2 * 4; // bpermute byte base

  const float* edb = ed + (size_t)b * NN;
  const float* esb = es + (size_t)b * NN;
  const char* hb = (const char*)(h2 + (size_t)b * NN * 64);

  // idx load + offset broadcast + issue all 16 gathers (before softmax)
  const int j = idx[nh * TOPK + ll];
  const int off = j << 8; // byte offset of h-row (256 B)
  int offk[16];
#pragma unroll
  for (int k = 0; k < 16; ++k)
    offk[k] = __builtin_amdgcn_ds_bpermute(pbase + k * 8, off);
  uint4 tv[16];
#pragma unroll
  for (int k = 0; k < 16; ++k)
    tv[k] = *(const uint4*)(hb + ((uint)offk[k] + c16 * 16));

  // softmax for this half's n (runs while gathers are in flight)
  const float esv = esb[nh];
  float s = esv + edb[j];
  s = s > 0.f ? s : NEG_SLOPE * s;
  const float p = __expf(s); // |s| <~ 6: safe without max-subtraction
  float dsum = p;
#pragma unroll
  for (int o = 1; o <= 16; o <<= 1) dsum += __shfl_xor(dsum, o);
  const float w = p * (1.0f / dsum);
  float wk[16];
#pragma unroll
  for (int k = 0; k < 16; ++k)
    wk[k] = __uint_as_float(
        __builtin_amdgcn_ds_bpermute(pbase + k * 8, __float_as_uint(w)));

  // permuted lin_W: uint c=4*c16+i -> cols 32*t4+nn (lo), 32*t4+16+nn (hi)
  float lwlo[4], lwhi[4];
#pragma unroll
  for (int i = 0; i < 4; ++i) {
    const int c = 4 * c16 + i;
    const int t4 = c >> 4, nn2 = c & 15;
    lwlo[i] = lin_W[t4 * 32 + nn2];
    lwhi[i] = lin_W[t4 * 32 + 16 + nn2];
  }
  const float bias = lin_b[0];

  float acc[8];
#pragma unroll
  for (int i = 0; i < 8; i++) acc[i] = 0.f;
#pragma unroll
  for (int k = 0; k < 16; ++k) {
    const float ak = wk[k];
    const uint4 u = tv[k];
    acc[0] += ak * bf_lo(u.x);
    acc[1] += ak * bf_hi_raw(u.x);
    acc[2] += ak * bf_lo(u.y);
    acc[3] += ak * bf_hi_raw(u.y);
    acc[4] += ak * bf_lo(u.z);
    acc[5] += ak * bf_hi_raw(u.z);
    acc[6] += ak * bf_lo(u.w);
    acc[7] += ak * bf_hi_raw(u.w);
  }
  // sum the two sub-groups (within this half), relu
#pragma unroll
  for (int i = 0; i < 8; i++) {
    acc[i] += __shfl_xor(acc[i], 16);
    acc[i] = acc[i] > 0.f ? acc[i] : 0.f;
  }
  float r = acc[0] * lwlo[0] + acc[1] * lwhi[0] + acc[2] * lwlo[1] +
            acc[3] * lwhi[1] + acc[4] * lwlo[2] + acc[5] * lwhi[2] +
            acc[6] * lwlo[3] + acc[7] * lwhi[3];
#pragma unroll
  for (int o = 8; o > 0; o >>= 1) r += __shfl_xor(r, o);
  if (ll == 0) y[(size_t)b * NN + nh] = r + bias; // lanes 0 and 32 store
}

// ---------------------------------------------------------------------------
extern "C" void kernel_launch(void* const* d_in, const int* in_sizes, int n_in,
                              void* d_out, int out_size, void* d_ws,
                              size_t ws_size, hipStream_t stream) {
  const float* x = (const float*)d_in[0];
  const float* emb = (const float*)d_in[1];
  const float* W_fe = (const float*)d_in[2];
  const float* a_src = (const float*)d_in[3];
  const float* a_dst = (const float*)d_in[4];
  const float* lin_W = (const float*)d_in[5];
  const float* lin_b = (const float*)d_in[6];
  float* y = (float*)d_out;

  char* ws = (char*)d_ws;
  float* u_src = (float*)(ws + 4096);
  float* u_dst = (float*)(ws + 8192);
  int* idx = (int*)(ws + 16384);                        // 128 KB
  float* es = (float*)(ws + 16384 + 131072);            // 256 KB
  float* ed = (float*)(ws + 16384 + 131072 + 262144);   // 256 KB
  uint* h2 = (uint*)(ws + 16384 + 131072 + 2 * 262144); // 16 MB (bf16 pairs)
  uint* keys = (uint*)(ws + 16384 + 131072 + 2 * 262144 + 16777216); // 4 MB

  k2a_sim<<<512, 256, 0, stream>>>(emb, a_src, a_dst, keys, u_src, u_dst);
  k23<<<2048, 256, 0, stream>>>(keys, idx, x, W_fe, a_src, a_dst, u_src,
                                u_dst, h2, es, ed);
  k4_attn<<<8192, 256, 0, stream>>>(h2, es, ed, idx, lin_W, lin_b, y);
}

// Round 11
// 139.149 us; speedup vs baseline: 1.6065x; 1.0512x over previous
//
#include <hip/hip_runtime.h>
#include <math.h>

#define BB 64
#define NN 1024
#define F_IN 64
#define EE 128
#define TOPK 32
#define NEG_SLOPE 0.2f

typedef unsigned int uint;
typedef unsigned short ushort;
typedef unsigned long long ull;
typedef __attribute__((ext_vector_type(8))) short short8; // bf16x8 MFMA frag
typedef __attribute__((ext_vector_type(4))) float f32x4;  // MFMA acc

// pack float -> bf16 (round-to-nearest-even)
static __device__ __forceinline__ uint f2bf(float f) {
  const uint x = __float_as_uint(f);
  return (x + 0x7fffu + ((x >> 16) & 1u)) >> 16;
}
static __device__ __forceinline__ float bf_lo(uint u) {
  return __uint_as_float(u << 16);
}
// hi bf16 WITHOUT masking: low 16 bits act as mantissa garbage, rel err <2^-7
static __device__ __forceinline__ float bf_hi_raw(uint u) {
  return __uint_as_float(u);
}
static __device__ __forceinline__ uint fmono(float f) {
  uint u = __float_as_uint(f);
  return (u & 0x80000000u) ? ~u : (u | 0x80000000u);
}
static __device__ __forceinline__ ull umax64(ull a, ull b) {
  return a > b ? a : b;
}
static __device__ __forceinline__ ull umin64(ull a, ull b) {
  return a < b ? a : b;
}
// shuffle a u64 across lanes via two b32 shuffles (pipelined)
static __device__ __forceinline__ ull shfl_xor64(ull v, int mask) {
  const uint lo = __shfl_xor((uint)v, mask);
  const uint hi = __shfl_xor((uint)(v >> 32), mask);
  return ((ull)hi << 32) | lo;
}

// ---------------------------------------------------------------------------
// K2a v4: sim keys via LDS-staged tiles + fused u_src/u_dst. fp32 throughout
// (top-k SET membership must match the fp32 reference ranking). UNCHANGED.
// ---------------------------------------------------------------------------
__global__ __launch_bounds__(256) void k2a_sim(
    const float* __restrict__ emb, const float* __restrict__ a_src,
    const float* __restrict__ a_dst, uint* __restrict__ keys,
    float* __restrict__ u_src, float* __restrict__ u_dst) {
  __shared__ float ei[8][130];  // 4.2 KB
  __shared__ float ej[64][130]; // 33.3 KB
  const int t = threadIdx.x, wid = t >> 6, lane = t & 63;
  const int i0 = (blockIdx.x >> 2) * 8;
  const int jbase = (blockIdx.x & 3) * 256;

  // fused k1: blocks with (blk&3)==0 compute u_src/u_dst for their 8 rows
  if ((blockIdx.x & 3) == 0) {
    const int row = i0 + 2 * wid + (lane >> 5); // half-wave per row
    const int ll = lane & 31;
    const float* er = emb + (size_t)row * EE;
    float us = 0.f, ud = 0.f;
#pragma unroll
    for (int c0 = 0; c0 < EE; c0 += 32) {
      const int c = c0 + ll;
      const float e = er[c];
      us += e * a_src[EE + c];
      ud += e * a_dst[EE + c];
    }
#pragma unroll
    for (int o = 1; o <= 16; o <<= 1) {
      us += __shfl_xor(us, o);
      ud += __shfl_xor(ud, o);
    }
    if (ll == 0) {
      u_src[row] = us;
      u_dst[row] = ud;
    }
  }

  { // stage ei: 8 rows x 128 = 256 float4, one per thread (coalesced)
    const int r = t >> 5, c4 = t & 31;
    const float4 v = *(const float4*)&emb[(size_t)(i0 + r) * EE + c4 * 4];
    *(float2*)&ei[r][c4 * 4] = make_float2(v.x, v.y);
    *(float2*)&ei[r][c4 * 4 + 2] = make_float2(v.z, v.w);
  }

  const int ia = i0 + wid * 2; // this wave's two i-rows: ia, ia+1

  for (int ch = 0; ch < 4; ++ch) {
    const int j0 = jbase + ch * 64;
#pragma unroll
    for (int p = 0; p < 8; ++p) {
      const int g = p * 256 + t;
      const int r = g >> 5, c4 = g & 31;
      const float4 v = *(const float4*)&emb[(size_t)(j0 + r) * EE + c4 * 4];
      *(float2*)&ej[r][c4 * 4] = make_float2(v.x, v.y);
      *(float2*)&ej[r][c4 * 4 + 2] = make_float2(v.z, v.w);
    }
    __syncthreads(); // staging done (covers ei on ch==0)

    float a0 = 0.f, a1 = 0.f, sq = 0.f;
#pragma unroll 8
    for (int d2 = 0; d2 < 64; ++d2) {
      const float2 e = *(const float2*)&ej[lane][2 * d2];
      const float2 wa = *(const float2*)&ei[wid * 2][2 * d2];     // broadcast
      const float2 wb = *(const float2*)&ei[wid * 2 + 1][2 * d2]; // broadcast
      a0 += e.x * wa.x + e.y * wa.y;
      a1 += e.x * wb.x + e.y * wb.y;
      sq += e.x * e.x + e.y * e.y;
    }
    const int jg = j0 + lane;
    const float rj = rsqrtf(sq);
    keys[(size_t)ia * NN + jg] = fmono(a0 * rj);
    keys[(size_t)(ia + 1) * NN + jg] = fmono(a1 * rj);
    __syncthreads(); // compute done before ej overwrite
  }
}

// ---------------------------------------------------------------------------
// K23 v3: fused selection + MFMA GEMM. Selection rewritten: full bitonic
// sort-256 per wave (4 u64/lane, e = lane*4+r; only 21 of 36 CE steps are
// cross-lane and their 8 b32 shuffles pipeline -> chain depth ~21 shuffle
// latencies instead of ~240 in the old 32-pop argmax loop). Top-32 land in
// lanes 0-7 -> LDS -> wave0 bitonic-128 merge (unchanged). Identical u64
// comparisons -> bit-identical selection. GEMM role unchanged from v2.
// ---------------------------------------------------------------------------
__global__ __launch_bounds__(256) void k23(
    const uint* __restrict__ keys, int* __restrict__ idx_out,
    const float* __restrict__ x, const float* __restrict__ W_fe,
    const float* __restrict__ a_src, const float* __restrict__ a_dst,
    const float* __restrict__ u_src, const float* __restrict__ u_dst,
    uint* __restrict__ h2, float* __restrict__ es, float* __restrict__ ed) {
  __shared__ __align__(16) ushort smem_w[EE * 72]; // 18.4 KB (union w/ cand)
  const int t = threadIdx.x, wid = t >> 6, lane = t & 63;

  if (blockIdx.x < NN) {
    // ---------------- selection role: top-32 for row = blockIdx.x ---------
    ull* cand = (ull*)smem_w; // 1 KB
    const int row = blockIdx.x;

    const int jb = wid * 256 + lane * 4;
    const uint4 kv = *(const uint4*)&keys[(size_t)row * NN + jb];
    ull xr[4];
    xr[0] = ((ull)kv.x << 32) | (uint)(jb + 0);
    xr[1] = ((ull)kv.y << 32) | (uint)(jb + 1);
    xr[2] = ((ull)kv.z << 32) | (uint)(jb + 2);
    xr[3] = ((ull)kv.w << 32) | (uint)(jb + 3);

    // bitonic sort-256 descending; element e = lane*4 + r
#pragma unroll
    for (int k = 2; k <= 256; k <<= 1) {
#pragma unroll
      for (int d = 128; d >= 1; d >>= 1) {
        if (d > (k >> 1)) continue;
        if (d >= 4) {
          const int pl = d >> 2; // partner lane distance
          const bool lower = (lane & pl) == 0;
#pragma unroll
          for (int r = 0; r < 4; ++r) {
            const ull o = shfl_xor64(xr[r], pl);
            const bool desc = (((lane * 4 + r) & k) == 0);
            const bool keepmax = (desc == lower);
            xr[r] = keepmax ? umax64(xr[r], o) : umin64(xr[r], o);
          }
        } else if (d == 2) {
          // pairs (r=0,r=2) and (r=1,r=3); lower elements r=0,1
#pragma unroll
          for (int r = 0; r < 2; ++r) {
            const bool desc = (((lane * 4 + r) & k) == 0);
            const ull hi = umax64(xr[r], xr[r + 2]);
            const ull lo = umin64(xr[r], xr[r + 2]);
            xr[r] = desc ? hi : lo;
            xr[r + 2] = desc ? lo : hi;
          }
        } else { // d == 1: pairs (0,1) and (2,3)
#pragma unroll
          for (int r = 0; r < 4; r += 2) {
            const bool desc = (((lane * 4 + r) & k) == 0);
            const ull hi = umax64(xr[r], xr[r + 1]);
            const ull lo = umin64(xr[r], xr[r + 1]);
            xr[r] = desc ? hi : lo;
            xr[r + 1] = desc ? lo : hi;
          }
        }
      }
    }
    // wave-local top-32 = elements 0..31 = lanes 0..7, sorted descending
    if (lane < 8) {
#pragma unroll
      for (int r = 0; r < 4; ++r) cand[wid * 32 + lane * 4 + r] = xr[r];
    }
    __syncthreads();

    if (wid == 0) {
      ull k0 = cand[2 * lane];
      ull k1 = cand[2 * lane + 1];
#pragma unroll
      for (int k = 2; k <= 128; k <<= 1) {
#pragma unroll
        for (int d = k >> 1; d > 0; d >>= 1) {
          if (d >= 2) {
            const int pl = d >> 1;
            const ull o0 = shfl_xor64(k0, pl);
            const ull o1 = shfl_xor64(k1, pl);
            const bool keepmax =
                ((lane & (k >> 1)) == 0) == ((lane & pl) == 0);
            k0 = keepmax ? umax64(k0, o0) : umin64(k0, o0);
            k1 = keepmax ? umax64(k1, o1) : umin64(k1, o1);
          } else {
            const bool keepmax0 = ((lane & (k >> 1)) == 0);
            const ull hi = umax64(k0, k1), lo = umin64(k0, k1);
            k0 = keepmax0 ? hi : lo;
            k1 = keepmax0 ? lo : hi;
          }
        }
      }
      if (lane < 16) {
        int* ro = idx_out + (size_t)row * TOPK;
        ro[2 * lane] = (int)(k0 & 1023u);
        ro[2 * lane + 1] = (int)(k1 & 1023u);
      }
    }
  } else {
    // ---------------- k3 role: MFMA GEMM, 64 rows (unchanged) -------------
    const int row0 = (blockIdx.x - NN) * 64;

#pragma unroll
    for (int p = 0; p < 8; ++p) {
      const int idx4 = p * 256 + t; // 0..2047 float4s of W_fe
      const int k = idx4 >> 5;
      const int n4 = (idx4 & 31) * 4;
      const float4 v = *(const float4*)&W_fe[k * EE + n4];
      smem_w[(n4 + 0) * 72 + k] = (ushort)f2bf(v.x);
      smem_w[(n4 + 1) * 72 + k] = (ushort)f2bf(v.y);
      smem_w[(n4 + 2) * 72 + k] = (ushort)f2bf(v.z);
      smem_w[(n4 + 3) * 72 + k] = (ushort)f2bf(v.w);
    }
    __syncthreads();

    const int nn = lane & 15, quad = lane >> 4;
    const int row0w = row0 + wid * 16;

    short8 af[2];
#pragma unroll
    for (int s = 0; s < 2; ++s) {
      const float* xr2 = x + (size_t)(row0w + nn) * F_IN + s * 32 + quad * 8;
      const float4 v0 = *(const float4*)&xr2[0];
      const float4 v1 = *(const float4*)&xr2[4];
      af[s][0] = (short)f2bf(v0.x);
      af[s][1] = (short)f2bf(v0.y);
      af[s][2] = (short)f2bf(v0.z);
      af[s][3] = (short)f2bf(v0.w);
      af[s][4] = (short)f2bf(v1.x);
      af[s][5] = (short)f2bf(v1.y);
      af[s][6] = (short)f2bf(v1.z);
      af[s][7] = (short)f2bf(v1.w);
    }

    f32x4 acc[8];
#pragma unroll
    for (int T = 0; T < 8; ++T) acc[T] = (f32x4){0.f, 0.f, 0.f, 0.f};

#pragma unroll
    for (int T = 0; T < 8; ++T) {
#pragma unroll
      for (int s = 0; s < 2; ++s) {
        const short8 bf =
            *(const short8*)&smem_w[(T * 16 + nn) * 72 + s * 32 + quad * 8];
        acc[T] =
            __builtin_amdgcn_mfma_f32_16x16x32_bf16(af[s], bf, acc[T], 0, 0, 0);
      }
    }

    const int growbase = row0w + quad * 4;
#pragma unroll
    for (int reg = 0; reg < 4; ++reg) {
      uint* hr = h2 + (size_t)(growbase + reg) * 64 + nn;
#pragma unroll
      for (int T4 = 0; T4 < 4; ++T4) {
        hr[T4 * 16] =
            f2bf(acc[2 * T4][reg]) | (f2bf(acc[2 * T4 + 1][reg]) << 16);
      }
    }
    float ae[8], de[8];
#pragma unroll
    for (int T = 0; T < 8; ++T) {
      ae[T] = a_src[T * 16 + nn];
      de[T] = a_dst[T * 16 + nn];
    }
#pragma unroll
    for (int reg = 0; reg < 4; ++reg) {
      float ps = 0.f, pd = 0.f;
#pragma unroll
      for (int T = 0; T < 8; ++T) {
        ps += acc[T][reg] * ae[T];
        pd += acc[T][reg] * de[T];
      }
#pragma unroll
      for (int o = 1; o <= 8; o <<= 1) {
        ps += __shfl_xor(ps, o);
        pd += __shfl_xor(pd, o);
      }
      if (nn == 0) {
        const int grow = growbase + reg;
        const int node = grow & (NN - 1);
        es[grow] = ps + u_src[node];
        ed[grow] = pd + u_dst[node];
      }
    }
  }
}

// ---------------------------------------------------------------------------
// K4 v7: single-shot waves, bpermute broadcast, 16 gathers in flight;
// lin_W follows h2's tile-pair column permutation. UNCHANGED.
// ---------------------------------------------------------------------------
__global__ __launch_bounds__(256) void k4_attn(
    const uint* __restrict__ h2, const float* __restrict__ es,
    const float* __restrict__ ed, const int* __restrict__ idx,
    const float* __restrict__ lin_W, const float* __restrict__ lin_b,
    float* __restrict__ y) {
  const int t = threadIdx.x, wid = t >> 6, lane = t & 63;
  const int blk = blockIdx.x;
  const int xcd = blk & 7, x = blk >> 3;   // x: 0..1023
  const int b = xcd * 8 + (x >> 7);        // 8 b's per XCD -> L2-resident h
  const int half = lane >> 5, ll = lane & 31;
  const int nh = (x & 127) * 8 + wid * 2 + half; // this half-wave's n
  const int sub2 = ll >> 4, c16 = ll & 15;
  const int pbase = half * 128 + sub2 * 4; // bpermute byte base

  const float* edb = ed + (size_t)b * NN;
  const float* esb = es + (size_t)b * NN;
  const char* hb = (const char*)(h2 + (size_t)b * NN * 64);

  const int j = idx[nh * TOPK + ll];
  const int off = j << 8; // byte offset of h-row (256 B)
  int offk[16];
#pragma unroll
  for (int k = 0; k < 16; ++k)
    offk[k] = __builtin_amdgcn_ds_bpermute(pbase + k * 8, off);
  uint4 tv[16];
#pragma unroll
  for (int k = 0; k < 16; ++k)
    tv[k] = *(const uint4*)(hb + ((uint)offk[k] + c16 * 16));

  const float esv = esb[nh];
  float s = esv + edb[j];
  s = s > 0.f ? s : NEG_SLOPE * s;
  const float p = __expf(s); // |s| <~ 6: safe without max-subtraction
  float dsum = p;
#pragma unroll
  for (int o = 1; o <= 16; o <<= 1) dsum += __shfl_xor(dsum, o);
  const float w = p * (1.0f / dsum);
  float wk[16];
#pragma unroll
  for (int k = 0; k < 16; ++k)
    wk[k] = __uint_as_float(
        __builtin_amdgcn_ds_bpermute(pbase + k * 8, __float_as_uint(w)));

  float lwlo[4], lwhi[4];
#pragma unroll
  for (int i = 0; i < 4; ++i) {
    const int c = 4 * c16 + i;
    const int t4 = c >> 4, nn2 = c & 15;
    lwlo[i] = lin_W[t4 * 32 + nn2];
    lwhi[i] = lin_W[t4 * 32 + 16 + nn2];
  }
  const float bias = lin_b[0];

  float acc[8];
#pragma unroll
  for (int i = 0; i < 8; i++) acc[i] = 0.f;
#pragma unroll
  for (int k = 0; k < 16; ++k) {
    const float ak = wk[k];
    const uint4 u = tv[k];
    acc[0] += ak * bf_lo(u.x);
    acc[1] += ak * bf_hi_raw(u.x);
    acc[2] += ak * bf_lo(u.y);
    acc[3] += ak * bf_hi_raw(u.y);
    acc[4] += ak * bf_lo(u.z);
    acc[5] += ak * bf_hi_raw(u.z);
    acc[6] += ak * bf_lo(u.w);
    acc[7] += ak * bf_hi_raw(u.w);
  }
#pragma unroll
  for (int i = 0; i < 8; i++) {
    acc[i] += __shfl_xor(acc[i], 16);
    acc[i] = acc[i] > 0.f ? acc[i] : 0.f;
  }
  float r = acc[0] * lwlo[0] + acc[1] * lwhi[0] + acc[2] * lwlo[1] +
            acc[3] * lwhi[1] + acc[4] * lwlo[2] + acc[5] * lwhi[2] +
            acc[6] * lwlo[3] + acc[7] * lwhi[3];
#pragma unroll
  for (int o = 8; o > 0; o >>= 1) r += __shfl_xor(r, o);
  if (ll == 0) y[(size_t)b * NN + nh] = r + bias; // lanes 0 and 32 store
}

// ---------------------------------------------------------------------------
extern "C" void kernel_launch(void* const* d_in, const int* in_sizes, int n_in,
                              void* d_out, int out_size, void* d_ws,
                              size_t ws_size, hipStream_t stream) {
  const float* x = (const float*)d_in[0];
  const float* emb = (const float*)d_in[1];
  const float* W_fe = (const float*)d_in[2];
  const float* a_src = (const float*)d_in[3];
  const float* a_dst = (const float*)d_in[4];
  const float* lin_W = (const float*)d_in[5];
  const float* lin_b = (const float*)d_in[6];
  float* y = (float*)d_out;

  char* ws = (char*)d_ws;
  float* u_src = (float*)(ws + 4096);
  float* u_dst = (float*)(ws + 8192);
  int* idx = (int*)(ws + 16384);                        // 128 KB
  float* es = (float*)(ws + 16384 + 131072);            // 256 KB
  float* ed = (float*)(ws + 16384 + 131072 + 262144);   // 256 KB
  uint* h2 = (uint*)(ws + 16384 + 131072 + 2 * 262144); // 16 MB (bf16 pairs)
  uint* keys = (uint*)(ws + 16384 + 131072 + 2 * 262144 + 16777216); // 4 MB

  k2a_sim<<<512, 256, 0, stream>>>(emb, a_src, a_dst, keys, u_src, u_dst);
  k23<<<2048, 256, 0, stream>>>(keys, idx, x, W_fe, a_src, a_dst, u_src,
                                u_dst, h2, es, ed);
  k4_attn<<<8192, 256, 0, stream>>>(h2, es, ed, idx, lin_W, lin_b, y);
}

// Round 12
// 135.078 us; speedup vs baseline: 1.6549x; 1.0301x over previous
//
#include <hip/hip_runtime.h>
#include <math.h>

#define BB 64
#define NN 1024
#define F_IN 64
#define EE 128
#define TOPK 32
#define NEG_SLOPE 0.2f

typedef unsigned int uint;
typedef unsigned short ushort;
typedef unsigned long long ull;
typedef __attribute__((ext_vector_type(8))) short short8; // bf16x8 MFMA frag
typedef __attribute__((ext_vector_type(4))) float f32x4;  // MFMA acc

// pack float -> bf16 (round-to-nearest-even)
static __device__ __forceinline__ uint f2bf(float f) {
  const uint x = __float_as_uint(f);
  return (x + 0x7fffu + ((x >> 16) & 1u)) >> 16;
}
static __device__ __forceinline__ float bf_lo(uint u) {
  return __uint_as_float(u << 16);
}
// hi bf16 WITHOUT masking: low 16 bits act as mantissa garbage, rel err <2^-7
static __device__ __forceinline__ float bf_hi_raw(uint u) {
  return __uint_as_float(u);
}
static __device__ __forceinline__ uint fmono(float f) {
  uint u = __float_as_uint(f);
  return (u & 0x80000000u) ? ~u : (u | 0x80000000u);
}
static __device__ __forceinline__ ull umax64(ull a, ull b) {
  return a > b ? a : b;
}
static __device__ __forceinline__ ull umin64(ull a, ull b) {
  return a < b ? a : b;
}
// shuffle a u64 across lanes via two b32 shuffles (pipelined)
static __device__ __forceinline__ ull shfl_xor64(ull v, int mask) {
  const uint lo = __shfl_xor((uint)v, mask);
  const uint hi = __shfl_xor((uint)(v >> 32), mask);
  return ((ull)hi << 32) | lo;
}

// ---------------------------------------------------------------------------
// K2a v5: sim keys via LDS-staged tiles + fused u_src/u_dst + fused one-shot
// W transpose: blocks (blk&3)==1, blk>>2<32 write Wt = bf16(W_fe^T) (16 KB)
// to global — removes k23's per-block LDS transpose (the 16-way-conflict
// staging identified in R11 post-mortem).
// ---------------------------------------------------------------------------
__global__ __launch_bounds__(256) void k2a_sim(
    const float* __restrict__ emb, const float* __restrict__ a_src,
    const float* __restrict__ a_dst, const float* __restrict__ W_fe,
    uint* __restrict__ keys, float* __restrict__ u_src,
    float* __restrict__ u_dst, ushort* __restrict__ wt) {
  __shared__ float ei[8][130];  // 4.2 KB
  __shared__ float ej[64][130]; // 33.3 KB
  const int t = threadIdx.x, wid = t >> 6, lane = t & 63;
  const int i0 = (blockIdx.x >> 2) * 8;
  const int jbase = (blockIdx.x & 3) * 256;

  // fused k1: blocks with (blk&3)==0 compute u_src/u_dst for their 8 rows
  if ((blockIdx.x & 3) == 0) {
    const int row = i0 + 2 * wid + (lane >> 5); // half-wave per row
    const int ll = lane & 31;
    const float* er = emb + (size_t)row * EE;
    float us = 0.f, ud = 0.f;
#pragma unroll
    for (int c0 = 0; c0 < EE; c0 += 32) {
      const int c = c0 + ll;
      const float e = er[c];
      us += e * a_src[EE + c];
      ud += e * a_dst[EE + c];
    }
#pragma unroll
    for (int o = 1; o <= 16; o <<= 1) {
      us += __shfl_xor(us, o);
      ud += __shfl_xor(ud, o);
    }
    if (ll == 0) {
      u_src[row] = us;
      u_dst[row] = ud;
    }
  } else if ((blockIdx.x & 3) == 1 && (blockIdx.x >> 2) < 32) {
    // fused W transpose: Wt[n][k] = bf16(W_fe[k][n]); coalesced ushort writes
    const int g = (blockIdx.x >> 2) * 256 + t; // 0..8191
    const int n = g >> 6, k = g & 63;
    wt[g] = (ushort)f2bf(W_fe[k * EE + n]);
  }

  { // stage ei: 8 rows x 128 = 256 float4, one per thread (coalesced)
    const int r = t >> 5, c4 = t & 31;
    const float4 v = *(const float4*)&emb[(size_t)(i0 + r) * EE + c4 * 4];
    *(float2*)&ei[r][c4 * 4] = make_float2(v.x, v.y);
    *(float2*)&ei[r][c4 * 4 + 2] = make_float2(v.z, v.w);
  }

  const int ia = i0 + wid * 2; // this wave's two i-rows: ia, ia+1

  for (int ch = 0; ch < 4; ++ch) {
    const int j0 = jbase + ch * 64;
#pragma unroll
    for (int p = 0; p < 8; ++p) {
      const int g = p * 256 + t;
      const int r = g >> 5, c4 = g & 31;
      const float4 v = *(const float4*)&emb[(size_t)(j0 + r) * EE + c4 * 4];
      *(float2*)&ej[r][c4 * 4] = make_float2(v.x, v.y);
      *(float2*)&ej[r][c4 * 4 + 2] = make_float2(v.z, v.w);
    }
    __syncthreads(); // staging done (covers ei on ch==0)

    float a0 = 0.f, a1 = 0.f, sq = 0.f;
#pragma unroll 8
    for (int d2 = 0; d2 < 64; ++d2) {
      const float2 e = *(const float2*)&ej[lane][2 * d2];
      const float2 wa = *(const float2*)&ei[wid * 2][2 * d2];     // broadcast
      const float2 wb = *(const float2*)&ei[wid * 2 + 1][2 * d2]; // broadcast
      a0 += e.x * wa.x + e.y * wa.y;
      a1 += e.x * wb.x + e.y * wb.y;
      sq += e.x * e.x + e.y * e.y;
    }
    const int jg = j0 + lane;
    const float rj = rsqrtf(sq);
    keys[(size_t)ia * NN + jg] = fmono(a0 * rj);
    keys[(size_t)(ia + 1) * NN + jg] = fmono(a1 * rj);
    __syncthreads(); // compute done before ej overwrite
  }
}

// ---------------------------------------------------------------------------
// K23 v4: fused selection + MFMA GEMM. Selection: bitonic sort-256/wave +
// wave0 bitonic-128 merge (unchanged, bit-identical). GEMM: B-frags now read
// DIRECT from global Wt (L1-resident 16 KB, perfectly coalesced 1-KB
// segments) — no LDS staging, no __syncthreads, no bank conflicts in the
// GEMM role. Kernel LDS = 1 KB (cand only).
// ---------------------------------------------------------------------------
__global__ __launch_bounds__(256) void k23(
    const uint* __restrict__ keys, int* __restrict__ idx_out,
    const float* __restrict__ x, const ushort* __restrict__ wt,
    const float* __restrict__ a_src, const float* __restrict__ a_dst,
    const float* __restrict__ u_src, const float* __restrict__ u_dst,
    uint* __restrict__ h2, float* __restrict__ es, float* __restrict__ ed) {
  __shared__ ull cand[128]; // 1 KB
  const int t = threadIdx.x, wid = t >> 6, lane = t & 63;

  if (blockIdx.x < NN) {
    // ---------------- selection role: top-32 for row = blockIdx.x ---------
    const int row = blockIdx.x;

    const int jb = wid * 256 + lane * 4;
    const uint4 kv = *(const uint4*)&keys[(size_t)row * NN + jb];
    ull xr[4];
    xr[0] = ((ull)kv.x << 32) | (uint)(jb + 0);
    xr[1] = ((ull)kv.y << 32) | (uint)(jb + 1);
    xr[2] = ((ull)kv.z << 32) | (uint)(jb + 2);
    xr[3] = ((ull)kv.w << 32) | (uint)(jb + 3);

    // bitonic sort-256 descending; element e = lane*4 + r
#pragma unroll
    for (int k = 2; k <= 256; k <<= 1) {
#pragma unroll
      for (int d = 128; d >= 1; d >>= 1) {
        if (d > (k >> 1)) continue;
        if (d >= 4) {
          const int pl = d >> 2; // partner lane distance
          const bool lower = (lane & pl) == 0;
#pragma unroll
          for (int r = 0; r < 4; ++r) {
            const ull o = shfl_xor64(xr[r], pl);
            const bool desc = (((lane * 4 + r) & k) == 0);
            const bool keepmax = (desc == lower);
            xr[r] = keepmax ? umax64(xr[r], o) : umin64(xr[r], o);
          }
        } else if (d == 2) {
#pragma unroll
          for (int r = 0; r < 2; ++r) {
            const bool desc = (((lane * 4 + r) & k) == 0);
            const ull hi = umax64(xr[r], xr[r + 2]);
            const ull lo = umin64(xr[r], xr[r + 2]);
            xr[r] = desc ? hi : lo;
            xr[r + 2] = desc ? lo : hi;
          }
        } else { // d == 1
#pragma unroll
          for (int r = 0; r < 4; r += 2) {
            const bool desc = (((lane * 4 + r) & k) == 0);
            const ull hi = umax64(xr[r], xr[r + 1]);
            const ull lo = umin64(xr[r], xr[r + 1]);
            xr[r] = desc ? hi : lo;
            xr[r + 1] = desc ? lo : hi;
          }
        }
      }
    }
    // wave-local top-32 = elements 0..31 = lanes 0..7, sorted descending
    if (lane < 8) {
#pragma unroll
      for (int r = 0; r < 4; ++r) cand[wid * 32 + lane * 4 + r] = xr[r];
    }
    __syncthreads();

    if (wid == 0) {
      ull k0 = cand[2 * lane];
      ull k1 = cand[2 * lane + 1];
#pragma unroll
      for (int k = 2; k <= 128; k <<= 1) {
#pragma unroll
        for (int d = k >> 1; d > 0; d >>= 1) {
          if (d >= 2) {
            const int pl = d >> 1;
            const ull o0 = shfl_xor64(k0, pl);
            const ull o1 = shfl_xor64(k1, pl);
            const bool keepmax =
                ((lane & (k >> 1)) == 0) == ((lane & pl) == 0);
            k0 = keepmax ? umax64(k0, o0) : umin64(k0, o0);
            k1 = keepmax ? umax64(k1, o1) : umin64(k1, o1);
          } else {
            const bool keepmax0 = ((lane & (k >> 1)) == 0);
            const ull hi = umax64(k0, k1), lo = umin64(k0, k1);
            k0 = keepmax0 ? hi : lo;
            k1 = keepmax0 ? lo : hi;
          }
        }
      }
      if (lane < 16) {
        int* ro = idx_out + (size_t)row * TOPK;
        ro[2 * lane] = (int)(k0 & 1023u);
        ro[2 * lane + 1] = (int)(k1 & 1023u);
      }
    }
  } else {
    // ---------------- k3 role: MFMA GEMM, 64 rows, LDS-free ---------------
    const int row0 = (blockIdx.x - NN) * 64;
    const int nn = lane & 15, quad = lane >> 4;
    const int row0w = row0 + wid * 16;

    // A-frags direct from global x: A[m=nn][k = s*32 + quad*8 + j]
    short8 af[2];
#pragma unroll
    for (int s = 0; s < 2; ++s) {
      const float* xr2 = x + (size_t)(row0w + nn) * F_IN + s * 32 + quad * 8;
      const float4 v0 = *(const float4*)&xr2[0];
      const float4 v1 = *(const float4*)&xr2[4];
      af[s][0] = (short)f2bf(v0.x);
      af[s][1] = (short)f2bf(v0.y);
      af[s][2] = (short)f2bf(v0.z);
      af[s][3] = (short)f2bf(v0.w);
      af[s][4] = (short)f2bf(v1.x);
      af[s][5] = (short)f2bf(v1.y);
      af[s][6] = (short)f2bf(v1.z);
      af[s][7] = (short)f2bf(v1.w);
    }

    f32x4 acc[8];
#pragma unroll
    for (int T = 0; T < 8; ++T) acc[T] = (f32x4){0.f, 0.f, 0.f, 0.f};

#pragma unroll
    for (int T = 0; T < 8; ++T) {
#pragma unroll
      for (int s = 0; s < 2; ++s) {
        // B-frag: Wt[n = T*16+nn][k = s*32+quad*8 ..+8] — coalesced 1 KB/instr
        const short8 bf =
            *(const short8*)&wt[(T * 16 + nn) * F_IN + s * 32 + quad * 8];
        acc[T] =
            __builtin_amdgcn_mfma_f32_16x16x32_bf16(af[s], bf, acc[T], 0, 0, 0);
      }
    }

    // epilogue: h2 packed (tile-pair permuted cols) + es/ed row dots
    const int growbase = row0w + quad * 4;
#pragma unroll
    for (int reg = 0; reg < 4; ++reg) {
      uint* hr = h2 + (size_t)(growbase + reg) * 64 + nn;
#pragma unroll
      for (int T4 = 0; T4 < 4; ++T4) {
        hr[T4 * 16] =
            f2bf(acc[2 * T4][reg]) | (f2bf(acc[2 * T4 + 1][reg]) << 16);
      }
    }
    float ae[8], de[8];
#pragma unroll
    for (int T = 0; T < 8; ++T) {
      ae[T] = a_src[T * 16 + nn];
      de[T] = a_dst[T * 16 + nn];
    }
#pragma unroll
    for (int reg = 0; reg < 4; ++reg) {
      float ps = 0.f, pd = 0.f;
#pragma unroll
      for (int T = 0; T < 8; ++T) {
        ps += acc[T][reg] * ae[T];
        pd += acc[T][reg] * de[T];
      }
#pragma unroll
      for (int o = 1; o <= 8; o <<= 1) {
        ps += __shfl_xor(ps, o);
        pd += __shfl_xor(pd, o);
      }
      if (nn == 0) {
        const int grow = growbase + reg;
        const int node = grow & (NN - 1);
        es[grow] = ps + u_src[node];
        ed[grow] = pd + u_dst[node];
      }
    }
  }
}

// ---------------------------------------------------------------------------
// K4 v7: single-shot waves, bpermute broadcast, 16 gathers in flight;
// lin_W follows h2's tile-pair column permutation. UNCHANGED.
// ---------------------------------------------------------------------------
__global__ __launch_bounds__(256) void k4_attn(
    const uint* __restrict__ h2, const float* __restrict__ es,
    const float* __restrict__ ed, const int* __restrict__ idx,
    const float* __restrict__ lin_W, const float* __restrict__ lin_b,
    float* __restrict__ y) {
  const int t = threadIdx.x, wid = t >> 6, lane = t & 63;
  const int blk = blockIdx.x;
  const int xcd = blk & 7, x = blk >> 3;   // x: 0..1023
  const int b = xcd * 8 + (x >> 7);        // 8 b's per XCD -> L2-resident h
  const int half = lane >> 5, ll = lane & 31;
  const int nh = (x & 127) * 8 + wid * 2 + half; // this half-wave's n
  const int sub2 = ll >> 4, c16 = ll & 15;
  const int pbase = half * 128 + sub2 * 4; // bpermute byte base

  const float* edb = ed + (size_t)b * NN;
  const float* esb = es + (size_t)b * NN;
  const char* hb = (const char*)(h2 + (size_t)b * NN * 64);

  const int j = idx[nh * TOPK + ll];
  const int off = j << 8; // byte offset of h-row (256 B)
  int offk[16];
#pragma unroll
  for (int k = 0; k < 16; ++k)
    offk[k] = __builtin_amdgcn_ds_bpermute(pbase + k * 8, off);
  uint4 tv[16];
#pragma unroll
  for (int k = 0; k < 16; ++k)
    tv[k] = *(const uint4*)(hb + ((uint)offk[k] + c16 * 16));

  const float esv = esb[nh];
  float s = esv + edb[j];
  s = s > 0.f ? s : NEG_SLOPE * s;
  const float p = __expf(s); // |s| <~ 6: safe without max-subtraction
  float dsum = p;
#pragma unroll
  for (int o = 1; o <= 16; o <<= 1) dsum += __shfl_xor(dsum, o);
  const float w = p * (1.0f / dsum);
  float wk[16];
#pragma unroll
  for (int k = 0; k < 16; ++k)
    wk[k] = __uint_as_float(
        __builtin_amdgcn_ds_bpermute(pbase + k * 8, __float_as_uint(w)));

  float lwlo[4], lwhi[4];
#pragma unroll
  for (int i = 0; i < 4; ++i) {
    const int c = 4 * c16 + i;
    const int t4 = c >> 4, nn2 = c & 15;
    lwlo[i] = lin_W[t4 * 32 + nn2];
    lwhi[i] = lin_W[t4 * 32 + 16 + nn2];
  }
  const float bias = lin_b[0];

  float acc[8];
#pragma unroll
  for (int i = 0; i < 8; i++) acc[i] = 0.f;
#pragma unroll
  for (int k = 0; k < 16; ++k) {
    const float ak = wk[k];
    const uint4 u = tv[k];
    acc[0] += ak * bf_lo(u.x);
    acc[1] += ak * bf_hi_raw(u.x);
    acc[2] += ak * bf_lo(u.y);
    acc[3] += ak * bf_hi_raw(u.y);
    acc[4] += ak * bf_lo(u.z);
    acc[5] += ak * bf_hi_raw(u.z);
    acc[6] += ak * bf_lo(u.w);
    acc[7] += ak * bf_hi_raw(u.w);
  }
#pragma unroll
  for (int i = 0; i < 8; i++) {
    acc[i] += __shfl_xor(acc[i], 16);
    acc[i] = acc[i] > 0.f ? acc[i] : 0.f;
  }
  float r = acc[0] * lwlo[0] + acc[1] * lwhi[0] + acc[2] * lwlo[1] +
            acc[3] * lwhi[1] + acc[4] * lwlo[2] + acc[5] * lwhi[2] +
            acc[6] * lwlo[3] + acc[7] * lwhi[3];
#pragma unroll
  for (int o = 8; o > 0; o >>= 1) r += __shfl_xor(r, o);
  if (ll == 0) y[(size_t)b * NN + nh] = r + bias; // lanes 0 and 32 store
}

// ---------------------------------------------------------------------------
extern "C" void kernel_launch(void* const* d_in, const int* in_sizes, int n_in,
                              void* d_out, int out_size, void* d_ws,
                              size_t ws_size, hipStream_t stream) {
  const float* x = (const float*)d_in[0];
  const float* emb = (const float*)d_in[1];
  const float* W_fe = (const float*)d_in[2];
  const float* a_src = (const float*)d_in[3];
  const float* a_dst = (const float*)d_in[4];
  const float* lin_W = (const float*)d_in[5];
  const float* lin_b = (const float*)d_in[6];
  float* y = (float*)d_out;

  char* ws = (char*)d_ws;
  float* u_src = (float*)(ws + 4096);
  float* u_dst = (float*)(ws + 8192);
  int* idx = (int*)(ws + 16384);                        // 128 KB
  float* es = (float*)(ws + 147456);                    // 256 KB
  float* ed = (float*)(ws + 409600);                    // 256 KB
  uint* h2 = (uint*)(ws + 671744);                      // 16 MB (bf16 pairs)
  uint* keys = (uint*)(ws + 17448960);                  // 4 MB
  ushort* wt = (ushort*)(ws + 21643264);                // 16 KB (bf16 W^T)

  k2a_sim<<<512, 256, 0, stream>>>(emb, a_src, a_dst, W_fe, keys, u_src,
                                   u_dst, wt);
  k23<<<2048, 256, 0, stream>>>(keys, idx, x, wt, a_src, a_dst, u_src, u_dst,
                                h2, es, ed);
  k4_attn<<<8192, 256, 0, stream>>>(h2, es, ed, idx, lin_W, lin_b, y);
}

// Round 13
// 132.887 us; speedup vs baseline: 1.6822x; 1.0165x over previous
//
#include <hip/hip_runtime.h>
#include <math.h>

#define BB 64
#define NN 1024
#define F_IN 64
#define EE 128
#define TOPK 32
#define NEG_SLOPE 0.2f

typedef unsigned int uint;
typedef unsigned short ushort;
typedef unsigned long long ull;
typedef __attribute__((ext_vector_type(8))) short short8; // bf16x8 MFMA frag
typedef __attribute__((ext_vector_type(4))) float f32x4;  // MFMA acc

// pack float -> bf16 (round-to-nearest-even)
static __device__ __forceinline__ uint f2bf(float f) {
  const uint x = __float_as_uint(f);
  return (x + 0x7fffu + ((x >> 16) & 1u)) >> 16;
}
static __device__ __forceinline__ float bf_lo(uint u) {
  return __uint_as_float(u << 16);
}
// hi bf16 WITHOUT masking: low 16 bits act as mantissa garbage, rel err <2^-7
static __device__ __forceinline__ float bf_hi_raw(uint u) {
  return __uint_as_float(u);
}
static __device__ __forceinline__ uint fmono(float f) {
  uint u = __float_as_uint(f);
  return (u & 0x80000000u) ? ~u : (u | 0x80000000u);
}
static __device__ __forceinline__ ull umax64(ull a, ull b) {
  return a > b ? a : b;
}
static __device__ __forceinline__ ull umin64(ull a, ull b) {
  return a < b ? a : b;
}
// shuffle a u64 across lanes via two b32 shuffles (pipelined)
static __device__ __forceinline__ ull shfl_xor64(ull v, int mask) {
  const uint lo = __shfl_xor((uint)v, mask);
  const uint hi = __shfl_xor((uint)(v >> 32), mask);
  return ((ull)hi << 32) | lo;
}

// ---------------------------------------------------------------------------
// K2a v6: sim keys via LDS-staged tiles; float4 (b128) LDS traffic, stride
// 132 (bank-clean: 4L+4d mod 32, 2x min aliasing for b128). Fused u_src/u_dst
// + one-shot Wt=bf16(W_fe^T) production. fp32 ranking preserved.
// ---------------------------------------------------------------------------
__global__ __launch_bounds__(256) void k2a_sim(
    const float* __restrict__ emb, const float* __restrict__ a_src,
    const float* __restrict__ a_dst, const float* __restrict__ W_fe,
    uint* __restrict__ keys, float* __restrict__ u_src,
    float* __restrict__ u_dst, ushort* __restrict__ wt) {
  __shared__ __align__(16) float ei[8][132];  // 4.2 KB
  __shared__ __align__(16) float ej[64][132]; // 33.8 KB
  const int t = threadIdx.x, wid = t >> 6, lane = t & 63;
  const int i0 = (blockIdx.x >> 2) * 8;
  const int jbase = (blockIdx.x & 3) * 256;

  // fused k1: blocks with (blk&3)==0 compute u_src/u_dst for their 8 rows
  if ((blockIdx.x & 3) == 0) {
    const int row = i0 + 2 * wid + (lane >> 5); // half-wave per row
    const int ll = lane & 31;
    const float* er = emb + (size_t)row * EE;
    float us = 0.f, ud = 0.f;
#pragma unroll
    for (int c0 = 0; c0 < EE; c0 += 32) {
      const int c = c0 + ll;
      const float e = er[c];
      us += e * a_src[EE + c];
      ud += e * a_dst[EE + c];
    }
#pragma unroll
    for (int o = 1; o <= 16; o <<= 1) {
      us += __shfl_xor(us, o);
      ud += __shfl_xor(ud, o);
    }
    if (ll == 0) {
      u_src[row] = us;
      u_dst[row] = ud;
    }
  } else if ((blockIdx.x & 3) == 1 && (blockIdx.x >> 2) < 32) {
    // fused W transpose: Wt[n][k] = bf16(W_fe[k][n]); coalesced ushort writes
    const int g = (blockIdx.x >> 2) * 256 + t; // 0..8191
    const int n = g >> 6, k = g & 63;
    wt[g] = (ushort)f2bf(W_fe[k * EE + n]);
  }

  { // stage ei: 8 rows x 128 = 256 float4, one per thread (coalesced)
    const int r = t >> 5, c4 = t & 31;
    const float4 v = *(const float4*)&emb[(size_t)(i0 + r) * EE + c4 * 4];
    *(float4*)&ei[r][c4 * 4] = v;
  }

  const int ia = i0 + wid * 2; // this wave's two i-rows: ia, ia+1

  for (int ch = 0; ch < 4; ++ch) {
    const int j0 = jbase + ch * 64;
#pragma unroll
    for (int p = 0; p < 8; ++p) {
      const int g = p * 256 + t;
      const int r = g >> 5, c4 = g & 31;
      const float4 v = *(const float4*)&emb[(size_t)(j0 + r) * EE + c4 * 4];
      *(float4*)&ej[r][c4 * 4] = v;
    }
    __syncthreads(); // staging done (covers ei on ch==0)

    float a0 = 0.f, a1 = 0.f, sq = 0.f;
#pragma unroll 8
    for (int d4 = 0; d4 < 32; ++d4) {
      const float4 e = *(const float4*)&ej[lane][4 * d4];
      const float4 wa = *(const float4*)&ei[wid * 2][4 * d4];     // broadcast
      const float4 wb = *(const float4*)&ei[wid * 2 + 1][4 * d4]; // broadcast
      a0 += e.x * wa.x + e.y * wa.y + e.z * wa.z + e.w * wa.w;
      a1 += e.x * wb.x + e.y * wb.y + e.z * wb.z + e.w * wb.w;
      sq += e.x * e.x + e.y * e.y + e.z * e.z + e.w * e.w;
    }
    const int jg = j0 + lane;
    const float rj = rsqrtf(sq);
    keys[(size_t)ia * NN + jg] = fmono(a0 * rj);
    keys[(size_t)(ia + 1) * NN + jg] = fmono(a1 * rj);
    __syncthreads(); // compute done before ej overwrite
  }
}

// ---------------------------------------------------------------------------
// K23 v5: fused selection + MFMA GEMM. Selection: bitonic sort-256/wave,
// then a 2-STAGE parallel merge: waves 0&1 each bitonic-merge-64 a pair of
// sorted-32 lists (6 steps), wave0 merges the two survivors (6 steps) —
// replaces the serial 28-step bitonic-128. Same u64 comparisons -> same set.
// GEMM role unchanged (direct-global Wt B-frags, LDS-free).
// ---------------------------------------------------------------------------
__global__ __launch_bounds__(256) void k23(
    const uint* __restrict__ keys, int* __restrict__ idx_out,
    const float* __restrict__ x, const ushort* __restrict__ wt,
    const float* __restrict__ a_src, const float* __restrict__ a_dst,
    const float* __restrict__ u_src, const float* __restrict__ u_dst,
    uint* __restrict__ h2, float* __restrict__ es, float* __restrict__ ed) {
  __shared__ ull cand[128]; // 1 KB
  const int t = threadIdx.x, wid = t >> 6, lane = t & 63;

  if (blockIdx.x < NN) {
    // ---------------- selection role: top-32 for row = blockIdx.x ---------
    const int row = blockIdx.x;

    const int jb = wid * 256 + lane * 4;
    const uint4 kv = *(const uint4*)&keys[(size_t)row * NN + jb];
    ull xr[4];
    xr[0] = ((ull)kv.x << 32) | (uint)(jb + 0);
    xr[1] = ((ull)kv.y << 32) | (uint)(jb + 1);
    xr[2] = ((ull)kv.z << 32) | (uint)(jb + 2);
    xr[3] = ((ull)kv.w << 32) | (uint)(jb + 3);

    // bitonic sort-256 descending; element e = lane*4 + r
#pragma unroll
    for (int k = 2; k <= 256; k <<= 1) {
#pragma unroll
      for (int d = 128; d >= 1; d >>= 1) {
        if (d > (k >> 1)) continue;
        if (d >= 4) {
          const int pl = d >> 2; // partner lane distance
          const bool lower = (lane & pl) == 0;
#pragma unroll
          for (int r = 0; r < 4; ++r) {
            const ull o = shfl_xor64(xr[r], pl);
            const bool desc = (((lane * 4 + r) & k) == 0);
            const bool keepmax = (desc == lower);
            xr[r] = keepmax ? umax64(xr[r], o) : umin64(xr[r], o);
          }
        } else if (d == 2) {
#pragma unroll
          for (int r = 0; r < 2; ++r) {
            const bool desc = (((lane * 4 + r) & k) == 0);
            const ull hi = umax64(xr[r], xr[r + 2]);
            const ull lo = umin64(xr[r], xr[r + 2]);
            xr[r] = desc ? hi : lo;
            xr[r + 2] = desc ? lo : hi;
          }
        } else { // d == 1
#pragma unroll
          for (int r = 0; r < 4; r += 2) {
            const bool desc = (((lane * 4 + r) & k) == 0);
            const ull hi = umax64(xr[r], xr[r + 1]);
            const ull lo = umin64(xr[r], xr[r + 1]);
            xr[r] = desc ? hi : lo;
            xr[r + 1] = desc ? lo : hi;
          }
        }
      }
    }
    // wave-local top-32 = elements 0..31 = lanes 0..7, sorted descending
    if (lane < 8) {
#pragma unroll
      for (int r = 0; r < 4; ++r) cand[wid * 32 + lane * 4 + r] = xr[r];
    }
    __syncthreads();

    // stage 1: wave w (w<2) merges sorted-32 lists [2w], [2w+1]
    if (wid < 2) {
      const int base = wid * 64;
      ull v = (lane < 32) ? cand[base + lane] : cand[base + 95 - lane];
#pragma unroll
      for (int d = 32; d >= 1; d >>= 1) {
        const ull o = shfl_xor64(v, d);
        v = ((lane & d) == 0) ? umax64(v, o) : umin64(v, o);
      }
      if (lane < 32) cand[base + lane] = v; // wave0 -> [0,32), wave1 -> [64,96)
    }
    __syncthreads();

    // stage 2: wave0 merges [0,32) with [64,96); top-32 out
    if (wid == 0) {
      ull v = (lane < 32) ? cand[lane] : cand[127 - lane];
#pragma unroll
      for (int d = 32; d >= 1; d >>= 1) {
        const ull o = shfl_xor64(v, d);
        v = ((lane & d) == 0) ? umax64(v, o) : umin64(v, o);
      }
      if (lane < 32) idx_out[(size_t)row * TOPK + lane] = (int)(v & 1023u);
    }
  } else {
    // ---------------- k3 role: MFMA GEMM, 64 rows, LDS-free ---------------
    const int row0 = (blockIdx.x - NN) * 64;
    const int nn = lane & 15, quad = lane >> 4;
    const int row0w = row0 + wid * 16;

    // A-frags direct from global x: A[m=nn][k = s*32 + quad*8 + j]
    short8 af[2];
#pragma unroll
    for (int s = 0; s < 2; ++s) {
      const float* xr2 = x + (size_t)(row0w + nn) * F_IN + s * 32 + quad * 8;
      const float4 v0 = *(const float4*)&xr2[0];
      const float4 v1 = *(const float4*)&xr2[4];
      af[s][0] = (short)f2bf(v0.x);
      af[s][1] = (short)f2bf(v0.y);
      af[s][2] = (short)f2bf(v0.z);
      af[s][3] = (short)f2bf(v0.w);
      af[s][4] = (short)f2bf(v1.x);
      af[s][5] = (short)f2bf(v1.y);
      af[s][6] = (short)f2bf(v1.z);
      af[s][7] = (short)f2bf(v1.w);
    }

    f32x4 acc[8];
#pragma unroll
    for (int T = 0; T < 8; ++T) acc[T] = (f32x4){0.f, 0.f, 0.f, 0.f};

#pragma unroll
    for (int T = 0; T < 8; ++T) {
#pragma unroll
      for (int s = 0; s < 2; ++s) {
        // B-frag: Wt[n = T*16+nn][k = s*32+quad*8 ..+8] — coalesced 1 KB/instr
        const short8 bf =
            *(const short8*)&wt[(T * 16 + nn) * F_IN + s * 32 + quad * 8];
        acc[T] =
            __builtin_amdgcn_mfma_f32_16x16x32_bf16(af[s], bf, acc[T], 0, 0, 0);
      }
    }

    // epilogue: h2 packed (tile-pair permuted cols) + es/ed row dots
    const int growbase = row0w + quad * 4;
#pragma unroll
    for (int reg = 0; reg < 4; ++reg) {
      uint* hr = h2 + (size_t)(growbase + reg) * 64 + nn;
#pragma unroll
      for (int T4 = 0; T4 < 4; ++T4) {
        hr[T4 * 16] =
            f2bf(acc[2 * T4][reg]) | (f2bf(acc[2 * T4 + 1][reg]) << 16);
      }
    }
    float ae[8], de[8];
#pragma unroll
    for (int T = 0; T < 8; ++T) {
      ae[T] = a_src[T * 16 + nn];
      de[T] = a_dst[T * 16 + nn];
    }
#pragma unroll
    for (int reg = 0; reg < 4; ++reg) {
      float ps = 0.f, pd = 0.f;
#pragma unroll
      for (int T = 0; T < 8; ++T) {
        ps += acc[T][reg] * ae[T];
        pd += acc[T][reg] * de[T];
      }
#pragma unroll
      for (int o = 1; o <= 8; o <<= 1) {
        ps += __shfl_xor(ps, o);
        pd += __shfl_xor(pd, o);
      }
      if (nn == 0) {
        const int grow = growbase + reg;
        const int node = grow & (NN - 1);
        es[grow] = ps + u_src[node];
        ed[grow] = pd + u_dst[node];
      }
    }
  }
}

// ---------------------------------------------------------------------------
// K4 v8: quarter-wave per n (16 lanes x 4 n/wave). Each quarter owns its n's
// full 128 cols: no cross-subgroup combine; softmax instrs serve 4 n's.
// 32 uint4 gathers (1 KB/instr) issued before the softmax chain; weights &
// offsets broadcast via quarter-local ds_bpermute. Grid 4096, XCD swizzle.
// ---------------------------------------------------------------------------
__global__ __launch_bounds__(256) void k4_attn(
    const uint* __restrict__ h2, const float* __restrict__ es,
    const float* __restrict__ ed, const int* __restrict__ idx,
    const float* __restrict__ lin_W, const float* __restrict__ lin_b,
    float* __restrict__ y) {
  const int t = threadIdx.x, wid = t >> 6, lane = t & 63;
  const int blk = blockIdx.x;
  const int xcd = blk & 7, x = blk >> 3; // x: 0..511
  const int b = xcd * 8 + (x >> 6);      // 8 b's per XCD -> L2-resident h
  const int q = lane >> 4, ll = lane & 15;
  const int n = (x & 63) * 16 + wid * 4 + q; // this quarter's n
  const int pbase = q * 64;                  // bpermute byte base (quarter)

  const float* edb = ed + (size_t)b * NN;
  const float* esb = es + (size_t)b * NN;
  const char* hb = (const char*)(h2 + (size_t)b * NN * 64);

  // idx loads (2 k's per lane) + offset broadcast + issue all 32 gathers
  const int j0 = idx[n * TOPK + ll];
  const int j1 = idx[n * TOPK + 16 + ll];
  const int off0 = j0 << 8, off1 = j1 << 8; // byte offsets of h-rows
  int offA[16], offB[16];
#pragma unroll
  for (int k = 0; k < 16; ++k) {
    offA[k] = __builtin_amdgcn_ds_bpermute(pbase + k * 4, off0);
    offB[k] = __builtin_amdgcn_ds_bpermute(pbase + k * 4, off1);
  }
  uint4 tvA[16];
#pragma unroll
  for (int k = 0; k < 16; ++k)
    tvA[k] = *(const uint4*)(hb + ((uint)offA[k] + ll * 16));
  uint4 tvB[16];
#pragma unroll
  for (int k = 0; k < 16; ++k)
    tvB[k] = *(const uint4*)(hb + ((uint)offB[k] + ll * 16));

  // softmax for this quarter's n (runs while gathers are in flight)
  const float esv = esb[n];
  float s0 = esv + edb[j0];
  float s1 = esv + edb[j1];
  s0 = s0 > 0.f ? s0 : NEG_SLOPE * s0;
  s1 = s1 > 0.f ? s1 : NEG_SLOPE * s1;
  const float p0 = __expf(s0); // |s| <~ 6: safe without max-subtraction
  const float p1 = __expf(s1);
  float dsum = p0 + p1;
#pragma unroll
  for (int o = 1; o <= 8; o <<= 1) dsum += __shfl_xor(dsum, o);
  const float rs = 1.0f / dsum;
  const float w0 = p0 * rs, w1 = p1 * rs;
  float wkA[16], wkB[16];
#pragma unroll
  for (int k = 0; k < 16; ++k) {
    wkA[k] = __uint_as_float(
        __builtin_amdgcn_ds_bpermute(pbase + k * 4, __float_as_uint(w0)));
    wkB[k] = __uint_as_float(
        __builtin_amdgcn_ds_bpermute(pbase + k * 4, __float_as_uint(w1)));
  }

  // permuted lin_W: uint c=4*ll+i -> cols 32*t4+nn2 (lo), 32*t4+16+nn2 (hi)
  float lwlo[4], lwhi[4];
#pragma unroll
  for (int i = 0; i < 4; ++i) {
    const int c = 4 * ll + i;
    const int t4 = c >> 4, nn2 = c & 15;
    lwlo[i] = lin_W[t4 * 32 + nn2];
    lwhi[i] = lin_W[t4 * 32 + 16 + nn2];
  }
  const float bias = lin_b[0];

  float acc[8];
#pragma unroll
  for (int i = 0; i < 8; i++) acc[i] = 0.f;
#pragma unroll
  for (int k = 0; k < 16; ++k) {
    const float ak = wkA[k];
    const uint4 u = tvA[k];
    acc[0] += ak * bf_lo(u.x);
    acc[1] += ak * bf_hi_raw(u.x);
    acc[2] += ak * bf_lo(u.y);
    acc[3] += ak * bf_hi_raw(u.y);
    acc[4] += ak * bf_lo(u.z);
    acc[5] += ak * bf_hi_raw(u.z);
    acc[6] += ak * bf_lo(u.w);
    acc[7] += ak * bf_hi_raw(u.w);
  }
#pragma unroll
  for (int k = 0; k < 16; ++k) {
    const float ak = wkB[k];
    const uint4 u = tvB[k];
    acc[0] += ak * bf_lo(u.x);
    acc[1] += ak * bf_hi_raw(u.x);
    acc[2] += ak * bf_lo(u.y);
    acc[3] += ak * bf_hi_raw(u.y);
    acc[4] += ak * bf_lo(u.z);
    acc[5] += ak * bf_hi_raw(u.z);
    acc[6] += ak * bf_lo(u.w);
    acc[7] += ak * bf_hi_raw(u.w);
  }
  // relu + lin_W dot + 16-lane reduce (all within the quarter)
  float r = 0.f;
#pragma unroll
  for (int i = 0; i < 4; ++i) {
    const float a0 = acc[2 * i] > 0.f ? acc[2 * i] : 0.f;
    const float a1 = acc[2 * i + 1] > 0.f ? acc[2 * i + 1] : 0.f;
    r += a0 * lwlo[i] + a1 * lwhi[i];
  }
#pragma unroll
  for (int o = 1; o <= 8; o <<= 1) r += __shfl_xor(r, o);
  if (ll == 0) y[(size_t)b * NN + n] = r + bias; // lanes 0,16,32,48 store
}

// ---------------------------------------------------------------------------
extern "C" void kernel_launch(void* const* d_in, const int* in_sizes, int n_in,
                              void* d_out, int out_size, void* d_ws,
                              size_t ws_size, hipStream_t stream) {
  const float* x = (const float*)d_in[0];
  const float* emb = (const float*)d_in[1];
  const float* W_fe = (const float*)d_in[2];
  const float* a_src = (const float*)d_in[3];
  const float* a_dst = (const float*)d_in[4];
  const float* lin_W = (const float*)d_in[5];
  const float* lin_b = (const float*)d_in[6];
  float* y = (float*)d_out;

  char* ws = (char*)d_ws;
  float* u_src = (float*)(ws + 4096);
  float* u_dst = (float*)(ws + 8192);
  int* idx = (int*)(ws + 16384);       // 128 KB
  float* es = (float*)(ws + 147456);   // 256 KB
  float* ed = (float*)(ws + 409600);   // 256 KB
  uint* h2 = (uint*)(ws + 671744);     // 16 MB (bf16 pairs)
  uint* keys = (uint*)(ws + 17448960); // 4 MB
  ushort* wt = (ushort*)(ws + 21643264); // 16 KB (bf16 W^T)

  k2a_sim<<<512, 256, 0, stream>>>(emb, a_src, a_dst, W_fe, keys, u_src,
                                   u_dst, wt);
  k23<<<2048, 256, 0, stream>>>(keys, idx, x, wt, a_src, a_dst, u_src, u_dst,
                                h2, es, ed);
  k4_attn<<<4096, 256, 0, stream>>>(h2, es, ed, idx, lin_W, lin_b, y);
}